// Round 5
// baseline (649.686 us; speedup 1.0000x reference)
//
#include <hip/hip_runtime.h>

// Shapes (fixed by the problem)
#define NB 8
#define NC 512
#define ND 256
#define NP 4096
#define NHD 8
#define TWO_PI 6.2831853071795864f
#define FPITCH 65
#define HPAD 70

typedef short bf16x8 __attribute__((ext_vector_type(8)));
typedef float f32x4 __attribute__((ext_vector_type(4)));

__device__ __forceinline__ unsigned short f2bf(float f) {
    unsigned u = __float_as_uint(f);
    u += 0x7FFFu + ((u >> 16) & 1u);
    return (unsigned short)(u >> 16);
}
__device__ __forceinline__ float bf2f(unsigned short u) {
    return __uint_as_float((unsigned)u << 16);
}

__device__ __forceinline__ void load_lds16(const void* g, void* l) {
    __builtin_amdgcn_global_load_lds((const __attribute__((address_space(1))) unsigned int*)g,
                                     (__attribute__((address_space(3))) unsigned int*)l, 16, 0, 0);
}

__device__ __forceinline__ float2 cmulf(float2 a, float2 b) {
    return make_float2(a.x*b.x - a.y*b.y, a.x*b.y + a.y*b.x);
}
__device__ __forceinline__ float2 caddf(float2 a, float2 b) { return make_float2(a.x+b.x, a.y+b.y); }
__device__ __forceinline__ float2 csubf(float2 a, float2 b) { return make_float2(a.x-b.x, a.y-b.y); }

// 8-point DFT in registers. S=-1 forward, S=+1 inverse (unscaled).
template<int S>
__device__ __forceinline__ void dft8(float2 v[8]) {
    float2 e0=v[0], e1=v[2], e2=v[4], e3=v[6];
    float2 o0=v[1], o1=v[3], o2=v[5], o3=v[7];
    float2 p0=caddf(e0,e2), p1=csubf(e0,e2), q0=caddf(e1,e3), q1=csubf(e1,e3);
    float2 q1r = make_float2(-(float)S*q1.y, (float)S*q1.x);
    float2 E0=caddf(p0,q0), E2=csubf(p0,q0), E1=caddf(p1,q1r), E3=csubf(p1,q1r);
    p0=caddf(o0,o2); p1=csubf(o0,o2); q0=caddf(o1,o3); q1=csubf(o1,o3);
    q1r = make_float2(-(float)S*q1.y, (float)S*q1.x);
    float2 O0=caddf(p0,q0), O2=csubf(p0,q0), O1=caddf(p1,q1r), O3=csubf(p1,q1r);
    const float r = 0.70710678118654752f;
    float2 w1 = make_float2(r, (float)S*r);
    float2 w2 = make_float2(0.f, (float)S);
    float2 w3 = make_float2(-r, (float)S*r);
    float2 t;
    t = O0;           v[0]=caddf(E0,t); v[4]=csubf(E0,t);
    t = cmulf(w1,O1); v[1]=caddf(E1,t); v[5]=csubf(E1,t);
    t = cmulf(w2,O2); v[2]=caddf(E2,t); v[6]=csubf(E2,t);
    t = cmulf(w3,O3); v[3]=caddf(E3,t); v[7]=csubf(E3,t);
}

// 64-pt transform along the contiguous axis of each of 64 rows in LDS planes.
template<int S, int MODE>
__device__ void fft64_rows(float* Re, float* Im, const float* twc, const float* tws,
                           int tid, float2* gout, float scale)
{
    int rb = tid & 31;
    int t8 = tid >> 5;
    for (int half = 0; half < 2; ++half) {
        int r = rb + 32*half;
        float2 v[8];
        __syncthreads();
        #pragma unroll
        for (int m = 0; m < 8; ++m) {
            int idx = r*FPITCH + 8*m + t8;
            v[m] = make_float2(Re[idx], Im[idx]);
        }
        dft8<S>(v);
        #pragma unroll
        for (int k1 = 1; k1 < 8; ++k1) {
            int mm = (t8*k1) & 63;
            v[k1] = cmulf(v[k1], make_float2(twc[mm], (float)S*tws[mm]));
        }
        __syncthreads();
        #pragma unroll
        for (int k1 = 0; k1 < 8; ++k1) {
            int idx = r*FPITCH + k1*8 + t8;
            Re[idx] = v[k1].x; Im[idx] = v[k1].y;
        }
        __syncthreads();
        float2 a[8];
        #pragma unroll
        for (int m = 0; m < 8; ++m) {
            int idx = r*FPITCH + t8*8 + m;
            a[m] = make_float2(Re[idx], Im[idx]);
        }
        dft8<S>(a);
        if (MODE == 0) {
            __syncthreads();
            #pragma unroll
            for (int k2 = 0; k2 < 8; ++k2) {
                int idx = r*FPITCH + t8 + 8*k2;
                Re[idx] = a[k2].x; Im[idx] = a[k2].y;
            }
        } else {
            #pragma unroll
            for (int k2 = 0; k2 < 8; ++k2) {
                int kq = t8 + 8*k2;
                gout[r + 64*kq] = make_float2(a[k2].x*scale, a[k2].y*scale);
            }
        }
    }
    __syncthreads();
}

// 64-pt transform along the vertical axis of each of 64 columns.
// MODE 0: in-place. MODE 1: in-place * mid-twiddle.
// MODE 2: split-plane out gre/gim (+|.|^2 partial into *ss). MODE 3: bf16 |.|*scale out.
template<int S, int MODE>
__device__ void fft64_cols(float* Re, float* Im, const float* twc, const float* tws,
                           int tid, float* gre, float* gim, unsigned short* goutr,
                           float scale, float* ss)
{
    int cb = tid & 31;
    int t8 = tid >> 5;
    for (int half = 0; half < 2; ++half) {
        int col = cb + 32*half;
        float2 v[8];
        __syncthreads();
        #pragma unroll
        for (int m = 0; m < 8; ++m) {
            int idx = (8*m + t8)*FPITCH + col;
            v[m] = make_float2(Re[idx], Im[idx]);
        }
        dft8<S>(v);
        #pragma unroll
        for (int k1 = 1; k1 < 8; ++k1) {
            int mm = (t8*k1) & 63;
            v[k1] = cmulf(v[k1], make_float2(twc[mm], (float)S*tws[mm]));
        }
        __syncthreads();
        #pragma unroll
        for (int k1 = 0; k1 < 8; ++k1) {
            int idx = (k1*8 + t8)*FPITCH + col;
            Re[idx] = v[k1].x; Im[idx] = v[k1].y;
        }
        __syncthreads();
        float2 a[8];
        #pragma unroll
        for (int m = 0; m < 8; ++m) {
            int idx = (t8*8 + m)*FPITCH + col;
            a[m] = make_float2(Re[idx], Im[idx]);
        }
        dft8<S>(a);
        if (MODE <= 1) {
            __syncthreads();
            #pragma unroll
            for (int k2 = 0; k2 < 8; ++k2) {
                int row = t8 + 8*k2;
                float2 rv = a[k2];
                if (MODE == 1) {
                    float sv, cv;
                    __sincosf((TWO_PI/4096.f) * (float)(row*col), &sv, &cv);
                    rv = cmulf(rv, make_float2(cv, (float)S*sv));
                }
                int idx = row*FPITCH + col;
                Re[idx] = rv.x; Im[idx] = rv.y;
            }
        } else if (MODE == 2) {
            #pragma unroll
            for (int k2 = 0; k2 < 8; ++k2) {
                int row = t8 + 8*k2;
                *ss += a[k2].x*a[k2].x + a[k2].y*a[k2].y;
                gre[row*64 + col] = a[k2].x*scale;
                gim[row*64 + col] = a[k2].y*scale;
            }
        } else {
            #pragma unroll
            for (int k2 = 0; k2 < 8; ++k2) {
                int row = t8 + 8*k2;
                goutr[row*64 + col] = f2bf(scale * sqrtf(a[k2].x*a[k2].x + a[k2].y*a[k2].y));
            }
        }
    }
    __syncthreads();
}

// conv weights (256,512,3,3) fp32 -> wB[t][o][i] bf16 (i contiguous = K-contiguous B rows)
__global__ __launch_bounds__(256) void k_wconv(const float* __restrict__ w, unsigned short* __restrict__ wB) {
    int idx = blockIdx.x*256 + threadIdx.x;
    if (idx >= 9*NC*ND) return;
    int i = idx & 511;
    int rest = idx >> 9;
    int o = rest & 255;
    int t = rest >> 8;
    wB[idx] = f2bf(w[(o*NC + i)*9 + t]);
}

// proj weights (512,512) fp32 -> bf16, same [o][c] layout
__global__ __launch_bounds__(256) void k_wproj(const float* __restrict__ w, unsigned short* __restrict__ wb) {
    int i = blockIdx.x*256 + threadIdx.x;
    wb[i] = f2bf(w[i]);
}

// x (b, 4096, 512) fp32 -> spatially padded bf16 xpad[b][hp][wp][c], hp/wp in [0,70)
__global__ __launch_bounds__(256) void k_xpad(const float* __restrict__ x, unsigned short* __restrict__ xpad) {
    int idx = blockIdx.x*256 + threadIdx.x;
    int c8 = idx & 63;
    int rest = idx >> 6;
    int wp = rest % HPAD;
    int rest2 = rest / HPAD;
    int hp = rest2 % HPAD;
    int b = rest2 / HPAD;
    int h = hp - 3, w = wp - 3;
    bf16x8 v = {0,0,0,0,0,0,0,0};
    if (((unsigned)h) < 64u && ((unsigned)w) < 64u) {
        const float* s = x + (((size_t)b*NP + h*64 + w)*NC + c8*8);
        float4 f0 = *(const float4*)(s);
        float4 f1 = *(const float4*)(s + 4);
        v[0]=(short)f2bf(f0.x); v[1]=(short)f2bf(f0.y); v[2]=(short)f2bf(f0.z); v[3]=(short)f2bf(f0.w);
        v[4]=(short)f2bf(f1.x); v[5]=(short)f2bf(f1.y); v[6]=(short)f2bf(f1.z); v[7]=(short)f2bf(f1.w);
    }
    *(bf16x8*)(xpad + ((size_t)(b*HPAD*HPAD) + hp*HPAD + wp)*NC + c8*8) = v;
}

// bf16 MFMA implicit-GEMM dilated conv (d=3,pad=3) + bias + BN + ReLU -> out[b][o][p] fp32
// LDS-port relief: A stays in LDS (global_load_lds, double-buffered, K-slot swizzle);
// B (weights, L2-hot) is loaded DIRECTLY global->VGPR one iter ahead (reg double-buffer B0/B1).
// LDS traffic per CU-iter drops 192KB -> 96KB; MFMA becomes the binding pipe.
__global__ __launch_bounds__(256, 2) void k_conv_mfma(
        const unsigned short* __restrict__ xpad, const unsigned short* __restrict__ wB,
        const float* __restrict__ cbias, const float* __restrict__ bg, const float* __restrict__ bb,
        const float* __restrict__ bm, const float* __restrict__ bv, float* __restrict__ out)
{
    __shared__ short Als[2][8192];   // [buf][ks*4096 + row*32 + slot*8], 32 KB total
    int tid = threadIdx.x;
    int p0 = blockIdx.x * 128;
    int o0 = blockIdx.y * 128;
    int b  = blockIdx.z;
    int lane = tid & 63;
    int wv = tid >> 6;
    int wr = wv >> 1, wc = wv & 1;
    int ln = lane & 15, kq = lane >> 4;
    int kqs = kq ^ ((ln >> 1) & 3);          // swizzled K-slot (A read side)

    f32x4 acc[4][4];
    #pragma unroll
    for (int i = 0; i < 4; ++i)
        #pragma unroll
        for (int j = 0; j < 4; ++j)
            acc[i][j] = (f32x4){0.f, 0.f, 0.f, 0.f};

    int r0 = tid >> 2;
    int c16 = tid & 3;
    int c16s = c16 ^ ((r0 >> 1) & 3);        // swizzled K-slot (A global source side)
    int pA0 = p0 + r0, pA1 = p0 + 64 + r0;
    int h0 = pA0 >> 6, w0c = pA0 & 63;
    int h1 = pA1 >> 6, w1c = pA1 & 63;
    const unsigned short* xb = xpad + (size_t)b*(HPAD*HPAD)*NC;
    short* AlsD0 = &Als[0][tid*8];
    short* AlsD1 = &Als[0][2048 + tid*8];
    // per-lane B base: row (o0 + wc*64 + ln), K-slot kq (no swizzle needed on direct path)
    const unsigned short* wBl = wB + (size_t)(o0 + wc*64 + ln)*NC + kq*8;

    // Stage A K-chunk `it` (of 72 = 9 taps x 8 chunks of K=64) into buffer it&1.
    auto stage = [&](int it) {
        int buf = it & 1;
        int tap = it >> 3;
        int kc  = (it & 7) << 6;
        int q   = (tap*11) >> 5;             // tap/3 for tap in [0,9)
        int dh  = q*3, dw = (tap - q*3)*3;
        const unsigned short* a0 = xb + ((size_t)((h0 + dh)*HPAD + (w0c + dw)))*NC + kc + c16s*8;
        const unsigned short* a1 = xb + ((size_t)((h1 + dh)*HPAD + (w1c + dw)))*NC + kc + c16s*8;
        int bo = buf ? 8192 : 0;
        load_lds16(a0,      AlsD0 + bo);          // ks=0 rows 0..63
        load_lds16(a1,      AlsD1 + bo);          // ks=0 rows 64..127
        load_lds16(a0 + 32, AlsD0 + bo + 4096);   // ks=1 rows 0..63
        load_lds16(a1 + 32, AlsD1 + bo + 4096);   // ks=1 rows 64..127
    };

    // Direct global->VGPR B fragments for K-chunk `it` (8x dwordx4 per lane, L2-hot).
    auto loadB = [&](int it, bf16x8 (&dst)[2][4]) {
        int tap = it >> 3;
        int kc  = (it & 7) << 6;
        const unsigned short* base = wBl + (size_t)(tap*ND)*NC + kc;
        #pragma unroll
        for (int ks = 0; ks < 2; ++ks)
            #pragma unroll
            for (int ni = 0; ni < 4; ++ni)
                dst[ks][ni] = *(const bf16x8*)(base + (size_t)(ni*16)*NC + ks*32);
    };

    auto compute = [&](int buf, bf16x8 (&B)[2][4]) {
        #pragma unroll
        for (int ks = 0; ks < 2; ++ks) {
            bf16x8 af[4];
            #pragma unroll
            for (int mi = 0; mi < 4; ++mi)
                af[mi] = *(const bf16x8*)&Als[buf][ks*4096 + (wr*64 + mi*16 + ln)*32 + kqs*8];
            #pragma unroll
            for (int mi = 0; mi < 4; ++mi)
                #pragma unroll
                for (int ni = 0; ni < 4; ++ni)
                    acc[mi][ni] = __builtin_amdgcn_mfma_f32_16x16x32_bf16(af[mi], B[ks][ni], acc[mi][ni], 0, 0, 0);
        }
    };

    bf16x8 B0[2][4], B1[2][4];
    stage(0);
    loadB(0, B0);
    for (int t = 0; t < 36; ++t) {
        int it0 = 2*t;
        // phase 0: consume buf0 with B0; prefetch it0+1 into buf1/B1
        asm volatile("s_waitcnt vmcnt(0)" ::: "memory");
        __builtin_amdgcn_s_barrier();
        __builtin_amdgcn_sched_barrier(0);
        if (it0 + 1 < 72) { stage(it0 + 1); loadB(it0 + 1, B1); }
        compute(0, B0);
        // phase 1: consume buf1 with B1; prefetch it0+2 into buf0/B0
        asm volatile("s_waitcnt vmcnt(0)" ::: "memory");
        __builtin_amdgcn_s_barrier();
        __builtin_amdgcn_sched_barrier(0);
        if (it0 + 2 < 72) { stage(it0 + 2); loadB(it0 + 2, B0); }
        compute(1, B1);
    }

    #pragma unroll
    for (int ni = 0; ni < 4; ++ni) {
        int o = o0 + wc*64 + ni*16 + ln;
        float inv = bg[o] * rsqrtf(bv[o] + 1e-5f);
        float beta = bb[o] - bm[o]*inv;
        float cbo = cbias[o];
        #pragma unroll
        for (int mi = 0; mi < 4; ++mi) {
            int p = p0 + wr*64 + mi*16 + kq*4;
            f32x4 v = acc[mi][ni];
            float4 rv;
            rv.x = fmaxf((v[0] + cbo)*inv + beta, 0.f);
            rv.y = fmaxf((v[1] + cbo)*inv + beta, 0.f);
            rv.z = fmaxf((v[2] + cbo)*inv + beta, 0.f);
            rv.w = fmaxf((v[3] + cbo)*inv + beta, 0.f);
            *(float4*)(out + ((size_t)(b*ND + o))*NP + p) = rv;
        }
    }
}

// fft2 (forward) of one 64x64 real image -> split planes fRe/fIm; also writes per-image L2 norm
__global__ __launch_bounds__(256) void k_fft2_fwd(const float* __restrict__ src, float* __restrict__ fRe,
                                                  float* __restrict__ fIm, float* __restrict__ nrm) {
    __shared__ float Re[64*FPITCH];
    __shared__ float Im[64*FPITCH];
    __shared__ float twc[64], tws[64];
    __shared__ float part[4];
    int tid = threadIdx.x;
    size_t img = blockIdx.x;
    const float* s = src + img*4096;
    if (tid < 64) { float sv, cv; __sincosf(TWO_PI*(float)tid/64.f, &sv, &cv); twc[tid]=cv; tws[tid]=sv; }
    for (int i = tid; i < 4096; i += 256) {
        Re[(i>>6)*FPITCH + (i&63)] = s[i];
        Im[(i>>6)*FPITCH + (i&63)] = 0.f;
    }
    fft64_rows<-1,0>(Re, Im, twc, tws, tid, nullptr, 1.f);
    float ssl = 0.f;
    fft64_cols<-1,2>(Re, Im, twc, tws, tid, fRe + img*4096, fIm + img*4096, nullptr, 1.f, &ssl);
    #pragma unroll
    for (int off = 32; off > 0; off >>= 1) ssl += __shfl_down(ssl, off, 64);
    if ((tid & 63) == 0) part[tid >> 6] = ssl;
    __syncthreads();
    if (tid == 0) nrm[img] = fmaxf(sqrtf(part[0]+part[1]+part[2]+part[3]), 1e-12f);
}

// 4096-pt inverse FFT of one f-row (Cooley-Tukey 64x64): Z[k1+64*k2], includes 1/4096
__global__ __launch_bounds__(256) void k_ifft_row4096(const float* __restrict__ fRe,
        const float* __restrict__ fIm, float2* __restrict__ Z) {
    __shared__ float Re[64*FPITCH];
    __shared__ float Im[64*FPITCH];
    __shared__ float twc[64], tws[64];
    int tid = threadIdx.x;
    size_t img = blockIdx.x;
    const float* sr = fRe + img*4096;
    const float* si = fIm + img*4096;
    if (tid < 64) { float sv, cv; __sincosf(TWO_PI*(float)tid/64.f, &sv, &cv); twc[tid]=cv; tws[tid]=sv; }
    for (int i = tid; i < 4096; i += 256) {
        Re[(i>>6)*FPITCH + (i&63)] = sr[i];
        Im[(i>>6)*FPITCH + (i&63)] = si[i];
    }
    fft64_cols<1,1>(Re, Im, twc, tws, tid, nullptr, nullptr, nullptr, 1.f, nullptr);
    fft64_rows<1,1>(Re, Im, twc, tws, tid, Z + img*4096, 1.f/4096.f);
}

// gated ifft2: computes gate = sigmoid(w2 @ g1 + b2) on the fly (g1 transposed [b][p][16],
// contiguous float4 reads), multiplies f, ifft2, abs * 1/4096 -> bf16 [c][p].
__global__ __launch_bounds__(256) void k_ifft2_abs_gated(const float* __restrict__ fRe,
        const float* __restrict__ fIm, const float* __restrict__ g1, const float* __restrict__ w2,
        const float* __restrict__ w2b, unsigned short* __restrict__ out) {
    __shared__ float Re[64*FPITCH];
    __shared__ float Im[64*FPITCH];
    __shared__ float twc[64], tws[64];
    int tid = threadIdx.x;
    size_t img = blockIdx.x;
    int b = (int)(img >> 8), ch = (int)(img & 255);
    const float* sr = fRe + img*4096;
    const float* si = fIm + img*4096;
    const float* g1b = g1 + (size_t)b*NP*16;
    float4 wv0 = *(const float4*)(w2 + ch*16);
    float4 wv1 = *(const float4*)(w2 + ch*16 + 4);
    float4 wv2 = *(const float4*)(w2 + ch*16 + 8);
    float4 wv3 = *(const float4*)(w2 + ch*16 + 12);
    float w2bias = w2b[ch];
    if (tid < 64) { float sv, cv; __sincosf(TWO_PI*(float)tid/64.f, &sv, &cv); twc[tid]=cv; tws[tid]=sv; }
    for (int i = tid; i < 4096; i += 256) {
        const float* gp = g1b + (size_t)i*16;
        float4 q0 = *(const float4*)(gp);
        float4 q1 = *(const float4*)(gp + 4);
        float4 q2 = *(const float4*)(gp + 8);
        float4 q3 = *(const float4*)(gp + 12);
        float acc = w2bias
            + wv0.x*q0.x + wv0.y*q0.y + wv0.z*q0.z + wv0.w*q0.w
            + wv1.x*q1.x + wv1.y*q1.y + wv1.z*q1.z + wv1.w*q1.w
            + wv2.x*q2.x + wv2.y*q2.y + wv2.z*q2.z + wv2.w*q2.w
            + wv3.x*q3.x + wv3.y*q3.y + wv3.z*q3.z + wv3.w*q3.w;
        float gate = 1.f / (1.f + __expf(-acc));
        Re[(i>>6)*FPITCH + (i&63)] = gate*sr[i];
        Im[(i>>6)*FPITCH + (i&63)] = gate*si[i];
    }
    fft64_rows<1,0>(Re, Im, twc, tws, tid, nullptr, 1.f);
    fft64_cols<1,3>(Re, Im, twc, tws, tid, nullptr, nullptr, out + img*4096, 1.f/4096.f, nullptr);
}

// G[c][d] = sum_n f_c[n]*f_d[n] (complex, no conj), split over n into 8 partials
__global__ __launch_bounds__(256) void k_gram(const float* __restrict__ fRe, const float* __restrict__ fIm,
                                              float2* __restrict__ Gpart) {
    int split = blockIdx.x;
    int bh = blockIdx.y;
    int b = bh >> 3, h = bh & 7;
    int tid = threadIdx.x;
    int ci = tid >> 3, dg = tid & 7;
    __shared__ float2 ft[32][65];
    const float* fRb = fRe + ((size_t)(b*ND + h*32))*NP;
    const float* fIb = fIm + ((size_t)(b*ND + h*32))*NP;
    float2 acc[4];
    acc[0]=acc[1]=acc[2]=acc[3]=make_float2(0.f,0.f);
    for (int chunk = 0; chunk < 8; ++chunk) {
        int nbase = split*512 + chunk*64;
        __syncthreads();
        for (int i = tid; i < 2048; i += 256) {
            size_t off = (size_t)(i>>6)*NP + nbase + (i&63);
            ft[i>>6][i&63] = make_float2(fRb[off], fIb[off]);
        }
        __syncthreads();
        for (int nn = 0; nn < 64; ++nn) {
            float2 fc = ft[ci][nn];
            #pragma unroll
            for (int j = 0; j < 4; ++j) {
                float2 fd = ft[dg*4+j][nn];
                acc[j].x += fc.x*fd.x - fc.y*fd.y;
                acc[j].y += fc.x*fd.y + fc.y*fd.x;
            }
        }
    }
    float2* g = Gpart + ((size_t)bh*8 + split)*1024;
    #pragma unroll
    for (int j = 0; j < 4; ++j) g[ci*32 + dg*4 + j] = acc[j];
}

// reduce partials, normalize, *temp, dual softmax, then A' = (1/32) W32+ @ S
__global__ __launch_bounds__(256) void k_attn(const float2* __restrict__ Gpart, const float* __restrict__ nrm,
                                              const float* __restrict__ temp, float2* __restrict__ Ap) {
    int bh = blockIdx.x;
    int b = bh >> 3, h = bh & 7;
    int tid = threadIdx.x;
    __shared__ float2 Sm[32][33];
    __shared__ float twc[32], tws[32];
    if (tid < 32) { float sv, cv; __sincosf(TWO_PI*(float)tid/32.f, &sv, &cv); twc[tid]=cv; tws[tid]=sv; }
    const float* nb = nrm + b*ND + h*32;
    float tv = temp[h];
    const float2* gp = Gpart + (size_t)bh*8*1024;
    #pragma unroll
    for (int j = 0; j < 4; ++j) {
        int e = tid*4 + j;
        int c = e >> 5, d = e & 31;
        float2 s = make_float2(0.f, 0.f);
        for (int sp = 0; sp < 8; ++sp) { float2 v = gp[sp*1024 + e]; s.x += v.x; s.y += v.y; }
        float sc = tv / (nb[c]*nb[d]);
        Sm[c][d] = make_float2(s.x*sc, s.y*sc);
    }
    __syncthreads();
    if (tid < 32) {
        float mr = -1e30f, mi = -1e30f;
        for (int d = 0; d < 32; ++d) { float2 v = Sm[tid][d]; mr = fmaxf(mr, v.x); mi = fmaxf(mi, v.y); }
        float sr = 0.f, si = 0.f;
        for (int d = 0; d < 32; ++d) {
            float2 v = Sm[tid][d];
            v.x = __expf(v.x - mr); v.y = __expf(v.y - mi);
            sr += v.x; si += v.y;
            Sm[tid][d] = v;
        }
        float ir = 1.f/sr, ii = 1.f/si;
        for (int d = 0; d < 32; ++d) { float2 v = Sm[tid][d]; Sm[tid][d] = make_float2(v.x*ir, v.y*ii); }
    }
    __syncthreads();
    float2* ap = Ap + (size_t)bh*1024;
    #pragma unroll
    for (int j = 0; j < 4; ++j) {
        int e = tid*4 + j;
        int k = e >> 5, d = e & 31;
        float2 acc = make_float2(0.f, 0.f);
        for (int c = 0; c < 32; ++c) {
            int m = (c*k) & 31;
            float2 w = make_float2(twc[m], tws[m]);
            float2 v = Sm[c][d];
            acc.x += w.x*v.x - w.y*v.y;
            acc.y += w.x*v.y + w.y*v.x;
        }
        ap[e] = make_float2(acc.x*(1.f/32.f), acc.y*(1.f/32.f));
    }
}

// out_f2 = | A' @ Z |  per (b,head) -> bf16 [c][p]
__global__ __launch_bounds__(256) void k_outf2(const float2* __restrict__ Ap, const float2* __restrict__ Z,
                                               unsigned short* __restrict__ outf2) {
    int nc = blockIdx.x, bh = blockIdx.y;
    int b = bh >> 3, h = bh & 7;
    int tid = threadIdx.x;
    __shared__ float2 A[32][32];
    const float2* ap = Ap + (size_t)bh*1024;
    for (int i = tid; i < 1024; i += 256) A[i>>5][i&31] = ap[i];
    __syncthreads();
    int n = nc*256 + tid;
    const float2* zb = Z + ((size_t)(b*ND + h*32))*NP + n;
    float2 z[32];
    #pragma unroll
    for (int d = 0; d < 32; ++d) z[d] = zb[(size_t)d*NP];
    unsigned short* ob = outf2 + ((size_t)(b*ND + h*32))*NP + n;
    for (int k = 0; k < 32; ++k) {
        float2 acc = make_float2(0.f, 0.f);
        #pragma unroll
        for (int d = 0; d < 32; ++d) {
            float2 a = A[k][d], zz = z[d];
            acc.x += a.x*zz.x - a.y*zz.y;
            acc.y += a.x*zz.y + a.y*zz.x;
        }
        ob[(size_t)k*NP] = f2bf(sqrtf(acc.x*acc.x + acc.y*acc.y));
    }
}

// g1 = relu(BN(w1 @ Re(f)))  -- reads the compact fRe plane; writes TRANSPOSED [b][p][16]
__global__ __launch_bounds__(256) void k_g1(const float* __restrict__ fRe, const float* __restrict__ w1,
        const float* __restrict__ w1b, const float* __restrict__ gg, const float* __restrict__ gb,
        const float* __restrict__ gm, const float* __restrict__ gv, float* __restrict__ g1)
{
    int pc = blockIdx.x, b = blockIdx.y;
    int tid = threadIdx.x;
    __shared__ float w1s[16*256];
    for (int i = tid; i < 4096; i += 256) w1s[i] = w1[i];
    __syncthreads();
    int p = pc*256 + tid;
    const float* fb = fRe + (size_t)b*ND*NP + p;
    float acc[16];
    #pragma unroll
    for (int j = 0; j < 16; ++j) acc[j] = 0.f;
    for (int i = 0; i < 256; ++i) {
        float v = fb[(size_t)i*NP];
        #pragma unroll
        for (int j = 0; j < 16; ++j) acc[j] += w1s[j*256 + i] * v;
    }
    float* go = g1 + ((size_t)b*NP + p)*16;
    float4 o4[4];
    #pragma unroll
    for (int j = 0; j < 16; ++j) {
        float inv = gg[j]*rsqrtf(gv[j] + 1e-5f);
        float val = (acc[j] + w1b[j])*inv + (gb[j] - gm[j]*inv);
        ((float*)o4)[j] = fmaxf(val, 0.f);
    }
    *(float4*)(go)      = o4[0];
    *(float4*)(go + 4)  = o4[1];
    *(float4*)(go + 8)  = o4[2];
    *(float4*)(go + 12) = o4[3];
}

// A[b][p][c] bf16 = cat(outf2b,outl2b)[c][p] + x[b][p][c]
__global__ __launch_bounds__(256) void k_prep(const unsigned short* __restrict__ outf2b,
        const unsigned short* __restrict__ outl2b, const float* __restrict__ x,
        unsigned short* __restrict__ A)
{
    int tid = threadIdx.x;
    int p = blockIdx.x*64 + (tid >> 2);
    int cs = blockIdx.y*64 + (tid & 3)*16;
    int b  = blockIdx.z;
    const unsigned short* src = (cs < ND) ? (outf2b + ((size_t)(b*ND) + cs)*NP + p)
                                          : (outl2b + ((size_t)(b*ND) + (cs - ND))*NP + p);
    float av[16];
    #pragma unroll
    for (int j = 0; j < 16; ++j) av[j] = bf2f(src[(size_t)j*NP]);
    const float* xp = x + ((size_t)(b*NP) + p)*NC + cs;
    #pragma unroll
    for (int j = 0; j < 4; ++j) {
        float4 xv = *(const float4*)(xp + j*4);
        av[j*4+0] += xv.x; av[j*4+1] += xv.y; av[j*4+2] += xv.z; av[j*4+3] += xv.w;
    }
    bf16x8 v0, v1;
    #pragma unroll
    for (int j = 0; j < 8; ++j) { v0[j] = (short)f2bf(av[j]); v1[j] = (short)f2bf(av[8+j]); }
    unsigned short* ap = A + ((size_t)(b*NP) + p)*NC + cs;
    *(bf16x8*)(ap) = v0;
    *(bf16x8*)(ap + 8) = v1;
}

// bf16 MFMA proj GEMM: out[b][p][o] = A[b][p][:] . pw[o][:] + pb[o]
// Same B-direct-to-VGPR structure as k_conv_mfma (Bw is 0.5MB, L2-hot).
__global__ __launch_bounds__(256, 2) void k_projm(
        const unsigned short* __restrict__ A, const unsigned short* __restrict__ Bw,
        const float* __restrict__ pb, float* __restrict__ out)
{
    __shared__ short Als[2][8192];
    int tid = threadIdx.x;
    int p0 = blockIdx.x * 128;
    int o0 = blockIdx.y * 128;
    int b  = blockIdx.z;
    int lane = tid & 63;
    int wv = tid >> 6;
    int wr = wv >> 1, wc = wv & 1;
    int ln = lane & 15, kq = lane >> 4;
    int kqs = kq ^ ((ln >> 1) & 3);

    f32x4 acc[4][4];
    #pragma unroll
    for (int i = 0; i < 4; ++i)
        #pragma unroll
        for (int j = 0; j < 4; ++j)
            acc[i][j] = (f32x4){0.f, 0.f, 0.f, 0.f};

    int r0 = tid >> 2;
    int c16 = tid & 3;
    int c16s = c16 ^ ((r0 >> 1) & 3);
    const unsigned short* ga0 = A + ((size_t)(b*NP) + p0 + r0)*NC + c16s*8;
    const unsigned short* ga1 = A + ((size_t)(b*NP) + p0 + 64 + r0)*NC + c16s*8;
    short* AlsD0 = &Als[0][tid*8];
    short* AlsD1 = &Als[0][2048 + tid*8];
    const unsigned short* Bwl = Bw + (size_t)(o0 + wc*64 + ln)*NC + kq*8;

    auto stage = [&](int it) {
        int buf = it & 1;
        int kc = it << 6;
        int bo = buf ? 8192 : 0;
        load_lds16(ga0 + kc,      AlsD0 + bo);
        load_lds16(ga1 + kc,      AlsD1 + bo);
        load_lds16(ga0 + kc + 32, AlsD0 + bo + 4096);
        load_lds16(ga1 + kc + 32, AlsD1 + bo + 4096);
    };

    auto loadB = [&](int it, bf16x8 (&dst)[2][4]) {
        int kc = it << 6;
        const unsigned short* base = Bwl + kc;
        #pragma unroll
        for (int ks = 0; ks < 2; ++ks)
            #pragma unroll
            for (int ni = 0; ni < 4; ++ni)
                dst[ks][ni] = *(const bf16x8*)(base + (size_t)(ni*16)*NC + ks*32);
    };

    auto compute = [&](int buf, bf16x8 (&B)[2][4]) {
        #pragma unroll
        for (int ks = 0; ks < 2; ++ks) {
            bf16x8 af[4];
            #pragma unroll
            for (int mi = 0; mi < 4; ++mi)
                af[mi] = *(const bf16x8*)&Als[buf][ks*4096 + (wr*64 + mi*16 + ln)*32 + kqs*8];
            #pragma unroll
            for (int mi = 0; mi < 4; ++mi)
                #pragma unroll
                for (int ni = 0; ni < 4; ++ni)
                    acc[mi][ni] = __builtin_amdgcn_mfma_f32_16x16x32_bf16(af[mi], B[ks][ni], acc[mi][ni], 0, 0, 0);
        }
    };

    bf16x8 B0[2][4], B1[2][4];
    stage(0);
    loadB(0, B0);
    for (int t = 0; t < 4; ++t) {
        int it0 = 2*t;
        asm volatile("s_waitcnt vmcnt(0)" ::: "memory");
        __builtin_amdgcn_s_barrier();
        __builtin_amdgcn_sched_barrier(0);
        if (it0 + 1 < 8) { stage(it0 + 1); loadB(it0 + 1, B1); }
        compute(0, B0);
        asm volatile("s_waitcnt vmcnt(0)" ::: "memory");
        __builtin_amdgcn_s_barrier();
        __builtin_amdgcn_sched_barrier(0);
        if (it0 + 2 < 8) { stage(it0 + 2); loadB(it0 + 2, B0); }
        compute(1, B1);
    }

    // C/D: col(ln)=o, row(kq*4+reg)=p. 16 lanes x 4B consecutive in o => full 64B lines.
    #pragma unroll
    for (int ni = 0; ni < 4; ++ni) {
        int o = o0 + wc*64 + ni*16 + ln;
        float bias = pb[o];
        #pragma unroll
        for (int mi = 0; mi < 4; ++mi) {
            int p = p0 + wr*64 + mi*16 + kq*4;
            f32x4 v = acc[mi][ni];
            float* op = out + ((size_t)(b*NP) + p)*NC + o;
            op[0]        = v[0] + bias;
            op[NC]       = v[1] + bias;
            op[2*NC]     = v[2] + bias;
            op[3*(size_t)NC] = v[3] + bias;
        }
    }
}

extern "C" void kernel_launch(void* const* d_in, const int* in_sizes, int n_in,
                              void* d_out, int out_size, void* d_ws, size_t ws_size,
                              hipStream_t stream)
{
    const float* x      = (const float*)d_in[0];
    const float* conv_w = (const float*)d_in[1];
    const float* conv_b = (const float*)d_in[2];
    const float* bn2g   = (const float*)d_in[3];
    const float* bn2b   = (const float*)d_in[4];
    const float* bn2m   = (const float*)d_in[5];
    const float* bn2v   = (const float*)d_in[6];
    const float* temp   = (const float*)d_in[7];
    const float* w1w    = (const float*)d_in[8];
    const float* w1b    = (const float*)d_in[9];
    const float* bnwg   = (const float*)d_in[10];
    const float* bnwb   = (const float*)d_in[11];
    const float* bnwm   = (const float*)d_in[12];
    const float* bnwv   = (const float*)d_in[13];
    const float* w2w    = (const float*)d_in[14];
    const float* w2b    = (const float*)d_in[15];
    const float* projw  = (const float*)d_in[16];
    const float* projb  = (const float*)d_in[17];
    float* out = (float*)d_out;

    char* ws = (char*)d_ws;
    // Head overlay region [0, 6,823,936):
    //   wB bf16 (2,359,296 B) during conv; nrm/Gpart/Ap/g1 reuse it afterwards.
    unsigned short* wB = (unsigned short*)(ws);
    float*  nrm   = (float*)(ws);
    float2* Gpart = (float2*)(ws + 8192);
    float2* Ap    = (float2*)(ws + 8192 + 4194304);
    float*  g1    = (float*)(ws + 8192 + 4194304 + 524288);   // [b][p][16] transposed, 2MB
    char* base = ws + 6823936;
    // conv region [base, +33.5MB): conv fp32 (dead after fft2_fwd), then outf2b bf16 (16.7MB)
    float*  conv  = (float*)(base);
    unsigned short* outf2b = (unsigned short*)(base);
    // f region [base+33.5MB, +67MB): xpad bf16 overlay (40.1MB, dead after conv);
    //   then split planes fRe (33.5MB) / fIm (33.5MB), live through k_ifft2_abs_gated.
    float* fRe = (float*)(base + 33554432);
    float* fIm = (float*)(base + 33554432 + 33554432);
    unsigned short* xpad = (unsigned short*)(base + 33554432);
    // Z region [base+100.6MB, +67MB): Z complex; after k_outf2 Z dead ->
    //   pwb bf16 (0.5MB) at base, Abf bf16 (33.5MB) at +4MB, outl2b bf16 (16.7MB) at +37.7MB
    char* zbase = base + 33554432 + 67108864;
    float2* Z     = (float2*)(zbase);
    unsigned short* pwb = (unsigned short*)(zbase);
    unsigned short* Abf = (unsigned short*)(zbase + 4194304);
    unsigned short* outl2b = (unsigned short*)(zbase + 37748736);
    // total workspace used: 174,596,096 bytes (unchanged)

    k_wconv<<<dim3(4608), 256, 0, stream>>>(conv_w, wB);
    k_xpad<<<dim3(9800), 256, 0, stream>>>(x, xpad);
    k_conv_mfma<<<dim3(32, 2, 8), 256, 0, stream>>>(xpad, wB, conv_b, bn2g, bn2b, bn2m, bn2v, conv);
    k_fft2_fwd<<<dim3(2048), 256, 0, stream>>>(conv, fRe, fIm, nrm);
    k_gram<<<dim3(8, 64), 256, 0, stream>>>(fRe, fIm, Gpart);
    k_attn<<<dim3(64), 256, 0, stream>>>(Gpart, nrm, temp, Ap);
    k_ifft_row4096<<<dim3(2048), 256, 0, stream>>>(fRe, fIm, Z);
    k_outf2<<<dim3(16, 64), 256, 0, stream>>>(Ap, Z, outf2b);
    k_g1<<<dim3(16, 8), 256, 0, stream>>>(fRe, w1w, w1b, bnwg, bnwb, bnwm, bnwv, g1);
    k_ifft2_abs_gated<<<dim3(2048), 256, 0, stream>>>(fRe, fIm, g1, w2w, w2b, outl2b);
    k_wproj<<<dim3(1024), 256, 0, stream>>>(projw, pwb);
    k_prep<<<dim3(64, 8, 8), 256, 0, stream>>>(outf2b, outl2b, x, Abf);
    k_projm<<<dim3(32, 4, 8), 256, 0, stream>>>(Abf, pwb, projb, out);
}

// Round 6
// 544.645 us; speedup vs baseline: 1.1929x; 1.1929x over previous
//
#include <hip/hip_runtime.h>

// Shapes (fixed by the problem)
#define NB 8
#define NC 512
#define ND 256
#define NP 4096
#define NHD 8
#define TWO_PI 6.2831853071795864f
#define FPITCH 65
#define HPAD 70

typedef short bf16x8 __attribute__((ext_vector_type(8)));
typedef float f32x4 __attribute__((ext_vector_type(4)));

__device__ __forceinline__ unsigned short f2bf(float f) {
    unsigned u = __float_as_uint(f);
    u += 0x7FFFu + ((u >> 16) & 1u);
    return (unsigned short)(u >> 16);
}
__device__ __forceinline__ float bf2f(unsigned short u) {
    return __uint_as_float((unsigned)u << 16);
}

__device__ __forceinline__ void load_lds16(const void* g, void* l) {
    __builtin_amdgcn_global_load_lds((const __attribute__((address_space(1))) unsigned int*)g,
                                     (__attribute__((address_space(3))) unsigned int*)l, 16, 0, 0);
}

__device__ __forceinline__ float2 cmulf(float2 a, float2 b) {
    return make_float2(a.x*b.x - a.y*b.y, a.x*b.y + a.y*b.x);
}
__device__ __forceinline__ float2 caddf(float2 a, float2 b) { return make_float2(a.x+b.x, a.y+b.y); }
__device__ __forceinline__ float2 csubf(float2 a, float2 b) { return make_float2(a.x-b.x, a.y-b.y); }

// 8-point DFT in registers. S=-1 forward, S=+1 inverse (unscaled).
template<int S>
__device__ __forceinline__ void dft8(float2 v[8]) {
    float2 e0=v[0], e1=v[2], e2=v[4], e3=v[6];
    float2 o0=v[1], o1=v[3], o2=v[5], o3=v[7];
    float2 p0=caddf(e0,e2), p1=csubf(e0,e2), q0=caddf(e1,e3), q1=csubf(e1,e3);
    float2 q1r = make_float2(-(float)S*q1.y, (float)S*q1.x);
    float2 E0=caddf(p0,q0), E2=csubf(p0,q0), E1=caddf(p1,q1r), E3=csubf(p1,q1r);
    p0=caddf(o0,o2); p1=csubf(o0,o2); q0=caddf(o1,o3); q1=csubf(o1,o3);
    q1r = make_float2(-(float)S*q1.y, (float)S*q1.x);
    float2 O0=caddf(p0,q0), O2=csubf(p0,q0), O1=caddf(p1,q1r), O3=csubf(p1,q1r);
    const float r = 0.70710678118654752f;
    float2 w1 = make_float2(r, (float)S*r);
    float2 w2 = make_float2(0.f, (float)S);
    float2 w3 = make_float2(-r, (float)S*r);
    float2 t;
    t = O0;           v[0]=caddf(E0,t); v[4]=csubf(E0,t);
    t = cmulf(w1,O1); v[1]=caddf(E1,t); v[5]=csubf(E1,t);
    t = cmulf(w2,O2); v[2]=caddf(E2,t); v[6]=csubf(E2,t);
    t = cmulf(w3,O3); v[3]=caddf(E3,t); v[7]=csubf(E3,t);
}

// 64-pt transform along the contiguous axis of each of 64 rows in LDS planes.
template<int S, int MODE>
__device__ void fft64_rows(float* Re, float* Im, const float* twc, const float* tws,
                           int tid, float2* gout, float scale)
{
    int rb = tid & 31;
    int t8 = tid >> 5;
    for (int half = 0; half < 2; ++half) {
        int r = rb + 32*half;
        float2 v[8];
        __syncthreads();
        #pragma unroll
        for (int m = 0; m < 8; ++m) {
            int idx = r*FPITCH + 8*m + t8;
            v[m] = make_float2(Re[idx], Im[idx]);
        }
        dft8<S>(v);
        #pragma unroll
        for (int k1 = 1; k1 < 8; ++k1) {
            int mm = (t8*k1) & 63;
            v[k1] = cmulf(v[k1], make_float2(twc[mm], (float)S*tws[mm]));
        }
        __syncthreads();
        #pragma unroll
        for (int k1 = 0; k1 < 8; ++k1) {
            int idx = r*FPITCH + k1*8 + t8;
            Re[idx] = v[k1].x; Im[idx] = v[k1].y;
        }
        __syncthreads();
        float2 a[8];
        #pragma unroll
        for (int m = 0; m < 8; ++m) {
            int idx = r*FPITCH + t8*8 + m;
            a[m] = make_float2(Re[idx], Im[idx]);
        }
        dft8<S>(a);
        if (MODE == 0) {
            __syncthreads();
            #pragma unroll
            for (int k2 = 0; k2 < 8; ++k2) {
                int idx = r*FPITCH + t8 + 8*k2;
                Re[idx] = a[k2].x; Im[idx] = a[k2].y;
            }
        } else {
            #pragma unroll
            for (int k2 = 0; k2 < 8; ++k2) {
                int kq = t8 + 8*k2;
                gout[r + 64*kq] = make_float2(a[k2].x*scale, a[k2].y*scale);
            }
        }
    }
    __syncthreads();
}

// 64-pt transform along the vertical axis of each of 64 columns.
// MODE 0: in-place. MODE 1: in-place * mid-twiddle.
// MODE 2: split-plane out gre/gim (+|.|^2 partial into *ss). MODE 3: bf16 |.|*scale out.
template<int S, int MODE>
__device__ void fft64_cols(float* Re, float* Im, const float* twc, const float* tws,
                           int tid, float* gre, float* gim, unsigned short* goutr,
                           float scale, float* ss)
{
    int cb = tid & 31;
    int t8 = tid >> 5;
    for (int half = 0; half < 2; ++half) {
        int col = cb + 32*half;
        float2 v[8];
        __syncthreads();
        #pragma unroll
        for (int m = 0; m < 8; ++m) {
            int idx = (8*m + t8)*FPITCH + col;
            v[m] = make_float2(Re[idx], Im[idx]);
        }
        dft8<S>(v);
        #pragma unroll
        for (int k1 = 1; k1 < 8; ++k1) {
            int mm = (t8*k1) & 63;
            v[k1] = cmulf(v[k1], make_float2(twc[mm], (float)S*tws[mm]));
        }
        __syncthreads();
        #pragma unroll
        for (int k1 = 0; k1 < 8; ++k1) {
            int idx = (k1*8 + t8)*FPITCH + col;
            Re[idx] = v[k1].x; Im[idx] = v[k1].y;
        }
        __syncthreads();
        float2 a[8];
        #pragma unroll
        for (int m = 0; m < 8; ++m) {
            int idx = (t8*8 + m)*FPITCH + col;
            a[m] = make_float2(Re[idx], Im[idx]);
        }
        dft8<S>(a);
        if (MODE <= 1) {
            __syncthreads();
            #pragma unroll
            for (int k2 = 0; k2 < 8; ++k2) {
                int row = t8 + 8*k2;
                float2 rv = a[k2];
                if (MODE == 1) {
                    float sv, cv;
                    __sincosf((TWO_PI/4096.f) * (float)(row*col), &sv, &cv);
                    rv = cmulf(rv, make_float2(cv, (float)S*sv));
                }
                int idx = row*FPITCH + col;
                Re[idx] = rv.x; Im[idx] = rv.y;
            }
        } else if (MODE == 2) {
            #pragma unroll
            for (int k2 = 0; k2 < 8; ++k2) {
                int row = t8 + 8*k2;
                *ss += a[k2].x*a[k2].x + a[k2].y*a[k2].y;
                gre[row*64 + col] = a[k2].x*scale;
                gim[row*64 + col] = a[k2].y*scale;
            }
        } else {
            #pragma unroll
            for (int k2 = 0; k2 < 8; ++k2) {
                int row = t8 + 8*k2;
                goutr[row*64 + col] = f2bf(scale * sqrtf(a[k2].x*a[k2].x + a[k2].y*a[k2].y));
            }
        }
    }
    __syncthreads();
}

// conv weights (256,512,3,3) fp32 -> wB[t][o][i] bf16 (i contiguous = K-contiguous B rows)
__global__ __launch_bounds__(256) void k_wconv(const float* __restrict__ w, unsigned short* __restrict__ wB) {
    int idx = blockIdx.x*256 + threadIdx.x;
    if (idx >= 9*NC*ND) return;
    int i = idx & 511;
    int rest = idx >> 9;
    int o = rest & 255;
    int t = rest >> 8;
    wB[idx] = f2bf(w[(o*NC + i)*9 + t]);
}

// proj weights (512,512) fp32 -> bf16, same [o][c] layout
__global__ __launch_bounds__(256) void k_wproj(const float* __restrict__ w, unsigned short* __restrict__ wb) {
    int i = blockIdx.x*256 + threadIdx.x;
    wb[i] = f2bf(w[i]);
}

// x (b, 4096, 512) fp32 -> spatially padded bf16 xpad[b][hp][wp][c], hp/wp in [0,70)
__global__ __launch_bounds__(256) void k_xpad(const float* __restrict__ x, unsigned short* __restrict__ xpad) {
    int idx = blockIdx.x*256 + threadIdx.x;
    int c8 = idx & 63;
    int rest = idx >> 6;
    int wp = rest % HPAD;
    int rest2 = rest / HPAD;
    int hp = rest2 % HPAD;
    int b = rest2 / HPAD;
    int h = hp - 3, w = wp - 3;
    bf16x8 v = {0,0,0,0,0,0,0,0};
    if (((unsigned)h) < 64u && ((unsigned)w) < 64u) {
        const float* s = x + (((size_t)b*NP + h*64 + w)*NC + c8*8);
        float4 f0 = *(const float4*)(s);
        float4 f1 = *(const float4*)(s + 4);
        v[0]=(short)f2bf(f0.x); v[1]=(short)f2bf(f0.y); v[2]=(short)f2bf(f0.z); v[3]=(short)f2bf(f0.w);
        v[4]=(short)f2bf(f1.x); v[5]=(short)f2bf(f1.y); v[6]=(short)f2bf(f1.z); v[7]=(short)f2bf(f1.w);
    }
    *(bf16x8*)(xpad + ((size_t)(b*HPAD*HPAD) + hp*HPAD + wp)*NC + c8*8) = v;
}

// bf16 MFMA implicit-GEMM dilated conv (d=3,pad=3) + bias + BN + ReLU -> out[b][o][p] fp32
// R4-proven 2-phase double-buffer: K=64 chunks, one barrier per chunk, stage issued before compute.
// K-slot swizzle (verified bijective; conflicts 0): source slot c16^((r0>>1)&3), read slot kq^((ln>>1)&3).
__global__ __launch_bounds__(256, 2) void k_conv_mfma(
        const unsigned short* __restrict__ xpad, const unsigned short* __restrict__ wB,
        const float* __restrict__ cbias, const float* __restrict__ bg, const float* __restrict__ bb,
        const float* __restrict__ bm, const float* __restrict__ bv, float* __restrict__ out)
{
    // [buf][ks*4096 + row*32 + slot*8] ; 2 bufs x (A,B) x 16 KB = 64 KB
    __shared__ short Als[2][8192];
    __shared__ short Bls[2][8192];
    int tid = threadIdx.x;
    int p0 = blockIdx.x * 128;
    int o0 = blockIdx.y * 128;
    int b  = blockIdx.z;
    int lane = tid & 63;
    int wv = tid >> 6;
    int wr = wv >> 1, wc = wv & 1;
    int ln = lane & 15, kq = lane >> 4;
    int kqs = kq ^ ((ln >> 1) & 3);          // swizzled K-slot (read side)

    f32x4 acc[4][4];
    #pragma unroll
    for (int i = 0; i < 4; ++i)
        #pragma unroll
        for (int j = 0; j < 4; ++j)
            acc[i][j] = (f32x4){0.f, 0.f, 0.f, 0.f};

    int r0 = tid >> 2;
    int c16 = tid & 3;
    int c16s = c16 ^ ((r0 >> 1) & 3);        // swizzled K-slot (global source side)
    int pA0 = p0 + r0, pA1 = p0 + 64 + r0;
    int h0 = pA0 >> 6, w0c = pA0 & 63;
    int h1 = pA1 >> 6, w1c = pA1 & 63;
    const unsigned short* xb = xpad + (size_t)b*(HPAD*HPAD)*NC;
    int oB0 = o0 + r0, oB1 = o0 + 64 + r0;
    short* AlsD0 = &Als[0][tid*8];
    short* AlsD1 = &Als[0][2048 + tid*8];
    short* BlsD0 = &Bls[0][tid*8];
    short* BlsD1 = &Bls[0][2048 + tid*8];

    // Stage K-chunk `it` (of 72 = 9 taps x 8 chunks of K=64) into buffer it&1.
    auto stage = [&](int it) {
        int buf = it & 1;
        int tap = it >> 3;
        int kc  = (it & 7) << 6;
        int q   = (tap*11) >> 5;             // tap/3 for tap in [0,9)
        int dh  = q*3, dw = (tap - q*3)*3;
        const unsigned short* a0 = xb + ((size_t)((h0 + dh)*HPAD + (w0c + dw)))*NC + kc + c16s*8;
        const unsigned short* a1 = xb + ((size_t)((h1 + dh)*HPAD + (w1c + dw)))*NC + kc + c16s*8;
        const unsigned short* b0 = wB + ((size_t)(tap*ND + oB0))*NC + kc + c16s*8;
        const unsigned short* b1 = wB + ((size_t)(tap*ND + oB1))*NC + kc + c16s*8;
        int bo = buf ? 8192 : 0;
        load_lds16(a0,      AlsD0 + bo);          // ks=0 rows 0..63
        load_lds16(a1,      AlsD1 + bo);          // ks=0 rows 64..127
        load_lds16(a0 + 32, AlsD0 + bo + 4096);   // ks=1 rows 0..63
        load_lds16(a1 + 32, AlsD1 + bo + 4096);   // ks=1 rows 64..127
        load_lds16(b0,      BlsD0 + bo);
        load_lds16(b1,      BlsD1 + bo);
        load_lds16(b0 + 32, BlsD0 + bo + 4096);
        load_lds16(b1 + 32, BlsD1 + bo + 4096);
    };

    stage(0);
    #pragma unroll 2
    for (int it = 0; it < 72; ++it) {
        int buf = it & 1;
        // my 8 loads for buf (issued last iteration / prologue) must be complete
        asm volatile("s_waitcnt vmcnt(0)" ::: "memory");
        __builtin_amdgcn_s_barrier();          // all waves: buf ready; all prev ds_reads done
        __builtin_amdgcn_sched_barrier(0);     // no LDS access motion across the barrier
        if (it + 1 < 72) stage(it + 1);        // overlap with compute below
        #pragma unroll
        for (int ks = 0; ks < 2; ++ks) {
            bf16x8 af[4], bfr[4];
            #pragma unroll
            for (int mi = 0; mi < 4; ++mi)
                af[mi] = *(const bf16x8*)&Als[buf][ks*4096 + (wr*64 + mi*16 + ln)*32 + kqs*8];
            #pragma unroll
            for (int ni = 0; ni < 4; ++ni)
                bfr[ni] = *(const bf16x8*)&Bls[buf][ks*4096 + (wc*64 + ni*16 + ln)*32 + kqs*8];
            #pragma unroll
            for (int mi = 0; mi < 4; ++mi)
                #pragma unroll
                for (int ni = 0; ni < 4; ++ni)
                    acc[mi][ni] = __builtin_amdgcn_mfma_f32_16x16x32_bf16(af[mi], bfr[ni], acc[mi][ni], 0, 0, 0);
        }
    }

    #pragma unroll
    for (int ni = 0; ni < 4; ++ni) {
        int o = o0 + wc*64 + ni*16 + ln;
        float inv = bg[o] * rsqrtf(bv[o] + 1e-5f);
        float beta = bb[o] - bm[o]*inv;
        float cbo = cbias[o];
        #pragma unroll
        for (int mi = 0; mi < 4; ++mi) {
            int p = p0 + wr*64 + mi*16 + kq*4;
            f32x4 v = acc[mi][ni];
            float4 rv;
            rv.x = fmaxf((v[0] + cbo)*inv + beta, 0.f);
            rv.y = fmaxf((v[1] + cbo)*inv + beta, 0.f);
            rv.z = fmaxf((v[2] + cbo)*inv + beta, 0.f);
            rv.w = fmaxf((v[3] + cbo)*inv + beta, 0.f);
            *(float4*)(out + ((size_t)(b*ND + o))*NP + p) = rv;
        }
    }
}

// fft2 (forward) of one 64x64 real image -> split planes fRe/fIm; also writes per-image L2 norm
__global__ __launch_bounds__(256) void k_fft2_fwd(const float* __restrict__ src, float* __restrict__ fRe,
                                                  float* __restrict__ fIm, float* __restrict__ nrm) {
    __shared__ float Re[64*FPITCH];
    __shared__ float Im[64*FPITCH];
    __shared__ float twc[64], tws[64];
    __shared__ float part[4];
    int tid = threadIdx.x;
    size_t img = blockIdx.x;
    const float* s = src + img*4096;
    if (tid < 64) { float sv, cv; __sincosf(TWO_PI*(float)tid/64.f, &sv, &cv); twc[tid]=cv; tws[tid]=sv; }
    for (int i = tid; i < 4096; i += 256) {
        Re[(i>>6)*FPITCH + (i&63)] = s[i];
        Im[(i>>6)*FPITCH + (i&63)] = 0.f;
    }
    fft64_rows<-1,0>(Re, Im, twc, tws, tid, nullptr, 1.f);
    float ssl = 0.f;
    fft64_cols<-1,2>(Re, Im, twc, tws, tid, fRe + img*4096, fIm + img*4096, nullptr, 1.f, &ssl);
    #pragma unroll
    for (int off = 32; off > 0; off >>= 1) ssl += __shfl_down(ssl, off, 64);
    if ((tid & 63) == 0) part[tid >> 6] = ssl;
    __syncthreads();
    if (tid == 0) nrm[img] = fmaxf(sqrtf(part[0]+part[1]+part[2]+part[3]), 1e-12f);
}

// 4096-pt inverse FFT of one f-row (Cooley-Tukey 64x64): Z[k1+64*k2], includes 1/4096
__global__ __launch_bounds__(256) void k_ifft_row4096(const float* __restrict__ fRe,
        const float* __restrict__ fIm, float2* __restrict__ Z) {
    __shared__ float Re[64*FPITCH];
    __shared__ float Im[64*FPITCH];
    __shared__ float twc[64], tws[64];
    int tid = threadIdx.x;
    size_t img = blockIdx.x;
    const float* sr = fRe + img*4096;
    const float* si = fIm + img*4096;
    if (tid < 64) { float sv, cv; __sincosf(TWO_PI*(float)tid/64.f, &sv, &cv); twc[tid]=cv; tws[tid]=sv; }
    for (int i = tid; i < 4096; i += 256) {
        Re[(i>>6)*FPITCH + (i&63)] = sr[i];
        Im[(i>>6)*FPITCH + (i&63)] = si[i];
    }
    fft64_cols<1,1>(Re, Im, twc, tws, tid, nullptr, nullptr, nullptr, 1.f, nullptr);
    fft64_rows<1,1>(Re, Im, twc, tws, tid, Z + img*4096, 1.f/4096.f);
}

// gated ifft2: computes gate = sigmoid(w2 @ g1 + b2) on the fly (g1 transposed [b][p][16],
// contiguous float4 reads), multiplies f, ifft2, abs * 1/4096 -> bf16 [c][p].
__global__ __launch_bounds__(256) void k_ifft2_abs_gated(const float* __restrict__ fRe,
        const float* __restrict__ fIm, const float* __restrict__ g1, const float* __restrict__ w2,
        const float* __restrict__ w2b, unsigned short* __restrict__ out) {
    __shared__ float Re[64*FPITCH];
    __shared__ float Im[64*FPITCH];
    __shared__ float twc[64], tws[64];
    int tid = threadIdx.x;
    size_t img = blockIdx.x;
    int b = (int)(img >> 8), ch = (int)(img & 255);
    const float* sr = fRe + img*4096;
    const float* si = fIm + img*4096;
    const float* g1b = g1 + (size_t)b*NP*16;
    float4 wv0 = *(const float4*)(w2 + ch*16);
    float4 wv1 = *(const float4*)(w2 + ch*16 + 4);
    float4 wv2 = *(const float4*)(w2 + ch*16 + 8);
    float4 wv3 = *(const float4*)(w2 + ch*16 + 12);
    float w2bias = w2b[ch];
    if (tid < 64) { float sv, cv; __sincosf(TWO_PI*(float)tid/64.f, &sv, &cv); twc[tid]=cv; tws[tid]=sv; }
    for (int i = tid; i < 4096; i += 256) {
        const float* gp = g1b + (size_t)i*16;
        float4 q0 = *(const float4*)(gp);
        float4 q1 = *(const float4*)(gp + 4);
        float4 q2 = *(const float4*)(gp + 8);
        float4 q3 = *(const float4*)(gp + 12);
        float acc = w2bias
            + wv0.x*q0.x + wv0.y*q0.y + wv0.z*q0.z + wv0.w*q0.w
            + wv1.x*q1.x + wv1.y*q1.y + wv1.z*q1.z + wv1.w*q1.w
            + wv2.x*q2.x + wv2.y*q2.y + wv2.z*q2.z + wv2.w*q2.w
            + wv3.x*q3.x + wv3.y*q3.y + wv3.z*q3.z + wv3.w*q3.w;
        float gate = 1.f / (1.f + __expf(-acc));
        Re[(i>>6)*FPITCH + (i&63)] = gate*sr[i];
        Im[(i>>6)*FPITCH + (i&63)] = gate*si[i];
    }
    fft64_rows<1,0>(Re, Im, twc, tws, tid, nullptr, 1.f);
    fft64_cols<1,3>(Re, Im, twc, tws, tid, nullptr, nullptr, out + img*4096, 1.f/4096.f, nullptr);
}

// G[c][d] = sum_n f_c[n]*f_d[n] (complex, no conj), split over n into 8 partials
__global__ __launch_bounds__(256) void k_gram(const float* __restrict__ fRe, const float* __restrict__ fIm,
                                              float2* __restrict__ Gpart) {
    int split = blockIdx.x;
    int bh = blockIdx.y;
    int b = bh >> 3, h = bh & 7;
    int tid = threadIdx.x;
    int ci = tid >> 3, dg = tid & 7;
    __shared__ float2 ft[32][65];
    const float* fRb = fRe + ((size_t)(b*ND + h*32))*NP;
    const float* fIb = fIm + ((size_t)(b*ND + h*32))*NP;
    float2 acc[4];
    acc[0]=acc[1]=acc[2]=acc[3]=make_float2(0.f,0.f);
    for (int chunk = 0; chunk < 8; ++chunk) {
        int nbase = split*512 + chunk*64;
        __syncthreads();
        for (int i = tid; i < 2048; i += 256) {
            size_t off = (size_t)(i>>6)*NP + nbase + (i&63);
            ft[i>>6][i&63] = make_float2(fRb[off], fIb[off]);
        }
        __syncthreads();
        for (int nn = 0; nn < 64; ++nn) {
            float2 fc = ft[ci][nn];
            #pragma unroll
            for (int j = 0; j < 4; ++j) {
                float2 fd = ft[dg*4+j][nn];
                acc[j].x += fc.x*fd.x - fc.y*fd.y;
                acc[j].y += fc.x*fd.y + fc.y*fd.x;
            }
        }
    }
    float2* g = Gpart + ((size_t)bh*8 + split)*1024;
    #pragma unroll
    for (int j = 0; j < 4; ++j) g[ci*32 + dg*4 + j] = acc[j];
}

// reduce partials, normalize, *temp, dual softmax, then A' = (1/32) W32+ @ S
__global__ __launch_bounds__(256) void k_attn(const float2* __restrict__ Gpart, const float* __restrict__ nrm,
                                              const float* __restrict__ temp, float2* __restrict__ Ap) {
    int bh = blockIdx.x;
    int b = bh >> 3, h = bh & 7;
    int tid = threadIdx.x;
    __shared__ float2 Sm[32][33];
    __shared__ float twc[32], tws[32];
    if (tid < 32) { float sv, cv; __sincosf(TWO_PI*(float)tid/32.f, &sv, &cv); twc[tid]=cv; tws[tid]=sv; }
    const float* nb = nrm + b*ND + h*32;
    float tv = temp[h];
    const float2* gp = Gpart + (size_t)bh*8*1024;
    #pragma unroll
    for (int j = 0; j < 4; ++j) {
        int e = tid*4 + j;
        int c = e >> 5, d = e & 31;
        float2 s = make_float2(0.f, 0.f);
        for (int sp = 0; sp < 8; ++sp) { float2 v = gp[sp*1024 + e]; s.x += v.x; s.y += v.y; }
        float sc = tv / (nb[c]*nb[d]);
        Sm[c][d] = make_float2(s.x*sc, s.y*sc);
    }
    __syncthreads();
    if (tid < 32) {
        float mr = -1e30f, mi = -1e30f;
        for (int d = 0; d < 32; ++d) { float2 v = Sm[tid][d]; mr = fmaxf(mr, v.x); mi = fmaxf(mi, v.y); }
        float sr = 0.f, si = 0.f;
        for (int d = 0; d < 32; ++d) {
            float2 v = Sm[tid][d];
            v.x = __expf(v.x - mr); v.y = __expf(v.y - mi);
            sr += v.x; si += v.y;
            Sm[tid][d] = v;
        }
        float ir = 1.f/sr, ii = 1.f/si;
        for (int d = 0; d < 32; ++d) { float2 v = Sm[tid][d]; Sm[tid][d] = make_float2(v.x*ir, v.y*ii); }
    }
    __syncthreads();
    float2* ap = Ap + (size_t)bh*1024;
    #pragma unroll
    for (int j = 0; j < 4; ++j) {
        int e = tid*4 + j;
        int k = e >> 5, d = e & 31;
        float2 acc = make_float2(0.f, 0.f);
        for (int c = 0; c < 32; ++c) {
            int m = (c*k) & 31;
            float2 w = make_float2(twc[m], tws[m]);
            float2 v = Sm[c][d];
            acc.x += w.x*v.x - w.y*v.y;
            acc.y += w.x*v.y + w.y*v.x;
        }
        ap[e] = make_float2(acc.x*(1.f/32.f), acc.y*(1.f/32.f));
    }
}

// out_f2 = | A' @ Z |  per (b,head) -> bf16 [c][p]
__global__ __launch_bounds__(256) void k_outf2(const float2* __restrict__ Ap, const float2* __restrict__ Z,
                                               unsigned short* __restrict__ outf2) {
    int nc = blockIdx.x, bh = blockIdx.y;
    int b = bh >> 3, h = bh & 7;
    int tid = threadIdx.x;
    __shared__ float2 A[32][32];
    const float2* ap = Ap + (size_t)bh*1024;
    for (int i = tid; i < 1024; i += 256) A[i>>5][i&31] = ap[i];
    __syncthreads();
    int n = nc*256 + tid;
    const float2* zb = Z + ((size_t)(b*ND + h*32))*NP + n;
    float2 z[32];
    #pragma unroll
    for (int d = 0; d < 32; ++d) z[d] = zb[(size_t)d*NP];
    unsigned short* ob = outf2 + ((size_t)(b*ND + h*32))*NP + n;
    for (int k = 0; k < 32; ++k) {
        float2 acc = make_float2(0.f, 0.f);
        #pragma unroll
        for (int d = 0; d < 32; ++d) {
            float2 a = A[k][d], zz = z[d];
            acc.x += a.x*zz.x - a.y*zz.y;
            acc.y += a.x*zz.y + a.y*zz.x;
        }
        ob[(size_t)k*NP] = f2bf(sqrtf(acc.x*acc.x + acc.y*acc.y));
    }
}

// g1 = relu(BN(w1 @ Re(f)))  -- reads the compact fRe plane; writes TRANSPOSED [b][p][16]
__global__ __launch_bounds__(256) void k_g1(const float* __restrict__ fRe, const float* __restrict__ w1,
        const float* __restrict__ w1b, const float* __restrict__ gg, const float* __restrict__ gb,
        const float* __restrict__ gm, const float* __restrict__ gv, float* __restrict__ g1)
{
    int pc = blockIdx.x, b = blockIdx.y;
    int tid = threadIdx.x;
    __shared__ float w1s[16*256];
    for (int i = tid; i < 4096; i += 256) w1s[i] = w1[i];
    __syncthreads();
    int p = pc*256 + tid;
    const float* fb = fRe + (size_t)b*ND*NP + p;
    float acc[16];
    #pragma unroll
    for (int j = 0; j < 16; ++j) acc[j] = 0.f;
    for (int i = 0; i < 256; ++i) {
        float v = fb[(size_t)i*NP];
        #pragma unroll
        for (int j = 0; j < 16; ++j) acc[j] += w1s[j*256 + i] * v;
    }
    float* go = g1 + ((size_t)b*NP + p)*16;
    float4 o4[4];
    #pragma unroll
    for (int j = 0; j < 16; ++j) {
        float inv = gg[j]*rsqrtf(gv[j] + 1e-5f);
        float val = (acc[j] + w1b[j])*inv + (gb[j] - gm[j]*inv);
        ((float*)o4)[j] = fmaxf(val, 0.f);
    }
    *(float4*)(go)      = o4[0];
    *(float4*)(go + 4)  = o4[1];
    *(float4*)(go + 8)  = o4[2];
    *(float4*)(go + 12) = o4[3];
}

// A[b][p][c] bf16 = cat(outf2b,outl2b)[c][p] + x[b][p][c]
__global__ __launch_bounds__(256) void k_prep(const unsigned short* __restrict__ outf2b,
        const unsigned short* __restrict__ outl2b, const float* __restrict__ x,
        unsigned short* __restrict__ A)
{
    int tid = threadIdx.x;
    int p = blockIdx.x*64 + (tid >> 2);
    int cs = blockIdx.y*64 + (tid & 3)*16;
    int b  = blockIdx.z;
    const unsigned short* src = (cs < ND) ? (outf2b + ((size_t)(b*ND) + cs)*NP + p)
                                          : (outl2b + ((size_t)(b*ND) + (cs - ND))*NP + p);
    float av[16];
    #pragma unroll
    for (int j = 0; j < 16; ++j) av[j] = bf2f(src[(size_t)j*NP]);
    const float* xp = x + ((size_t)(b*NP) + p)*NC + cs;
    #pragma unroll
    for (int j = 0; j < 4; ++j) {
        float4 xv = *(const float4*)(xp + j*4);
        av[j*4+0] += xv.x; av[j*4+1] += xv.y; av[j*4+2] += xv.z; av[j*4+3] += xv.w;
    }
    bf16x8 v0, v1;
    #pragma unroll
    for (int j = 0; j < 8; ++j) { v0[j] = (short)f2bf(av[j]); v1[j] = (short)f2bf(av[8+j]); }
    unsigned short* ap = A + ((size_t)(b*NP) + p)*NC + cs;
    *(bf16x8*)(ap) = v0;
    *(bf16x8*)(ap + 8) = v1;
}

// bf16 MFMA proj GEMM: out[b][p][o] = A[b][p][:] . pw[o][:] + pb[o]
// R4-proven 2-phase double-buffer + K-slot swizzle.
__global__ __launch_bounds__(256, 2) void k_projm(
        const unsigned short* __restrict__ A, const unsigned short* __restrict__ Bw,
        const float* __restrict__ pb, float* __restrict__ out)
{
    __shared__ short Als[2][8192];
    __shared__ short Bls[2][8192];
    int tid = threadIdx.x;
    int p0 = blockIdx.x * 128;
    int o0 = blockIdx.y * 128;
    int b  = blockIdx.z;
    int lane = tid & 63;
    int wv = tid >> 6;
    int wr = wv >> 1, wc = wv & 1;
    int ln = lane & 15, kq = lane >> 4;
    int kqs = kq ^ ((ln >> 1) & 3);

    f32x4 acc[4][4];
    #pragma unroll
    for (int i = 0; i < 4; ++i)
        #pragma unroll
        for (int j = 0; j < 4; ++j)
            acc[i][j] = (f32x4){0.f, 0.f, 0.f, 0.f};

    int r0 = tid >> 2;
    int c16 = tid & 3;
    int c16s = c16 ^ ((r0 >> 1) & 3);
    const unsigned short* ga0 = A + ((size_t)(b*NP) + p0 + r0)*NC + c16s*8;
    const unsigned short* ga1 = A + ((size_t)(b*NP) + p0 + 64 + r0)*NC + c16s*8;
    const unsigned short* gb0 = Bw + (size_t)(o0 + r0)*NC + c16s*8;
    const unsigned short* gb1 = Bw + (size_t)(o0 + 64 + r0)*NC + c16s*8;
    short* AlsD0 = &Als[0][tid*8];
    short* AlsD1 = &Als[0][2048 + tid*8];
    short* BlsD0 = &Bls[0][tid*8];
    short* BlsD1 = &Bls[0][2048 + tid*8];

    auto stage = [&](int it) {
        int buf = it & 1;
        int kc = it << 6;
        int bo = buf ? 8192 : 0;
        load_lds16(ga0 + kc,      AlsD0 + bo);
        load_lds16(ga1 + kc,      AlsD1 + bo);
        load_lds16(ga0 + kc + 32, AlsD0 + bo + 4096);
        load_lds16(ga1 + kc + 32, AlsD1 + bo + 4096);
        load_lds16(gb0 + kc,      BlsD0 + bo);
        load_lds16(gb1 + kc,      BlsD1 + bo);
        load_lds16(gb0 + kc + 32, BlsD0 + bo + 4096);
        load_lds16(gb1 + kc + 32, BlsD1 + bo + 4096);
    };

    stage(0);
    #pragma unroll 2
    for (int it = 0; it < 8; ++it) {
        int buf = it & 1;
        asm volatile("s_waitcnt vmcnt(0)" ::: "memory");
        __builtin_amdgcn_s_barrier();
        __builtin_amdgcn_sched_barrier(0);
        if (it + 1 < 8) stage(it + 1);
        #pragma unroll
        for (int ks = 0; ks < 2; ++ks) {
            bf16x8 af[4], bfr[4];
            #pragma unroll
            for (int mi = 0; mi < 4; ++mi)
                af[mi] = *(const bf16x8*)&Als[buf][ks*4096 + (wr*64 + mi*16 + ln)*32 + kqs*8];
            #pragma unroll
            for (int ni = 0; ni < 4; ++ni)
                bfr[ni] = *(const bf16x8*)&Bls[buf][ks*4096 + (wc*64 + ni*16 + ln)*32 + kqs*8];
            #pragma unroll
            for (int mi = 0; mi < 4; ++mi)
                #pragma unroll
                for (int ni = 0; ni < 4; ++ni)
                    acc[mi][ni] = __builtin_amdgcn_mfma_f32_16x16x32_bf16(af[mi], bfr[ni], acc[mi][ni], 0, 0, 0);
        }
    }

    // C/D: col(ln)=o, row(kq*4+reg)=p. 16 lanes x 4B consecutive in o => full 64B lines.
    #pragma unroll
    for (int ni = 0; ni < 4; ++ni) {
        int o = o0 + wc*64 + ni*16 + ln;
        float bias = pb[o];
        #pragma unroll
        for (int mi = 0; mi < 4; ++mi) {
            int p = p0 + wr*64 + mi*16 + kq*4;
            f32x4 v = acc[mi][ni];
            float* op = out + ((size_t)(b*NP) + p)*NC + o;
            op[0]        = v[0] + bias;
            op[NC]       = v[1] + bias;
            op[2*NC]     = v[2] + bias;
            op[3*(size_t)NC] = v[3] + bias;
        }
    }
}

extern "C" void kernel_launch(void* const* d_in, const int* in_sizes, int n_in,
                              void* d_out, int out_size, void* d_ws, size_t ws_size,
                              hipStream_t stream)
{
    const float* x      = (const float*)d_in[0];
    const float* conv_w = (const float*)d_in[1];
    const float* conv_b = (const float*)d_in[2];
    const float* bn2g   = (const float*)d_in[3];
    const float* bn2b   = (const float*)d_in[4];
    const float* bn2m   = (const float*)d_in[5];
    const float* bn2v   = (const float*)d_in[6];
    const float* temp   = (const float*)d_in[7];
    const float* w1w    = (const float*)d_in[8];
    const float* w1b    = (const float*)d_in[9];
    const float* bnwg   = (const float*)d_in[10];
    const float* bnwb   = (const float*)d_in[11];
    const float* bnwm   = (const float*)d_in[12];
    const float* bnwv   = (const float*)d_in[13];
    const float* w2w    = (const float*)d_in[14];
    const float* w2b    = (const float*)d_in[15];
    const float* projw  = (const float*)d_in[16];
    const float* projb  = (const float*)d_in[17];
    float* out = (float*)d_out;

    char* ws = (char*)d_ws;
    // Head overlay region [0, 6,823,936):
    //   wB bf16 (2,359,296 B) during conv; nrm/Gpart/Ap/g1 reuse it afterwards.
    unsigned short* wB = (unsigned short*)(ws);
    float*  nrm   = (float*)(ws);
    float2* Gpart = (float2*)(ws + 8192);
    float2* Ap    = (float2*)(ws + 8192 + 4194304);
    float*  g1    = (float*)(ws + 8192 + 4194304 + 524288);   // [b][p][16] transposed, 2MB
    char* base = ws + 6823936;
    // conv region [base, +33.5MB): conv fp32 (dead after fft2_fwd), then outf2b bf16 (16.7MB)
    float*  conv  = (float*)(base);
    unsigned short* outf2b = (unsigned short*)(base);
    // f region [base+33.5MB, +67MB): xpad bf16 overlay (40.1MB, dead after conv);
    //   then split planes fRe (33.5MB) / fIm (33.5MB), live through k_ifft2_abs_gated.
    float* fRe = (float*)(base + 33554432);
    float* fIm = (float*)(base + 33554432 + 33554432);
    unsigned short* xpad = (unsigned short*)(base + 33554432);
    // Z region [base+100.6MB, +67MB): Z complex; after k_outf2 Z dead ->
    //   pwb bf16 (0.5MB) at base, Abf bf16 (33.5MB) at +4MB, outl2b bf16 (16.7MB) at +37.7MB
    char* zbase = base + 33554432 + 67108864;
    float2* Z     = (float2*)(zbase);
    unsigned short* pwb = (unsigned short*)(zbase);
    unsigned short* Abf = (unsigned short*)(zbase + 4194304);
    unsigned short* outl2b = (unsigned short*)(zbase + 37748736);
    // total workspace used: 174,596,096 bytes (unchanged)

    k_wconv<<<dim3(4608), 256, 0, stream>>>(conv_w, wB);
    k_xpad<<<dim3(9800), 256, 0, stream>>>(x, xpad);
    k_conv_mfma<<<dim3(32, 2, 8), 256, 0, stream>>>(xpad, wB, conv_b, bn2g, bn2b, bn2m, bn2v, conv);
    k_fft2_fwd<<<dim3(2048), 256, 0, stream>>>(conv, fRe, fIm, nrm);
    k_gram<<<dim3(8, 64), 256, 0, stream>>>(fRe, fIm, Gpart);
    k_attn<<<dim3(64), 256, 0, stream>>>(Gpart, nrm, temp, Ap);
    k_ifft_row4096<<<dim3(2048), 256, 0, stream>>>(fRe, fIm, Z);
    k_outf2<<<dim3(16, 64), 256, 0, stream>>>(Ap, Z, outf2b);
    k_g1<<<dim3(16, 8), 256, 0, stream>>>(fRe, w1w, w1b, bnwg, bnwb, bnwm, bnwv, g1);
    k_ifft2_abs_gated<<<dim3(2048), 256, 0, stream>>>(fRe, fIm, g1, w2w, w2b, outl2b);
    k_wproj<<<dim3(1024), 256, 0, stream>>>(projw, pwb);
    k_prep<<<dim3(64, 8, 8), 256, 0, stream>>>(outf2b, outl2b, x, Abf);
    k_projm<<<dim3(32, 4, 8), 256, 0, stream>>>(Abf, pwb, projb, out);
}

// Round 7
// 473.862 us; speedup vs baseline: 1.3710x; 1.1494x over previous
//
#include <hip/hip_runtime.h>

// Shapes (fixed by the problem)
#define NB 8
#define NC 512
#define ND 256
#define NP 4096
#define NHD 8
#define TWO_PI 6.2831853071795864f
#define FPITCH 65
#define HPAD 70
#define NSPL 16

typedef short bf16x8 __attribute__((ext_vector_type(8)));
typedef float f32x4 __attribute__((ext_vector_type(4)));

__device__ __forceinline__ unsigned short f2bf(float f) {
    unsigned u = __float_as_uint(f);
    u += 0x7FFFu + ((u >> 16) & 1u);
    return (unsigned short)(u >> 16);
}
__device__ __forceinline__ float bf2f(unsigned short u) {
    return __uint_as_float((unsigned)u << 16);
}

__device__ __forceinline__ void load_lds16(const void* g, void* l) {
    __builtin_amdgcn_global_load_lds((const __attribute__((address_space(1))) unsigned int*)g,
                                     (__attribute__((address_space(3))) unsigned int*)l, 16, 0, 0);
}

__device__ __forceinline__ float2 cmulf(float2 a, float2 b) {
    return make_float2(a.x*b.x - a.y*b.y, a.x*b.y + a.y*b.x);
}
__device__ __forceinline__ float2 caddf(float2 a, float2 b) { return make_float2(a.x+b.x, a.y+b.y); }
__device__ __forceinline__ float2 csubf(float2 a, float2 b) { return make_float2(a.x-b.x, a.y-b.y); }

// 8-point DFT in registers. S=-1 forward, S=+1 inverse (unscaled).
template<int S>
__device__ __forceinline__ void dft8(float2 v[8]) {
    float2 e0=v[0], e1=v[2], e2=v[4], e3=v[6];
    float2 o0=v[1], o1=v[3], o2=v[5], o3=v[7];
    float2 p0=caddf(e0,e2), p1=csubf(e0,e2), q0=caddf(e1,e3), q1=csubf(e1,e3);
    float2 q1r = make_float2(-(float)S*q1.y, (float)S*q1.x);
    float2 E0=caddf(p0,q0), E2=csubf(p0,q0), E1=caddf(p1,q1r), E3=csubf(p1,q1r);
    p0=caddf(o0,o2); p1=csubf(o0,o2); q0=caddf(o1,o3); q1=csubf(o1,o3);
    q1r = make_float2(-(float)S*q1.y, (float)S*q1.x);
    float2 O0=caddf(p0,q0), O2=csubf(p0,q0), O1=caddf(p1,q1r), O3=csubf(p1,q1r);
    const float r = 0.70710678118654752f;
    float2 w1 = make_float2(r, (float)S*r);
    float2 w2 = make_float2(0.f, (float)S);
    float2 w3 = make_float2(-r, (float)S*r);
    float2 t;
    t = O0;           v[0]=caddf(E0,t); v[4]=csubf(E0,t);
    t = cmulf(w1,O1); v[1]=caddf(E1,t); v[5]=csubf(E1,t);
    t = cmulf(w2,O2); v[2]=caddf(E2,t); v[6]=csubf(E2,t);
    t = cmulf(w3,O3); v[3]=caddf(E3,t); v[7]=csubf(E3,t);
}

// 64-pt transform along the contiguous axis of each of 64 rows in LDS planes.
template<int S, int MODE>
__device__ void fft64_rows(float* Re, float* Im, const float* twc, const float* tws,
                           int tid, float2* gout, float scale)
{
    int rb = tid & 31;
    int t8 = tid >> 5;
    for (int half = 0; half < 2; ++half) {
        int r = rb + 32*half;
        float2 v[8];
        __syncthreads();
        #pragma unroll
        for (int m = 0; m < 8; ++m) {
            int idx = r*FPITCH + 8*m + t8;
            v[m] = make_float2(Re[idx], Im[idx]);
        }
        dft8<S>(v);
        #pragma unroll
        for (int k1 = 1; k1 < 8; ++k1) {
            int mm = (t8*k1) & 63;
            v[k1] = cmulf(v[k1], make_float2(twc[mm], (float)S*tws[mm]));
        }
        __syncthreads();
        #pragma unroll
        for (int k1 = 0; k1 < 8; ++k1) {
            int idx = r*FPITCH + k1*8 + t8;
            Re[idx] = v[k1].x; Im[idx] = v[k1].y;
        }
        __syncthreads();
        float2 a[8];
        #pragma unroll
        for (int m = 0; m < 8; ++m) {
            int idx = r*FPITCH + t8*8 + m;
            a[m] = make_float2(Re[idx], Im[idx]);
        }
        dft8<S>(a);
        if (MODE == 0) {
            __syncthreads();
            #pragma unroll
            for (int k2 = 0; k2 < 8; ++k2) {
                int idx = r*FPITCH + t8 + 8*k2;
                Re[idx] = a[k2].x; Im[idx] = a[k2].y;
            }
        } else {
            #pragma unroll
            for (int k2 = 0; k2 < 8; ++k2) {
                int kq = t8 + 8*k2;
                gout[r + 64*kq] = make_float2(a[k2].x*scale, a[k2].y*scale);
            }
        }
    }
    __syncthreads();
}

// 64-pt transform along the vertical axis of each of 64 columns.
// MODE 0: in-place. MODE 1: in-place * mid-twiddle.
// MODE 2: split-plane out gre/gim (+|.|^2 partial into *ss). MODE 3: bf16 |.|*scale out.
template<int S, int MODE>
__device__ void fft64_cols(float* Re, float* Im, const float* twc, const float* tws,
                           int tid, float* gre, float* gim, unsigned short* goutr,
                           float scale, float* ss)
{
    int cb = tid & 31;
    int t8 = tid >> 5;
    for (int half = 0; half < 2; ++half) {
        int col = cb + 32*half;
        float2 v[8];
        __syncthreads();
        #pragma unroll
        for (int m = 0; m < 8; ++m) {
            int idx = (8*m + t8)*FPITCH + col;
            v[m] = make_float2(Re[idx], Im[idx]);
        }
        dft8<S>(v);
        #pragma unroll
        for (int k1 = 1; k1 < 8; ++k1) {
            int mm = (t8*k1) & 63;
            v[k1] = cmulf(v[k1], make_float2(twc[mm], (float)S*tws[mm]));
        }
        __syncthreads();
        #pragma unroll
        for (int k1 = 0; k1 < 8; ++k1) {
            int idx = (k1*8 + t8)*FPITCH + col;
            Re[idx] = v[k1].x; Im[idx] = v[k1].y;
        }
        __syncthreads();
        float2 a[8];
        #pragma unroll
        for (int m = 0; m < 8; ++m) {
            int idx = (t8*8 + m)*FPITCH + col;
            a[m] = make_float2(Re[idx], Im[idx]);
        }
        dft8<S>(a);
        if (MODE <= 1) {
            __syncthreads();
            #pragma unroll
            for (int k2 = 0; k2 < 8; ++k2) {
                int row = t8 + 8*k2;
                float2 rv = a[k2];
                if (MODE == 1) {
                    float sv, cv;
                    __sincosf((TWO_PI/4096.f) * (float)(row*col), &sv, &cv);
                    rv = cmulf(rv, make_float2(cv, (float)S*sv));
                }
                int idx = row*FPITCH + col;
                Re[idx] = rv.x; Im[idx] = rv.y;
            }
        } else if (MODE == 2) {
            #pragma unroll
            for (int k2 = 0; k2 < 8; ++k2) {
                int row = t8 + 8*k2;
                *ss += a[k2].x*a[k2].x + a[k2].y*a[k2].y;
                gre[row*64 + col] = a[k2].x*scale;
                gim[row*64 + col] = a[k2].y*scale;
            }
        } else {
            #pragma unroll
            for (int k2 = 0; k2 < 8; ++k2) {
                int row = t8 + 8*k2;
                goutr[row*64 + col] = f2bf(scale * sqrtf(a[k2].x*a[k2].x + a[k2].y*a[k2].y));
            }
        }
    }
    __syncthreads();
}

// conv weights (256,512,3,3) fp32 -> wB[t][o][i] bf16 (i contiguous = K-contiguous B rows)
__global__ __launch_bounds__(256) void k_wconv(const float* __restrict__ w, unsigned short* __restrict__ wB) {
    int idx = blockIdx.x*256 + threadIdx.x;
    if (idx >= 9*NC*ND) return;
    int i = idx & 511;
    int rest = idx >> 9;
    int o = rest & 255;
    int t = rest >> 8;
    wB[idx] = f2bf(w[(o*NC + i)*9 + t]);
}

// proj weights (512,512) fp32 -> bf16, same [o][c] layout
__global__ __launch_bounds__(256) void k_wproj(const float* __restrict__ w, unsigned short* __restrict__ wb) {
    int i = blockIdx.x*256 + threadIdx.x;
    wb[i] = f2bf(w[i]);
}

// x (b, 4096, 512) fp32 -> spatially padded bf16 xpad[b][hp][wp][c], hp/wp in [0,70)
__global__ __launch_bounds__(256) void k_xpad(const float* __restrict__ x, unsigned short* __restrict__ xpad) {
    int idx = blockIdx.x*256 + threadIdx.x;
    int c8 = idx & 63;
    int rest = idx >> 6;
    int wp = rest % HPAD;
    int rest2 = rest / HPAD;
    int hp = rest2 % HPAD;
    int b = rest2 / HPAD;
    int h = hp - 3, w = wp - 3;
    bf16x8 v = {0,0,0,0,0,0,0,0};
    if (((unsigned)h) < 64u && ((unsigned)w) < 64u) {
        const float* s = x + (((size_t)b*NP + h*64 + w)*NC + c8*8);
        float4 f0 = *(const float4*)(s);
        float4 f1 = *(const float4*)(s + 4);
        v[0]=(short)f2bf(f0.x); v[1]=(short)f2bf(f0.y); v[2]=(short)f2bf(f0.z); v[3]=(short)f2bf(f0.w);
        v[4]=(short)f2bf(f1.x); v[5]=(short)f2bf(f1.y); v[6]=(short)f2bf(f1.z); v[7]=(short)f2bf(f1.w);
    }
    *(bf16x8*)(xpad + ((size_t)(b*HPAD*HPAD) + hp*HPAD + wp)*NC + c8*8) = v;
}

// bf16 MFMA implicit-GEMM dilated conv (d=3,pad=3) + bias + BN + ReLU -> out[b][o][p] fp32
// R4-proven 2-phase double-buffer: K=64 chunks, one barrier per chunk, stage issued before compute.
// K-slot swizzle (verified bijective; conflicts 0): source slot c16^((r0>>1)&3), read slot kq^((ln>>1)&3).
__global__ __launch_bounds__(256, 2) void k_conv_mfma(
        const unsigned short* __restrict__ xpad, const unsigned short* __restrict__ wB,
        const float* __restrict__ cbias, const float* __restrict__ bg, const float* __restrict__ bb,
        const float* __restrict__ bm, const float* __restrict__ bv, float* __restrict__ out)
{
    // [buf][ks*4096 + row*32 + slot*8] ; 2 bufs x (A,B) x 16 KB = 64 KB
    __shared__ short Als[2][8192];
    __shared__ short Bls[2][8192];
    int tid = threadIdx.x;
    int p0 = blockIdx.x * 128;
    int o0 = blockIdx.y * 128;
    int b  = blockIdx.z;
    int lane = tid & 63;
    int wv = tid >> 6;
    int wr = wv >> 1, wc = wv & 1;
    int ln = lane & 15, kq = lane >> 4;
    int kqs = kq ^ ((ln >> 1) & 3);          // swizzled K-slot (read side)

    f32x4 acc[4][4];
    #pragma unroll
    for (int i = 0; i < 4; ++i)
        #pragma unroll
        for (int j = 0; j < 4; ++j)
            acc[i][j] = (f32x4){0.f, 0.f, 0.f, 0.f};

    int r0 = tid >> 2;
    int c16 = tid & 3;
    int c16s = c16 ^ ((r0 >> 1) & 3);        // swizzled K-slot (global source side)
    int pA0 = p0 + r0, pA1 = p0 + 64 + r0;
    int h0 = pA0 >> 6, w0c = pA0 & 63;
    int h1 = pA1 >> 6, w1c = pA1 & 63;
    const unsigned short* xb = xpad + (size_t)b*(HPAD*HPAD)*NC;
    int oB0 = o0 + r0, oB1 = o0 + 64 + r0;
    short* AlsD0 = &Als[0][tid*8];
    short* AlsD1 = &Als[0][2048 + tid*8];
    short* BlsD0 = &Bls[0][tid*8];
    short* BlsD1 = &Bls[0][2048 + tid*8];

    // Stage K-chunk `it` (of 72 = 9 taps x 8 chunks of K=64) into buffer it&1.
    auto stage = [&](int it) {
        int buf = it & 1;
        int tap = it >> 3;
        int kc  = (it & 7) << 6;
        int q   = (tap*11) >> 5;             // tap/3 for tap in [0,9)
        int dh  = q*3, dw = (tap - q*3)*3;
        const unsigned short* a0 = xb + ((size_t)((h0 + dh)*HPAD + (w0c + dw)))*NC + kc + c16s*8;
        const unsigned short* a1 = xb + ((size_t)((h1 + dh)*HPAD + (w1c + dw)))*NC + kc + c16s*8;
        const unsigned short* b0 = wB + ((size_t)(tap*ND + oB0))*NC + kc + c16s*8;
        const unsigned short* b1 = wB + ((size_t)(tap*ND + oB1))*NC + kc + c16s*8;
        int bo = buf ? 8192 : 0;
        load_lds16(a0,      AlsD0 + bo);          // ks=0 rows 0..63
        load_lds16(a1,      AlsD1 + bo);          // ks=0 rows 64..127
        load_lds16(a0 + 32, AlsD0 + bo + 4096);   // ks=1 rows 0..63
        load_lds16(a1 + 32, AlsD1 + bo + 4096);   // ks=1 rows 64..127
        load_lds16(b0,      BlsD0 + bo);
        load_lds16(b1,      BlsD1 + bo);
        load_lds16(b0 + 32, BlsD0 + bo + 4096);
        load_lds16(b1 + 32, BlsD1 + bo + 4096);
    };

    stage(0);
    #pragma unroll 2
    for (int it = 0; it < 72; ++it) {
        int buf = it & 1;
        // my 8 loads for buf (issued last iteration / prologue) must be complete
        asm volatile("s_waitcnt vmcnt(0)" ::: "memory");
        __builtin_amdgcn_s_barrier();          // all waves: buf ready; all prev ds_reads done
        __builtin_amdgcn_sched_barrier(0);     // no LDS access motion across the barrier
        if (it + 1 < 72) stage(it + 1);        // overlap with compute below
        #pragma unroll
        for (int ks = 0; ks < 2; ++ks) {
            bf16x8 af[4], bfr[4];
            #pragma unroll
            for (int mi = 0; mi < 4; ++mi)
                af[mi] = *(const bf16x8*)&Als[buf][ks*4096 + (wr*64 + mi*16 + ln)*32 + kqs*8];
            #pragma unroll
            for (int ni = 0; ni < 4; ++ni)
                bfr[ni] = *(const bf16x8*)&Bls[buf][ks*4096 + (wc*64 + ni*16 + ln)*32 + kqs*8];
            #pragma unroll
            for (int mi = 0; mi < 4; ++mi)
                #pragma unroll
                for (int ni = 0; ni < 4; ++ni)
                    acc[mi][ni] = __builtin_amdgcn_mfma_f32_16x16x32_bf16(af[mi], bfr[ni], acc[mi][ni], 0, 0, 0);
        }
    }

    #pragma unroll
    for (int ni = 0; ni < 4; ++ni) {
        int o = o0 + wc*64 + ni*16 + ln;
        float inv = bg[o] * rsqrtf(bv[o] + 1e-5f);
        float beta = bb[o] - bm[o]*inv;
        float cbo = cbias[o];
        #pragma unroll
        for (int mi = 0; mi < 4; ++mi) {
            int p = p0 + wr*64 + mi*16 + kq*4;
            f32x4 v = acc[mi][ni];
            float4 rv;
            rv.x = fmaxf((v[0] + cbo)*inv + beta, 0.f);
            rv.y = fmaxf((v[1] + cbo)*inv + beta, 0.f);
            rv.z = fmaxf((v[2] + cbo)*inv + beta, 0.f);
            rv.w = fmaxf((v[3] + cbo)*inv + beta, 0.f);
            *(float4*)(out + ((size_t)(b*ND + o))*NP + p) = rv;
        }
    }
}

// fft2 (forward) of one 64x64 real image -> split planes fRe/fIm; also writes per-image L2 norm
__global__ __launch_bounds__(256) void k_fft2_fwd(const float* __restrict__ src, float* __restrict__ fRe,
                                                  float* __restrict__ fIm, float* __restrict__ nrm) {
    __shared__ float Re[64*FPITCH];
    __shared__ float Im[64*FPITCH];
    __shared__ float twc[64], tws[64];
    __shared__ float part[4];
    int tid = threadIdx.x;
    size_t img = blockIdx.x;
    const float* s = src + img*4096;
    if (tid < 64) { float sv, cv; __sincosf(TWO_PI*(float)tid/64.f, &sv, &cv); twc[tid]=cv; tws[tid]=sv; }
    for (int i = tid; i < 4096; i += 256) {
        Re[(i>>6)*FPITCH + (i&63)] = s[i];
        Im[(i>>6)*FPITCH + (i&63)] = 0.f;
    }
    fft64_rows<-1,0>(Re, Im, twc, tws, tid, nullptr, 1.f);
    float ssl = 0.f;
    fft64_cols<-1,2>(Re, Im, twc, tws, tid, fRe + img*4096, fIm + img*4096, nullptr, 1.f, &ssl);
    #pragma unroll
    for (int off = 32; off > 0; off >>= 1) ssl += __shfl_down(ssl, off, 64);
    if ((tid & 63) == 0) part[tid >> 6] = ssl;
    __syncthreads();
    if (tid == 0) nrm[img] = fmaxf(sqrtf(part[0]+part[1]+part[2]+part[3]), 1e-12f);
}

// 4096-pt inverse FFT of one f-row (Cooley-Tukey 64x64): Z[k1+64*k2], includes 1/4096
__global__ __launch_bounds__(256) void k_ifft_row4096(const float* __restrict__ fRe,
        const float* __restrict__ fIm, float2* __restrict__ Z) {
    __shared__ float Re[64*FPITCH];
    __shared__ float Im[64*FPITCH];
    __shared__ float twc[64], tws[64];
    int tid = threadIdx.x;
    size_t img = blockIdx.x;
    const float* sr = fRe + img*4096;
    const float* si = fIm + img*4096;
    if (tid < 64) { float sv, cv; __sincosf(TWO_PI*(float)tid/64.f, &sv, &cv); twc[tid]=cv; tws[tid]=sv; }
    for (int i = tid; i < 4096; i += 256) {
        Re[(i>>6)*FPITCH + (i&63)] = sr[i];
        Im[(i>>6)*FPITCH + (i&63)] = si[i];
    }
    fft64_cols<1,1>(Re, Im, twc, tws, tid, nullptr, nullptr, nullptr, 1.f, nullptr);
    fft64_rows<1,1>(Re, Im, twc, tws, tid, Z + img*4096, 1.f/4096.f);
}

// gated ifft2: computes gate = sigmoid(w2 @ g1 + b2) on the fly (g1 transposed [b][p][16],
// contiguous float4 reads), multiplies f, ifft2, abs * 1/4096 -> bf16 [c][p].
__global__ __launch_bounds__(256) void k_ifft2_abs_gated(const float* __restrict__ fRe,
        const float* __restrict__ fIm, const float* __restrict__ g1, const float* __restrict__ w2,
        const float* __restrict__ w2b, unsigned short* __restrict__ out) {
    __shared__ float Re[64*FPITCH];
    __shared__ float Im[64*FPITCH];
    __shared__ float twc[64], tws[64];
    int tid = threadIdx.x;
    size_t img = blockIdx.x;
    int b = (int)(img >> 8), ch = (int)(img & 255);
    const float* sr = fRe + img*4096;
    const float* si = fIm + img*4096;
    const float* g1b = g1 + (size_t)b*NP*16;
    float4 wv0 = *(const float4*)(w2 + ch*16);
    float4 wv1 = *(const float4*)(w2 + ch*16 + 4);
    float4 wv2 = *(const float4*)(w2 + ch*16 + 8);
    float4 wv3 = *(const float4*)(w2 + ch*16 + 12);
    float w2bias = w2b[ch];
    if (tid < 64) { float sv, cv; __sincosf(TWO_PI*(float)tid/64.f, &sv, &cv); twc[tid]=cv; tws[tid]=sv; }
    for (int i = tid; i < 4096; i += 256) {
        const float* gp = g1b + (size_t)i*16;
        float4 q0 = *(const float4*)(gp);
        float4 q1 = *(const float4*)(gp + 4);
        float4 q2 = *(const float4*)(gp + 8);
        float4 q3 = *(const float4*)(gp + 12);
        float acc = w2bias
            + wv0.x*q0.x + wv0.y*q0.y + wv0.z*q0.z + wv0.w*q0.w
            + wv1.x*q1.x + wv1.y*q1.y + wv1.z*q1.z + wv1.w*q1.w
            + wv2.x*q2.x + wv2.y*q2.y + wv2.z*q2.z + wv2.w*q2.w
            + wv3.x*q3.x + wv3.y*q3.y + wv3.z*q3.z + wv3.w*q3.w;
        float gate = 1.f / (1.f + __expf(-acc));
        Re[(i>>6)*FPITCH + (i&63)] = gate*sr[i];
        Im[(i>>6)*FPITCH + (i&63)] = gate*si[i];
    }
    fft64_rows<1,0>(Re, Im, twc, tws, tid, nullptr, 1.f);
    fft64_cols<1,3>(Re, Im, twc, tws, tid, nullptr, nullptr, out + img*4096, 1.f/4096.f, nullptr);
}

// G[c][d] = sum_n f_c[n]*f_d[n] (complex, no conj) via bf16 hi+lo split MFMA.
// Each fp32 -> (hi,lo) bf16 pair (K doubled); MFMA fp32 accumulator makes the product
// exact to ~2^-16 relative. Re = FrFr - FiFi, Im = FrFi + FiFr (4 accumulators).
// Grid (NSPL=16 n-splits, 64 bh); 4 waves = 2x2 quadrants of the 32x32 output.
__global__ __launch_bounds__(256) void k_gram(const float* __restrict__ fRe, const float* __restrict__ fIm,
                                              float2* __restrict__ Gpart) {
    __shared__ short FrP[32*136];   // [row][K2=128], row padded to 136 (68 words -> 2-way max)
    __shared__ short FiP[32*136];
    int split = blockIdx.x;
    int bh = blockIdx.y;
    int b = bh >> 3, h = bh & 7;
    int tid = threadIdx.x;
    int lane = tid & 63;
    int wv = tid >> 6;
    int cr = (wv >> 1) * 16, dc = (wv & 1) * 16;
    int ln = lane & 15, kq = lane >> 4;
    int r = tid >> 3;          // staging row 0..31
    int g = tid & 7;           // staging n-octet
    const float* fRb = fRe + ((size_t)(b*ND + h*32) + r)*NP + split*256 + g*8;
    const float* fIb = fIm + ((size_t)(b*ND + h*32) + r)*NP + split*256 + g*8;
    short* wFr = FrP + r*136 + g*16;
    short* wFi = FiP + r*136 + g*16;

    f32x4 arr = {0.f,0.f,0.f,0.f}, aii = {0.f,0.f,0.f,0.f};
    f32x4 ari = {0.f,0.f,0.f,0.f}, air = {0.f,0.f,0.f,0.f};

    for (int chunk = 0; chunk < 4; ++chunk) {       // 4 chunks x 64 n = 256 n per split
        float4 v0 = *(const float4*)(fRb + chunk*64);
        float4 v1 = *(const float4*)(fRb + chunk*64 + 4);
        float4 w0 = *(const float4*)(fIb + chunk*64);
        float4 w1 = *(const float4*)(fIb + chunk*64 + 4);
        __syncthreads();                            // previous chunk's MFMA reads done
        float vr[8] = {v0.x,v0.y,v0.z,v0.w,v1.x,v1.y,v1.z,v1.w};
        float vi[8] = {w0.x,w0.y,w0.z,w0.w,w1.x,w1.y,w1.z,w1.w};
        bf16x8 r0v, r1v, i0v, i1v;
        #pragma unroll
        for (int j = 0; j < 4; ++j) {
            unsigned short hb;
            hb = f2bf(vr[j]);   r0v[2*j] = (short)hb; r0v[2*j+1] = (short)f2bf(vr[j]   - bf2f(hb));
            hb = f2bf(vr[4+j]); r1v[2*j] = (short)hb; r1v[2*j+1] = (short)f2bf(vr[4+j] - bf2f(hb));
            hb = f2bf(vi[j]);   i0v[2*j] = (short)hb; i0v[2*j+1] = (short)f2bf(vi[j]   - bf2f(hb));
            hb = f2bf(vi[4+j]); i1v[2*j] = (short)hb; i1v[2*j+1] = (short)f2bf(vi[4+j] - bf2f(hb));
        }
        *(bf16x8*)(wFr)     = r0v;
        *(bf16x8*)(wFr + 8) = r1v;
        *(bf16x8*)(wFi)     = i0v;
        *(bf16x8*)(wFi + 8) = i1v;
        __syncthreads();
        const short* aRp = FrP + (cr + ln)*136;
        const short* aIp = FiP + (cr + ln)*136;
        const short* bRp = FrP + (dc + ln)*136;
        const short* bIp = FiP + (dc + ln)*136;
        #pragma unroll
        for (int s = 0; s < 4; ++s) {               // K2 = 128 -> 4 mfma steps of K=32
            int ko = s*32 + kq*8;
            bf16x8 aR = *(const bf16x8*)(aRp + ko);
            bf16x8 aI = *(const bf16x8*)(aIp + ko);
            bf16x8 bR = *(const bf16x8*)(bRp + ko);
            bf16x8 bI = *(const bf16x8*)(bIp + ko);
            arr = __builtin_amdgcn_mfma_f32_16x16x32_bf16(aR, bR, arr, 0, 0, 0);
            aii = __builtin_amdgcn_mfma_f32_16x16x32_bf16(aI, bI, aii, 0, 0, 0);
            ari = __builtin_amdgcn_mfma_f32_16x16x32_bf16(aR, bI, ari, 0, 0, 0);
            air = __builtin_amdgcn_mfma_f32_16x16x32_bf16(aI, bR, air, 0, 0, 0);
        }
    }
    // C/D layout: col = ln (d), row = kq*4 + j (c) within the wave's 16x16 quadrant.
    float2* gout = Gpart + ((size_t)bh*NSPL + split)*1024;
    #pragma unroll
    for (int j = 0; j < 4; ++j) {
        int c = cr + kq*4 + j;
        int d = dc + ln;
        gout[c*32 + d] = make_float2(arr[j] - aii[j], ari[j] + air[j]);
    }
}

// reduce partials, normalize, *temp, dual softmax, then A' = (1/32) W32+ @ S
__global__ __launch_bounds__(256) void k_attn(const float2* __restrict__ Gpart, const float* __restrict__ nrm,
                                              const float* __restrict__ temp, float2* __restrict__ Ap) {
    int bh = blockIdx.x;
    int b = bh >> 3, h = bh & 7;
    int tid = threadIdx.x;
    __shared__ float2 Sm[32][33];
    __shared__ float twc[32], tws[32];
    if (tid < 32) { float sv, cv; __sincosf(TWO_PI*(float)tid/32.f, &sv, &cv); twc[tid]=cv; tws[tid]=sv; }
    const float* nb = nrm + b*ND + h*32;
    float tv = temp[h];
    const float2* gp = Gpart + (size_t)bh*NSPL*1024;
    #pragma unroll
    for (int j = 0; j < 4; ++j) {
        int e = tid*4 + j;
        int c = e >> 5, d = e & 31;
        float2 s = make_float2(0.f, 0.f);
        for (int sp = 0; sp < NSPL; ++sp) { float2 v = gp[sp*1024 + e]; s.x += v.x; s.y += v.y; }
        float sc = tv / (nb[c]*nb[d]);
        Sm[c][d] = make_float2(s.x*sc, s.y*sc);
    }
    __syncthreads();
    if (tid < 32) {
        float mr = -1e30f, mi = -1e30f;
        for (int d = 0; d < 32; ++d) { float2 v = Sm[tid][d]; mr = fmaxf(mr, v.x); mi = fmaxf(mi, v.y); }
        float sr = 0.f, si = 0.f;
        for (int d = 0; d < 32; ++d) {
            float2 v = Sm[tid][d];
            v.x = __expf(v.x - mr); v.y = __expf(v.y - mi);
            sr += v.x; si += v.y;
            Sm[tid][d] = v;
        }
        float ir = 1.f/sr, ii = 1.f/si;
        for (int d = 0; d < 32; ++d) { float2 v = Sm[tid][d]; Sm[tid][d] = make_float2(v.x*ir, v.y*ii); }
    }
    __syncthreads();
    float2* ap = Ap + (size_t)bh*1024;
    #pragma unroll
    for (int j = 0; j < 4; ++j) {
        int e = tid*4 + j;
        int k = e >> 5, d = e & 31;
        float2 acc = make_float2(0.f, 0.f);
        for (int c = 0; c < 32; ++c) {
            int m = (c*k) & 31;
            float2 w = make_float2(twc[m], tws[m]);
            float2 v = Sm[c][d];
            acc.x += w.x*v.x - w.y*v.y;
            acc.y += w.x*v.y + w.y*v.x;
        }
        ap[e] = make_float2(acc.x*(1.f/32.f), acc.y*(1.f/32.f));
    }
}

// out_f2 = | A' @ Z |  per (b,head) -> bf16 [c][p]
__global__ __launch_bounds__(256) void k_outf2(const float2* __restrict__ Ap, const float2* __restrict__ Z,
                                               unsigned short* __restrict__ outf2) {
    int nc = blockIdx.x, bh = blockIdx.y;
    int b = bh >> 3, h = bh & 7;
    int tid = threadIdx.x;
    __shared__ float2 A[32][32];
    const float2* ap = Ap + (size_t)bh*1024;
    for (int i = tid; i < 1024; i += 256) A[i>>5][i&31] = ap[i];
    __syncthreads();
    int n = nc*256 + tid;
    const float2* zb = Z + ((size_t)(b*ND + h*32))*NP + n;
    float2 z[32];
    #pragma unroll
    for (int d = 0; d < 32; ++d) z[d] = zb[(size_t)d*NP];
    unsigned short* ob = outf2 + ((size_t)(b*ND + h*32))*NP + n;
    for (int k = 0; k < 32; ++k) {
        float2 acc = make_float2(0.f, 0.f);
        #pragma unroll
        for (int d = 0; d < 32; ++d) {
            float2 a = A[k][d], zz = z[d];
            acc.x += a.x*zz.x - a.y*zz.y;
            acc.y += a.x*zz.y + a.y*zz.x;
        }
        ob[(size_t)k*NP] = f2bf(sqrtf(acc.x*acc.x + acc.y*acc.y));
    }
}

// g1 = relu(BN(w1 @ Re(f)))  -- reads the compact fRe plane; writes TRANSPOSED [b][p][16]
__global__ __launch_bounds__(256) void k_g1(const float* __restrict__ fRe, const float* __restrict__ w1,
        const float* __restrict__ w1b, const float* __restrict__ gg, const float* __restrict__ gb,
        const float* __restrict__ gm, const float* __restrict__ gv, float* __restrict__ g1)
{
    int pc = blockIdx.x, b = blockIdx.y;
    int tid = threadIdx.x;
    __shared__ float w1s[16*256];
    for (int i = tid; i < 4096; i += 256) w1s[i] = w1[i];
    __syncthreads();
    int p = pc*256 + tid;
    const float* fb = fRe + (size_t)b*ND*NP + p;
    float acc[16];
    #pragma unroll
    for (int j = 0; j < 16; ++j) acc[j] = 0.f;
    for (int i = 0; i < 256; ++i) {
        float v = fb[(size_t)i*NP];
        #pragma unroll
        for (int j = 0; j < 16; ++j) acc[j] += w1s[j*256 + i] * v;
    }
    float* go = g1 + ((size_t)b*NP + p)*16;
    float4 o4[4];
    #pragma unroll
    for (int j = 0; j < 16; ++j) {
        float inv = gg[j]*rsqrtf(gv[j] + 1e-5f);
        float val = (acc[j] + w1b[j])*inv + (gb[j] - gm[j]*inv);
        ((float*)o4)[j] = fmaxf(val, 0.f);
    }
    *(float4*)(go)      = o4[0];
    *(float4*)(go + 4)  = o4[1];
    *(float4*)(go + 8)  = o4[2];
    *(float4*)(go + 12) = o4[3];
}

// A[b][p][c] bf16 = cat(outf2b,outl2b)[c][p] + x[b][p][c]
__global__ __launch_bounds__(256) void k_prep(const unsigned short* __restrict__ outf2b,
        const unsigned short* __restrict__ outl2b, const float* __restrict__ x,
        unsigned short* __restrict__ A)
{
    int tid = threadIdx.x;
    int p = blockIdx.x*64 + (tid >> 2);
    int cs = blockIdx.y*64 + (tid & 3)*16;
    int b  = blockIdx.z;
    const unsigned short* src = (cs < ND) ? (outf2b + ((size_t)(b*ND) + cs)*NP + p)
                                          : (outl2b + ((size_t)(b*ND) + (cs - ND))*NP + p);
    float av[16];
    #pragma unroll
    for (int j = 0; j < 16; ++j) av[j] = bf2f(src[(size_t)j*NP]);
    const float* xp = x + ((size_t)(b*NP) + p)*NC + cs;
    #pragma unroll
    for (int j = 0; j < 4; ++j) {
        float4 xv = *(const float4*)(xp + j*4);
        av[j*4+0] += xv.x; av[j*4+1] += xv.y; av[j*4+2] += xv.z; av[j*4+3] += xv.w;
    }
    bf16x8 v0, v1;
    #pragma unroll
    for (int j = 0; j < 8; ++j) { v0[j] = (short)f2bf(av[j]); v1[j] = (short)f2bf(av[8+j]); }
    unsigned short* ap = A + ((size_t)(b*NP) + p)*NC + cs;
    *(bf16x8*)(ap) = v0;
    *(bf16x8*)(ap + 8) = v1;
}

// bf16 MFMA proj GEMM: out[b][p][o] = A[b][p][:] . pw[o][:] + pb[o]
// R4-proven 2-phase double-buffer + K-slot swizzle.
__global__ __launch_bounds__(256, 2) void k_projm(
        const unsigned short* __restrict__ A, const unsigned short* __restrict__ Bw,
        const float* __restrict__ pb, float* __restrict__ out)
{
    __shared__ short Als[2][8192];
    __shared__ short Bls[2][8192];
    int tid = threadIdx.x;
    int p0 = blockIdx.x * 128;
    int o0 = blockIdx.y * 128;
    int b  = blockIdx.z;
    int lane = tid & 63;
    int wv = tid >> 6;
    int wr = wv >> 1, wc = wv & 1;
    int ln = lane & 15, kq = lane >> 4;
    int kqs = kq ^ ((ln >> 1) & 3);

    f32x4 acc[4][4];
    #pragma unroll
    for (int i = 0; i < 4; ++i)
        #pragma unroll
        for (int j = 0; j < 4; ++j)
            acc[i][j] = (f32x4){0.f, 0.f, 0.f, 0.f};

    int r0 = tid >> 2;
    int c16 = tid & 3;
    int c16s = c16 ^ ((r0 >> 1) & 3);
    const unsigned short* ga0 = A + ((size_t)(b*NP) + p0 + r0)*NC + c16s*8;
    const unsigned short* ga1 = A + ((size_t)(b*NP) + p0 + 64 + r0)*NC + c16s*8;
    const unsigned short* gb0 = Bw + (size_t)(o0 + r0)*NC + c16s*8;
    const unsigned short* gb1 = Bw + (size_t)(o0 + 64 + r0)*NC + c16s*8;
    short* AlsD0 = &Als[0][tid*8];
    short* AlsD1 = &Als[0][2048 + tid*8];
    short* BlsD0 = &Bls[0][tid*8];
    short* BlsD1 = &Bls[0][2048 + tid*8];

    auto stage = [&](int it) {
        int buf = it & 1;
        int kc = it << 6;
        int bo = buf ? 8192 : 0;
        load_lds16(ga0 + kc,      AlsD0 + bo);
        load_lds16(ga1 + kc,      AlsD1 + bo);
        load_lds16(ga0 + kc + 32, AlsD0 + bo + 4096);
        load_lds16(ga1 + kc + 32, AlsD1 + bo + 4096);
        load_lds16(gb0 + kc,      BlsD0 + bo);
        load_lds16(gb1 + kc,      BlsD1 + bo);
        load_lds16(gb0 + kc + 32, BlsD0 + bo + 4096);
        load_lds16(gb1 + kc + 32, BlsD1 + bo + 4096);
    };

    stage(0);
    #pragma unroll 2
    for (int it = 0; it < 8; ++it) {
        int buf = it & 1;
        asm volatile("s_waitcnt vmcnt(0)" ::: "memory");
        __builtin_amdgcn_s_barrier();
        __builtin_amdgcn_sched_barrier(0);
        if (it + 1 < 8) stage(it + 1);
        #pragma unroll
        for (int ks = 0; ks < 2; ++ks) {
            bf16x8 af[4], bfr[4];
            #pragma unroll
            for (int mi = 0; mi < 4; ++mi)
                af[mi] = *(const bf16x8*)&Als[buf][ks*4096 + (wr*64 + mi*16 + ln)*32 + kqs*8];
            #pragma unroll
            for (int ni = 0; ni < 4; ++ni)
                bfr[ni] = *(const bf16x8*)&Bls[buf][ks*4096 + (wc*64 + ni*16 + ln)*32 + kqs*8];
            #pragma unroll
            for (int mi = 0; mi < 4; ++mi)
                #pragma unroll
                for (int ni = 0; ni < 4; ++ni)
                    acc[mi][ni] = __builtin_amdgcn_mfma_f32_16x16x32_bf16(af[mi], bfr[ni], acc[mi][ni], 0, 0, 0);
        }
    }

    // C/D: col(ln)=o, row(kq*4+reg)=p. 16 lanes x 4B consecutive in o => full 64B lines.
    #pragma unroll
    for (int ni = 0; ni < 4; ++ni) {
        int o = o0 + wc*64 + ni*16 + ln;
        float bias = pb[o];
        #pragma unroll
        for (int mi = 0; mi < 4; ++mi) {
            int p = p0 + wr*64 + mi*16 + kq*4;
            f32x4 v = acc[mi][ni];
            float* op = out + ((size_t)(b*NP) + p)*NC + o;
            op[0]        = v[0] + bias;
            op[NC]       = v[1] + bias;
            op[2*NC]     = v[2] + bias;
            op[3*(size_t)NC] = v[3] + bias;
        }
    }
}

extern "C" void kernel_launch(void* const* d_in, const int* in_sizes, int n_in,
                              void* d_out, int out_size, void* d_ws, size_t ws_size,
                              hipStream_t stream)
{
    const float* x      = (const float*)d_in[0];
    const float* conv_w = (const float*)d_in[1];
    const float* conv_b = (const float*)d_in[2];
    const float* bn2g   = (const float*)d_in[3];
    const float* bn2b   = (const float*)d_in[4];
    const float* bn2m   = (const float*)d_in[5];
    const float* bn2v   = (const float*)d_in[6];
    const float* temp   = (const float*)d_in[7];
    const float* w1w    = (const float*)d_in[8];
    const float* w1b    = (const float*)d_in[9];
    const float* bnwg   = (const float*)d_in[10];
    const float* bnwb   = (const float*)d_in[11];
    const float* bnwm   = (const float*)d_in[12];
    const float* bnwv   = (const float*)d_in[13];
    const float* w2w    = (const float*)d_in[14];
    const float* w2b    = (const float*)d_in[15];
    const float* projw  = (const float*)d_in[16];
    const float* projb  = (const float*)d_in[17];
    float* out = (float*)d_out;

    char* ws = (char*)d_ws;
    // Head overlay region [0, 6,823,936):
    //   wB bf16 (2,359,296 B) during conv; nrm/Ap/g1 reuse it afterwards.
    unsigned short* wB = (unsigned short*)(ws);
    float*  nrm   = (float*)(ws);
    float2* Ap    = (float2*)(ws + 8192 + 4194304);
    float*  g1    = (float*)(ws + 8192 + 4194304 + 524288);   // [b][p][16] transposed, 2MB
    char* base = ws + 6823936;
    // conv region [base, +33.5MB): conv fp32 (dead after fft2_fwd), then outf2b bf16 (16.7MB)
    float*  conv  = (float*)(base);
    unsigned short* outf2b = (unsigned short*)(base);
    // f region [base+33.5MB, +67MB): xpad bf16 overlay (40.1MB, dead after conv);
    //   then split planes fRe (33.5MB) / fIm (33.5MB), live through k_ifft2_abs_gated.
    float* fRe = (float*)(base + 33554432);
    float* fIm = (float*)(base + 33554432 + 33554432);
    unsigned short* xpad = (unsigned short*)(base + 33554432);
    // Z region [base+100.6MB, +67MB): Gpart (8MB, gram->attn, dead before Z written);
    //   then Z complex; after k_outf2 Z dead -> pwb bf16 (0.5MB) at base, Abf bf16 (33.5MB)
    //   at +4MB, outl2b bf16 (16.7MB) at +37.7MB
    char* zbase = base + 33554432 + 67108864;
    float2* Gpart = (float2*)(zbase);     // 64 bh x NSPL x 1024 float2 = 8 MB
    float2* Z     = (float2*)(zbase);
    unsigned short* pwb = (unsigned short*)(zbase);
    unsigned short* Abf = (unsigned short*)(zbase + 4194304);
    unsigned short* outl2b = (unsigned short*)(zbase + 37748736);
    // total workspace used: 174,596,096 bytes (unchanged)

    k_wconv<<<dim3(4608), 256, 0, stream>>>(conv_w, wB);
    k_xpad<<<dim3(9800), 256, 0, stream>>>(x, xpad);
    k_conv_mfma<<<dim3(32, 2, 8), 256, 0, stream>>>(xpad, wB, conv_b, bn2g, bn2b, bn2m, bn2v, conv);
    k_fft2_fwd<<<dim3(2048), 256, 0, stream>>>(conv, fRe, fIm, nrm);
    k_gram<<<dim3(NSPL, 64), 256, 0, stream>>>(fRe, fIm, Gpart);
    k_attn<<<dim3(64), 256, 0, stream>>>(Gpart, nrm, temp, Ap);
    k_ifft_row4096<<<dim3(2048), 256, 0, stream>>>(fRe, fIm, Z);
    k_outf2<<<dim3(16, 64), 256, 0, stream>>>(Ap, Z, outf2b);
    k_g1<<<dim3(16, 8), 256, 0, stream>>>(fRe, w1w, w1b, bnwg, bnwb, bnwm, bnwv, g1);
    k_ifft2_abs_gated<<<dim3(2048), 256, 0, stream>>>(fRe, fIm, g1, w2w, w2b, outl2b);
    k_wproj<<<dim3(1024), 256, 0, stream>>>(projw, pwb);
    k_prep<<<dim3(64, 8, 8), 256, 0, stream>>>(outf2b, outl2b, x, Abf);
    k_projm<<<dim3(32, 4, 8), 256, 0, stream>>>(Abf, pwb, projb, out);
}

// Round 8
// 469.696 us; speedup vs baseline: 1.3832x; 1.0089x over previous
//
#include <hip/hip_runtime.h>

// Shapes (fixed by the problem)
#define NB 8
#define NC 512
#define ND 256
#define NP 4096
#define NHD 8
#define TWO_PI 6.2831853071795864f
#define FPITCH 65
#define HPAD 70
#define NSPL 16

typedef short bf16x8 __attribute__((ext_vector_type(8)));
typedef float f32x4 __attribute__((ext_vector_type(4)));

__device__ __forceinline__ unsigned short f2bf(float f) {
    unsigned u = __float_as_uint(f);
    u += 0x7FFFu + ((u >> 16) & 1u);
    return (unsigned short)(u >> 16);
}
__device__ __forceinline__ float bf2f(unsigned short u) {
    return __uint_as_float((unsigned)u << 16);
}

__device__ __forceinline__ void load_lds16(const void* g, void* l) {
    __builtin_amdgcn_global_load_lds((const __attribute__((address_space(1))) unsigned int*)g,
                                     (__attribute__((address_space(3))) unsigned int*)l, 16, 0, 0);
}

__device__ __forceinline__ float2 cmulf(float2 a, float2 b) {
    return make_float2(a.x*b.x - a.y*b.y, a.x*b.y + a.y*b.x);
}
__device__ __forceinline__ float2 caddf(float2 a, float2 b) { return make_float2(a.x+b.x, a.y+b.y); }
__device__ __forceinline__ float2 csubf(float2 a, float2 b) { return make_float2(a.x-b.x, a.y-b.y); }

// 8-point DFT in registers. S=-1 forward, S=+1 inverse (unscaled).
template<int S>
__device__ __forceinline__ void dft8(float2 v[8]) {
    float2 e0=v[0], e1=v[2], e2=v[4], e3=v[6];
    float2 o0=v[1], o1=v[3], o2=v[5], o3=v[7];
    float2 p0=caddf(e0,e2), p1=csubf(e0,e2), q0=caddf(e1,e3), q1=csubf(e1,e3);
    float2 q1r = make_float2(-(float)S*q1.y, (float)S*q1.x);
    float2 E0=caddf(p0,q0), E2=csubf(p0,q0), E1=caddf(p1,q1r), E3=csubf(p1,q1r);
    p0=caddf(o0,o2); p1=csubf(o0,o2); q0=caddf(o1,o3); q1=csubf(o1,o3);
    q1r = make_float2(-(float)S*q1.y, (float)S*q1.x);
    float2 O0=caddf(p0,q0), O2=csubf(p0,q0), O1=caddf(p1,q1r), O3=csubf(p1,q1r);
    const float r = 0.70710678118654752f;
    float2 w1 = make_float2(r, (float)S*r);
    float2 w2 = make_float2(0.f, (float)S);
    float2 w3 = make_float2(-r, (float)S*r);
    float2 t;
    t = O0;           v[0]=caddf(E0,t); v[4]=csubf(E0,t);
    t = cmulf(w1,O1); v[1]=caddf(E1,t); v[5]=csubf(E1,t);
    t = cmulf(w2,O2); v[2]=caddf(E2,t); v[6]=csubf(E2,t);
    t = cmulf(w3,O3); v[3]=caddf(E3,t); v[7]=csubf(E3,t);
}

// 64-pt transform along the contiguous axis of all 64 rows at once (512 threads: 64 rows x 8).
template<int S, int MODE>
__device__ void fft64_rows(float* Re, float* Im, const float* twc, const float* tws,
                           int tid, float2* gout, float scale)
{
    int r  = tid & 63;
    int t8 = tid >> 6;
    float2 v[8];
    __syncthreads();
    #pragma unroll
    for (int m = 0; m < 8; ++m) {
        int idx = r*FPITCH + 8*m + t8;
        v[m] = make_float2(Re[idx], Im[idx]);
    }
    dft8<S>(v);
    #pragma unroll
    for (int k1 = 1; k1 < 8; ++k1) {
        int mm = (t8*k1) & 63;
        v[k1] = cmulf(v[k1], make_float2(twc[mm], (float)S*tws[mm]));
    }
    __syncthreads();
    #pragma unroll
    for (int k1 = 0; k1 < 8; ++k1) {
        int idx = r*FPITCH + k1*8 + t8;
        Re[idx] = v[k1].x; Im[idx] = v[k1].y;
    }
    __syncthreads();
    float2 a[8];
    #pragma unroll
    for (int m = 0; m < 8; ++m) {
        int idx = r*FPITCH + t8*8 + m;
        a[m] = make_float2(Re[idx], Im[idx]);
    }
    dft8<S>(a);
    if (MODE == 0) {
        __syncthreads();
        #pragma unroll
        for (int k2 = 0; k2 < 8; ++k2) {
            int idx = r*FPITCH + t8 + 8*k2;
            Re[idx] = a[k2].x; Im[idx] = a[k2].y;
        }
    } else {
        #pragma unroll
        for (int k2 = 0; k2 < 8; ++k2) {
            int kq = t8 + 8*k2;
            gout[r + 64*kq] = make_float2(a[k2].x*scale, a[k2].y*scale);
        }
    }
    __syncthreads();
}

// 64-pt transform along the vertical axis of all 64 columns at once (512 threads).
// MODE 0: in-place. MODE 1: in-place * mid-twiddle.
// MODE 2: split-plane out gre/gim (+|.|^2 partial into *ss). MODE 3: bf16 |.|*scale out.
template<int S, int MODE>
__device__ void fft64_cols(float* Re, float* Im, const float* twc, const float* tws,
                           int tid, float* gre, float* gim, unsigned short* goutr,
                           float scale, float* ss)
{
    int col = tid & 63;
    int t8  = tid >> 6;
    float2 v[8];
    __syncthreads();
    #pragma unroll
    for (int m = 0; m < 8; ++m) {
        int idx = (8*m + t8)*FPITCH + col;
        v[m] = make_float2(Re[idx], Im[idx]);
    }
    dft8<S>(v);
    #pragma unroll
    for (int k1 = 1; k1 < 8; ++k1) {
        int mm = (t8*k1) & 63;
        v[k1] = cmulf(v[k1], make_float2(twc[mm], (float)S*tws[mm]));
    }
    __syncthreads();
    #pragma unroll
    for (int k1 = 0; k1 < 8; ++k1) {
        int idx = (k1*8 + t8)*FPITCH + col;
        Re[idx] = v[k1].x; Im[idx] = v[k1].y;
    }
    __syncthreads();
    float2 a[8];
    #pragma unroll
    for (int m = 0; m < 8; ++m) {
        int idx = (t8*8 + m)*FPITCH + col;
        a[m] = make_float2(Re[idx], Im[idx]);
    }
    dft8<S>(a);
    if (MODE <= 1) {
        __syncthreads();
        #pragma unroll
        for (int k2 = 0; k2 < 8; ++k2) {
            int row = t8 + 8*k2;
            float2 rv = a[k2];
            if (MODE == 1) {
                float sv, cv;
                __sincosf((TWO_PI/4096.f) * (float)(row*col), &sv, &cv);
                rv = cmulf(rv, make_float2(cv, (float)S*sv));
            }
            int idx = row*FPITCH + col;
            Re[idx] = rv.x; Im[idx] = rv.y;
        }
    } else if (MODE == 2) {
        #pragma unroll
        for (int k2 = 0; k2 < 8; ++k2) {
            int row = t8 + 8*k2;
            *ss += a[k2].x*a[k2].x + a[k2].y*a[k2].y;
            gre[row*64 + col] = a[k2].x*scale;
            gim[row*64 + col] = a[k2].y*scale;
        }
    } else {
        #pragma unroll
        for (int k2 = 0; k2 < 8; ++k2) {
            int row = t8 + 8*k2;
            goutr[row*64 + col] = f2bf(scale * sqrtf(a[k2].x*a[k2].x + a[k2].y*a[k2].y));
        }
    }
    __syncthreads();
}

// conv weights (256,512,3,3) fp32 -> wB[t][o][i] bf16 (i contiguous = K-contiguous B rows)
__global__ __launch_bounds__(256) void k_wconv(const float* __restrict__ w, unsigned short* __restrict__ wB) {
    int idx = blockIdx.x*256 + threadIdx.x;
    if (idx >= 9*NC*ND) return;
    int i = idx & 511;
    int rest = idx >> 9;
    int o = rest & 255;
    int t = rest >> 8;
    wB[idx] = f2bf(w[(o*NC + i)*9 + t]);
}

// proj weights (512,512) fp32 -> bf16, same [o][c] layout
__global__ __launch_bounds__(256) void k_wproj(const float* __restrict__ w, unsigned short* __restrict__ wb) {
    int i = blockIdx.x*256 + threadIdx.x;
    wb[i] = f2bf(w[i]);
}

// x (b, 4096, 512) fp32 -> spatially padded bf16 xpad[b][hp][wp][c], hp/wp in [0,70)
__global__ __launch_bounds__(256) void k_xpad(const float* __restrict__ x, unsigned short* __restrict__ xpad) {
    int idx = blockIdx.x*256 + threadIdx.x;
    int c8 = idx & 63;
    int rest = idx >> 6;
    int wp = rest % HPAD;
    int rest2 = rest / HPAD;
    int hp = rest2 % HPAD;
    int b = rest2 / HPAD;
    int h = hp - 3, w = wp - 3;
    bf16x8 v = {0,0,0,0,0,0,0,0};
    if (((unsigned)h) < 64u && ((unsigned)w) < 64u) {
        const float* s = x + (((size_t)b*NP + h*64 + w)*NC + c8*8);
        float4 f0 = *(const float4*)(s);
        float4 f1 = *(const float4*)(s + 4);
        v[0]=(short)f2bf(f0.x); v[1]=(short)f2bf(f0.y); v[2]=(short)f2bf(f0.z); v[3]=(short)f2bf(f0.w);
        v[4]=(short)f2bf(f1.x); v[5]=(short)f2bf(f1.y); v[6]=(short)f2bf(f1.z); v[7]=(short)f2bf(f1.w);
    }
    *(bf16x8*)(xpad + ((size_t)(b*HPAD*HPAD) + hp*HPAD + wp)*NC + c8*8) = v;
}

// bf16 MFMA implicit-GEMM dilated conv (d=3,pad=3) + bias + BN + ReLU -> out[b][o][p] fp32
// R4-proven 2-phase double-buffer: K=64 chunks, one barrier per chunk, stage issued before compute.
// K-slot swizzle (verified bijective; conflicts 0): source slot c16^((r0>>1)&3), read slot kq^((ln>>1)&3).
__global__ __launch_bounds__(256, 2) void k_conv_mfma(
        const unsigned short* __restrict__ xpad, const unsigned short* __restrict__ wB,
        const float* __restrict__ cbias, const float* __restrict__ bg, const float* __restrict__ bb,
        const float* __restrict__ bm, const float* __restrict__ bv, float* __restrict__ out)
{
    // [buf][ks*4096 + row*32 + slot*8] ; 2 bufs x (A,B) x 16 KB = 64 KB
    __shared__ short Als[2][8192];
    __shared__ short Bls[2][8192];
    int tid = threadIdx.x;
    int p0 = blockIdx.x * 128;
    int o0 = blockIdx.y * 128;
    int b  = blockIdx.z;
    int lane = tid & 63;
    int wv = tid >> 6;
    int wr = wv >> 1, wc = wv & 1;
    int ln = lane & 15, kq = lane >> 4;
    int kqs = kq ^ ((ln >> 1) & 3);          // swizzled K-slot (read side)

    f32x4 acc[4][4];
    #pragma unroll
    for (int i = 0; i < 4; ++i)
        #pragma unroll
        for (int j = 0; j < 4; ++j)
            acc[i][j] = (f32x4){0.f, 0.f, 0.f, 0.f};

    int r0 = tid >> 2;
    int c16 = tid & 3;
    int c16s = c16 ^ ((r0 >> 1) & 3);        // swizzled K-slot (global source side)
    int pA0 = p0 + r0, pA1 = p0 + 64 + r0;
    int h0 = pA0 >> 6, w0c = pA0 & 63;
    int h1 = pA1 >> 6, w1c = pA1 & 63;
    const unsigned short* xb = xpad + (size_t)b*(HPAD*HPAD)*NC;
    int oB0 = o0 + r0, oB1 = o0 + 64 + r0;
    short* AlsD0 = &Als[0][tid*8];
    short* AlsD1 = &Als[0][2048 + tid*8];
    short* BlsD0 = &Bls[0][tid*8];
    short* BlsD1 = &Bls[0][2048 + tid*8];

    // Stage K-chunk `it` (of 72 = 9 taps x 8 chunks of K=64) into buffer it&1.
    auto stage = [&](int it) {
        int buf = it & 1;
        int tap = it >> 3;
        int kc  = (it & 7) << 6;
        int q   = (tap*11) >> 5;             // tap/3 for tap in [0,9)
        int dh  = q*3, dw = (tap - q*3)*3;
        const unsigned short* a0 = xb + ((size_t)((h0 + dh)*HPAD + (w0c + dw)))*NC + kc + c16s*8;
        const unsigned short* a1 = xb + ((size_t)((h1 + dh)*HPAD + (w1c + dw)))*NC + kc + c16s*8;
        const unsigned short* b0 = wB + ((size_t)(tap*ND + oB0))*NC + kc + c16s*8;
        const unsigned short* b1 = wB + ((size_t)(tap*ND + oB1))*NC + kc + c16s*8;
        int bo = buf ? 8192 : 0;
        load_lds16(a0,      AlsD0 + bo);          // ks=0 rows 0..63
        load_lds16(a1,      AlsD1 + bo);          // ks=0 rows 64..127
        load_lds16(a0 + 32, AlsD0 + bo + 4096);   // ks=1 rows 0..63
        load_lds16(a1 + 32, AlsD1 + bo + 4096);   // ks=1 rows 64..127
        load_lds16(b0,      BlsD0 + bo);
        load_lds16(b1,      BlsD1 + bo);
        load_lds16(b0 + 32, BlsD0 + bo + 4096);
        load_lds16(b1 + 32, BlsD1 + bo + 4096);
    };

    stage(0);
    #pragma unroll 2
    for (int it = 0; it < 72; ++it) {
        int buf = it & 1;
        // my 8 loads for buf (issued last iteration / prologue) must be complete
        asm volatile("s_waitcnt vmcnt(0)" ::: "memory");
        __builtin_amdgcn_s_barrier();          // all waves: buf ready; all prev ds_reads done
        __builtin_amdgcn_sched_barrier(0);     // no LDS access motion across the barrier
        if (it + 1 < 72) stage(it + 1);        // overlap with compute below
        #pragma unroll
        for (int ks = 0; ks < 2; ++ks) {
            bf16x8 af[4], bfr[4];
            #pragma unroll
            for (int mi = 0; mi < 4; ++mi)
                af[mi] = *(const bf16x8*)&Als[buf][ks*4096 + (wr*64 + mi*16 + ln)*32 + kqs*8];
            #pragma unroll
            for (int ni = 0; ni < 4; ++ni)
                bfr[ni] = *(const bf16x8*)&Bls[buf][ks*4096 + (wc*64 + ni*16 + ln)*32 + kqs*8];
            #pragma unroll
            for (int mi = 0; mi < 4; ++mi)
                #pragma unroll
                for (int ni = 0; ni < 4; ++ni)
                    acc[mi][ni] = __builtin_amdgcn_mfma_f32_16x16x32_bf16(af[mi], bfr[ni], acc[mi][ni], 0, 0, 0);
        }
    }

    #pragma unroll
    for (int ni = 0; ni < 4; ++ni) {
        int o = o0 + wc*64 + ni*16 + ln;
        float inv = bg[o] * rsqrtf(bv[o] + 1e-5f);
        float beta = bb[o] - bm[o]*inv;
        float cbo = cbias[o];
        #pragma unroll
        for (int mi = 0; mi < 4; ++mi) {
            int p = p0 + wr*64 + mi*16 + kq*4;
            f32x4 v = acc[mi][ni];
            float4 rv;
            rv.x = fmaxf((v[0] + cbo)*inv + beta, 0.f);
            rv.y = fmaxf((v[1] + cbo)*inv + beta, 0.f);
            rv.z = fmaxf((v[2] + cbo)*inv + beta, 0.f);
            rv.w = fmaxf((v[3] + cbo)*inv + beta, 0.f);
            *(float4*)(out + ((size_t)(b*ND + o))*NP + p) = rv;
        }
    }
}

// fft2 (forward) of one 64x64 real image -> split planes fRe/fIm; also writes per-image L2 norm
__global__ __launch_bounds__(512) void k_fft2_fwd(const float* __restrict__ src, float* __restrict__ fRe,
                                                  float* __restrict__ fIm, float* __restrict__ nrm) {
    __shared__ float Re[64*FPITCH];
    __shared__ float Im[64*FPITCH];
    __shared__ float twc[64], tws[64];
    __shared__ float part[8];
    int tid = threadIdx.x;
    size_t img = blockIdx.x;
    const float* s = src + img*4096;
    if (tid < 64) { float sv, cv; __sincosf(TWO_PI*(float)tid/64.f, &sv, &cv); twc[tid]=cv; tws[tid]=sv; }
    for (int i = tid; i < 4096; i += 512) {
        Re[(i>>6)*FPITCH + (i&63)] = s[i];
        Im[(i>>6)*FPITCH + (i&63)] = 0.f;
    }
    fft64_rows<-1,0>(Re, Im, twc, tws, tid, nullptr, 1.f);
    float ssl = 0.f;
    fft64_cols<-1,2>(Re, Im, twc, tws, tid, fRe + img*4096, fIm + img*4096, nullptr, 1.f, &ssl);
    #pragma unroll
    for (int off = 32; off > 0; off >>= 1) ssl += __shfl_down(ssl, off, 64);
    if ((tid & 63) == 0) part[tid >> 6] = ssl;
    __syncthreads();
    if (tid == 0) {
        float t = part[0]+part[1]+part[2]+part[3]+part[4]+part[5]+part[6]+part[7];
        nrm[img] = fmaxf(sqrtf(t), 1e-12f);
    }
}

// 4096-pt inverse FFT of one f-row (Cooley-Tukey 64x64): Z[k1+64*k2], includes 1/4096
__global__ __launch_bounds__(512) void k_ifft_row4096(const float* __restrict__ fRe,
        const float* __restrict__ fIm, float2* __restrict__ Z) {
    __shared__ float Re[64*FPITCH];
    __shared__ float Im[64*FPITCH];
    __shared__ float twc[64], tws[64];
    int tid = threadIdx.x;
    size_t img = blockIdx.x;
    const float* sr = fRe + img*4096;
    const float* si = fIm + img*4096;
    if (tid < 64) { float sv, cv; __sincosf(TWO_PI*(float)tid/64.f, &sv, &cv); twc[tid]=cv; tws[tid]=sv; }
    for (int i = tid; i < 4096; i += 512) {
        Re[(i>>6)*FPITCH + (i&63)] = sr[i];
        Im[(i>>6)*FPITCH + (i&63)] = si[i];
    }
    fft64_cols<1,1>(Re, Im, twc, tws, tid, nullptr, nullptr, nullptr, 1.f, nullptr);
    fft64_rows<1,1>(Re, Im, twc, tws, tid, Z + img*4096, 1.f/4096.f);
}

// gated ifft2: computes gate = sigmoid(w2 @ g1 + b2) on the fly (g1 transposed [b][p][16],
// contiguous float4 reads), multiplies f, ifft2, abs * 1/4096 -> bf16 [c][p].
__global__ __launch_bounds__(512) void k_ifft2_abs_gated(const float* __restrict__ fRe,
        const float* __restrict__ fIm, const float* __restrict__ g1, const float* __restrict__ w2,
        const float* __restrict__ w2b, unsigned short* __restrict__ out) {
    __shared__ float Re[64*FPITCH];
    __shared__ float Im[64*FPITCH];
    __shared__ float twc[64], tws[64];
    int tid = threadIdx.x;
    size_t img = blockIdx.x;
    int b = (int)(img >> 8), ch = (int)(img & 255);
    const float* sr = fRe + img*4096;
    const float* si = fIm + img*4096;
    const float* g1b = g1 + (size_t)b*NP*16;
    float4 wv0 = *(const float4*)(w2 + ch*16);
    float4 wv1 = *(const float4*)(w2 + ch*16 + 4);
    float4 wv2 = *(const float4*)(w2 + ch*16 + 8);
    float4 wv3 = *(const float4*)(w2 + ch*16 + 12);
    float w2bias = w2b[ch];
    if (tid < 64) { float sv, cv; __sincosf(TWO_PI*(float)tid/64.f, &sv, &cv); twc[tid]=cv; tws[tid]=sv; }
    for (int i = tid; i < 4096; i += 512) {
        const float* gp = g1b + (size_t)i*16;
        float4 q0 = *(const float4*)(gp);
        float4 q1 = *(const float4*)(gp + 4);
        float4 q2 = *(const float4*)(gp + 8);
        float4 q3 = *(const float4*)(gp + 12);
        float acc = w2bias
            + wv0.x*q0.x + wv0.y*q0.y + wv0.z*q0.z + wv0.w*q0.w
            + wv1.x*q1.x + wv1.y*q1.y + wv1.z*q1.z + wv1.w*q1.w
            + wv2.x*q2.x + wv2.y*q2.y + wv2.z*q2.z + wv2.w*q2.w
            + wv3.x*q3.x + wv3.y*q3.y + wv3.z*q3.z + wv3.w*q3.w;
        float gate = 1.f / (1.f + __expf(-acc));
        Re[(i>>6)*FPITCH + (i&63)] = gate*sr[i];
        Im[(i>>6)*FPITCH + (i&63)] = gate*si[i];
    }
    fft64_rows<1,0>(Re, Im, twc, tws, tid, nullptr, 1.f);
    fft64_cols<1,3>(Re, Im, twc, tws, tid, nullptr, nullptr, out + img*4096, 1.f/4096.f, nullptr);
}

// G[c][d] = sum_n f_c[n]*f_d[n] (complex, no conj) via bf16 hi+lo split MFMA.
// Each fp32 -> (hi,lo) bf16 pair (K doubled); MFMA fp32 accumulator makes the product
// exact to ~2^-16 relative. Re = FrFr - FiFi, Im = FrFi + FiFr (4 accumulators).
// Grid (NSPL=16 n-splits, 64 bh); 4 waves = 2x2 quadrants of the 32x32 output.
__global__ __launch_bounds__(256) void k_gram(const float* __restrict__ fRe, const float* __restrict__ fIm,
                                              float2* __restrict__ Gpart) {
    __shared__ short FrP[32*136];   // [row][K2=128], row padded to 136 (68 words -> 2-way max)
    __shared__ short FiP[32*136];
    int split = blockIdx.x;
    int bh = blockIdx.y;
    int b = bh >> 3, h = bh & 7;
    int tid = threadIdx.x;
    int lane = tid & 63;
    int wv = tid >> 6;
    int cr = (wv >> 1) * 16, dc = (wv & 1) * 16;
    int ln = lane & 15, kq = lane >> 4;
    int r = tid >> 3;          // staging row 0..31
    int g = tid & 7;           // staging n-octet
    const float* fRb = fRe + ((size_t)(b*ND + h*32) + r)*NP + split*256 + g*8;
    const float* fIb = fIm + ((size_t)(b*ND + h*32) + r)*NP + split*256 + g*8;
    short* wFr = FrP + r*136 + g*16;
    short* wFi = FiP + r*136 + g*16;

    f32x4 arr = {0.f,0.f,0.f,0.f}, aii = {0.f,0.f,0.f,0.f};
    f32x4 ari = {0.f,0.f,0.f,0.f}, air = {0.f,0.f,0.f,0.f};

    for (int chunk = 0; chunk < 4; ++chunk) {       // 4 chunks x 64 n = 256 n per split
        float4 v0 = *(const float4*)(fRb + chunk*64);
        float4 v1 = *(const float4*)(fRb + chunk*64 + 4);
        float4 w0 = *(const float4*)(fIb + chunk*64);
        float4 w1 = *(const float4*)(fIb + chunk*64 + 4);
        __syncthreads();                            // previous chunk's MFMA reads done
        float vr[8] = {v0.x,v0.y,v0.z,v0.w,v1.x,v1.y,v1.z,v1.w};
        float vi[8] = {w0.x,w0.y,w0.z,w0.w,w1.x,w1.y,w1.z,w1.w};
        bf16x8 r0v, r1v, i0v, i1v;
        #pragma unroll
        for (int j = 0; j < 4; ++j) {
            unsigned short hb;
            hb = f2bf(vr[j]);   r0v[2*j] = (short)hb; r0v[2*j+1] = (short)f2bf(vr[j]   - bf2f(hb));
            hb = f2bf(vr[4+j]); r1v[2*j] = (short)hb; r1v[2*j+1] = (short)f2bf(vr[4+j] - bf2f(hb));
            hb = f2bf(vi[j]);   i0v[2*j] = (short)hb; i0v[2*j+1] = (short)f2bf(vi[j]   - bf2f(hb));
            hb = f2bf(vi[4+j]); i1v[2*j] = (short)hb; i1v[2*j+1] = (short)f2bf(vi[4+j] - bf2f(hb));
        }
        *(bf16x8*)(wFr)     = r0v;
        *(bf16x8*)(wFr + 8) = r1v;
        *(bf16x8*)(wFi)     = i0v;
        *(bf16x8*)(wFi + 8) = i1v;
        __syncthreads();
        const short* aRp = FrP + (cr + ln)*136;
        const short* aIp = FiP + (cr + ln)*136;
        const short* bRp = FrP + (dc + ln)*136;
        const short* bIp = FiP + (dc + ln)*136;
        #pragma unroll
        for (int s = 0; s < 4; ++s) {               // K2 = 128 -> 4 mfma steps of K=32
            int ko = s*32 + kq*8;
            bf16x8 aR = *(const bf16x8*)(aRp + ko);
            bf16x8 aI = *(const bf16x8*)(aIp + ko);
            bf16x8 bR = *(const bf16x8*)(bRp + ko);
            bf16x8 bI = *(const bf16x8*)(bIp + ko);
            arr = __builtin_amdgcn_mfma_f32_16x16x32_bf16(aR, bR, arr, 0, 0, 0);
            aii = __builtin_amdgcn_mfma_f32_16x16x32_bf16(aI, bI, aii, 0, 0, 0);
            ari = __builtin_amdgcn_mfma_f32_16x16x32_bf16(aR, bI, ari, 0, 0, 0);
            air = __builtin_amdgcn_mfma_f32_16x16x32_bf16(aI, bR, air, 0, 0, 0);
        }
    }
    // C/D layout: col = ln (d), row = kq*4 + j (c) within the wave's 16x16 quadrant.
    float2* gout = Gpart + ((size_t)bh*NSPL + split)*1024;
    #pragma unroll
    for (int j = 0; j < 4; ++j) {
        int c = cr + kq*4 + j;
        int d = dc + ln;
        gout[c*32 + d] = make_float2(arr[j] - aii[j], ari[j] + air[j]);
    }
}

// reduce partials, normalize, *temp, dual softmax, then A' = (1/32) W32+ @ S
__global__ __launch_bounds__(256) void k_attn(const float2* __restrict__ Gpart, const float* __restrict__ nrm,
                                              const float* __restrict__ temp, float2* __restrict__ Ap) {
    int bh = blockIdx.x;
    int b = bh >> 3, h = bh & 7;
    int tid = threadIdx.x;
    __shared__ float2 Sm[32][33];
    __shared__ float twc[32], tws[32];
    if (tid < 32) { float sv, cv; __sincosf(TWO_PI*(float)tid/32.f, &sv, &cv); twc[tid]=cv; tws[tid]=sv; }
    const float* nb = nrm + b*ND + h*32;
    float tv = temp[h];
    const float2* gp = Gpart + (size_t)bh*NSPL*1024;
    #pragma unroll
    for (int j = 0; j < 4; ++j) {
        int e = tid*4 + j;
        int c = e >> 5, d = e & 31;
        float2 s = make_float2(0.f, 0.f);
        for (int sp = 0; sp < NSPL; ++sp) { float2 v = gp[sp*1024 + e]; s.x += v.x; s.y += v.y; }
        float sc = tv / (nb[c]*nb[d]);
        Sm[c][d] = make_float2(s.x*sc, s.y*sc);
    }
    __syncthreads();
    if (tid < 32) {
        float mr = -1e30f, mi = -1e30f;
        for (int d = 0; d < 32; ++d) { float2 v = Sm[tid][d]; mr = fmaxf(mr, v.x); mi = fmaxf(mi, v.y); }
        float sr = 0.f, si = 0.f;
        for (int d = 0; d < 32; ++d) {
            float2 v = Sm[tid][d];
            v.x = __expf(v.x - mr); v.y = __expf(v.y - mi);
            sr += v.x; si += v.y;
            Sm[tid][d] = v;
        }
        float ir = 1.f/sr, ii = 1.f/si;
        for (int d = 0; d < 32; ++d) { float2 v = Sm[tid][d]; Sm[tid][d] = make_float2(v.x*ir, v.y*ii); }
    }
    __syncthreads();
    float2* ap = Ap + (size_t)bh*1024;
    #pragma unroll
    for (int j = 0; j < 4; ++j) {
        int e = tid*4 + j;
        int k = e >> 5, d = e & 31;
        float2 acc = make_float2(0.f, 0.f);
        for (int c = 0; c < 32; ++c) {
            int m = (c*k) & 31;
            float2 w = make_float2(twc[m], tws[m]);
            float2 v = Sm[c][d];
            acc.x += w.x*v.x - w.y*v.y;
            acc.y += w.x*v.y + w.y*v.x;
        }
        ap[e] = make_float2(acc.x*(1.f/32.f), acc.y*(1.f/32.f));
    }
}

// out_f2 = | A' @ Z |  per (b,head) -> bf16 [c][p]
__global__ __launch_bounds__(256) void k_outf2(const float2* __restrict__ Ap, const float2* __restrict__ Z,
                                               unsigned short* __restrict__ outf2) {
    int nc = blockIdx.x, bh = blockIdx.y;
    int b = bh >> 3, h = bh & 7;
    int tid = threadIdx.x;
    __shared__ float2 A[32][32];
    const float2* ap = Ap + (size_t)bh*1024;
    for (int i = tid; i < 1024; i += 256) A[i>>5][i&31] = ap[i];
    __syncthreads();
    int n = nc*256 + tid;
    const float2* zb = Z + ((size_t)(b*ND + h*32))*NP + n;
    float2 z[32];
    #pragma unroll
    for (int d = 0; d < 32; ++d) z[d] = zb[(size_t)d*NP];
    unsigned short* ob = outf2 + ((size_t)(b*ND + h*32))*NP + n;
    for (int k = 0; k < 32; ++k) {
        float2 acc = make_float2(0.f, 0.f);
        #pragma unroll
        for (int d = 0; d < 32; ++d) {
            float2 a = A[k][d], zz = z[d];
            acc.x += a.x*zz.x - a.y*zz.y;
            acc.y += a.x*zz.y + a.y*zz.x;
        }
        ob[(size_t)k*NP] = f2bf(sqrtf(acc.x*acc.x + acc.y*acc.y));
    }
}

// g1 = relu(BN(w1 @ Re(f)))  -- reads the compact fRe plane; writes TRANSPOSED [b][p][16]
__global__ __launch_bounds__(256) void k_g1(const float* __restrict__ fRe, const float* __restrict__ w1,
        const float* __restrict__ w1b, const float* __restrict__ gg, const float* __restrict__ gb,
        const float* __restrict__ gm, const float* __restrict__ gv, float* __restrict__ g1)
{
    int pc = blockIdx.x, b = blockIdx.y;
    int tid = threadIdx.x;
    __shared__ float w1s[16*256];
    for (int i = tid; i < 4096; i += 256) w1s[i] = w1[i];
    __syncthreads();
    int p = pc*256 + tid;
    const float* fb = fRe + (size_t)b*ND*NP + p;
    float acc[16];
    #pragma unroll
    for (int j = 0; j < 16; ++j) acc[j] = 0.f;
    for (int i = 0; i < 256; ++i) {
        float v = fb[(size_t)i*NP];
        #pragma unroll
        for (int j = 0; j < 16; ++j) acc[j] += w1s[j*256 + i] * v;
    }
    float* go = g1 + ((size_t)b*NP + p)*16;
    float4 o4[4];
    #pragma unroll
    for (int j = 0; j < 16; ++j) {
        float inv = gg[j]*rsqrtf(gv[j] + 1e-5f);
        float val = (acc[j] + w1b[j])*inv + (gb[j] - gm[j]*inv);
        ((float*)o4)[j] = fmaxf(val, 0.f);
    }
    *(float4*)(go)      = o4[0];
    *(float4*)(go + 4)  = o4[1];
    *(float4*)(go + 8)  = o4[2];
    *(float4*)(go + 12) = o4[3];
}

// A[b][p][c] bf16 = cat(outf2b,outl2b)[c][p] + x[b][p][c]
__global__ __launch_bounds__(256) void k_prep(const unsigned short* __restrict__ outf2b,
        const unsigned short* __restrict__ outl2b, const float* __restrict__ x,
        unsigned short* __restrict__ A)
{
    int tid = threadIdx.x;
    int p = blockIdx.x*64 + (tid >> 2);
    int cs = blockIdx.y*64 + (tid & 3)*16;
    int b  = blockIdx.z;
    const unsigned short* src = (cs < ND) ? (outf2b + ((size_t)(b*ND) + cs)*NP + p)
                                          : (outl2b + ((size_t)(b*ND) + (cs - ND))*NP + p);
    float av[16];
    #pragma unroll
    for (int j = 0; j < 16; ++j) av[j] = bf2f(src[(size_t)j*NP]);
    const float* xp = x + ((size_t)(b*NP) + p)*NC + cs;
    #pragma unroll
    for (int j = 0; j < 4; ++j) {
        float4 xv = *(const float4*)(xp + j*4);
        av[j*4+0] += xv.x; av[j*4+1] += xv.y; av[j*4+2] += xv.z; av[j*4+3] += xv.w;
    }
    bf16x8 v0, v1;
    #pragma unroll
    for (int j = 0; j < 8; ++j) { v0[j] = (short)f2bf(av[j]); v1[j] = (short)f2bf(av[8+j]); }
    unsigned short* ap = A + ((size_t)(b*NP) + p)*NC + cs;
    *(bf16x8*)(ap) = v0;
    *(bf16x8*)(ap + 8) = v1;
}

// bf16 MFMA proj GEMM: out[b][p][o] = A[b][p][:] . pw[o][:] + pb[o]
// R4-proven 2-phase double-buffer + K-slot swizzle.
__global__ __launch_bounds__(256, 2) void k_projm(
        const unsigned short* __restrict__ A, const unsigned short* __restrict__ Bw,
        const float* __restrict__ pb, float* __restrict__ out)
{
    __shared__ short Als[2][8192];
    __shared__ short Bls[2][8192];
    int tid = threadIdx.x;
    int p0 = blockIdx.x * 128;
    int o0 = blockIdx.y * 128;
    int b  = blockIdx.z;
    int lane = tid & 63;
    int wv = tid >> 6;
    int wr = wv >> 1, wc = wv & 1;
    int ln = lane & 15, kq = lane >> 4;
    int kqs = kq ^ ((ln >> 1) & 3);

    f32x4 acc[4][4];
    #pragma unroll
    for (int i = 0; i < 4; ++i)
        #pragma unroll
        for (int j = 0; j < 4; ++j)
            acc[i][j] = (f32x4){0.f, 0.f, 0.f, 0.f};

    int r0 = tid >> 2;
    int c16 = tid & 3;
    int c16s = c16 ^ ((r0 >> 1) & 3);
    const unsigned short* ga0 = A + ((size_t)(b*NP) + p0 + r0)*NC + c16s*8;
    const unsigned short* ga1 = A + ((size_t)(b*NP) + p0 + 64 + r0)*NC + c16s*8;
    const unsigned short* gb0 = Bw + (size_t)(o0 + r0)*NC + c16s*8;
    const unsigned short* gb1 = Bw + (size_t)(o0 + 64 + r0)*NC + c16s*8;
    short* AlsD0 = &Als[0][tid*8];
    short* AlsD1 = &Als[0][2048 + tid*8];
    short* BlsD0 = &Bls[0][tid*8];
    short* BlsD1 = &Bls[0][2048 + tid*8];

    auto stage = [&](int it) {
        int buf = it & 1;
        int kc = it << 6;
        int bo = buf ? 8192 : 0;
        load_lds16(ga0 + kc,      AlsD0 + bo);
        load_lds16(ga1 + kc,      AlsD1 + bo);
        load_lds16(ga0 + kc + 32, AlsD0 + bo + 4096);
        load_lds16(ga1 + kc + 32, AlsD1 + bo + 4096);
        load_lds16(gb0 + kc,      BlsD0 + bo);
        load_lds16(gb1 + kc,      BlsD1 + bo);
        load_lds16(gb0 + kc + 32, BlsD0 + bo + 4096);
        load_lds16(gb1 + kc + 32, BlsD1 + bo + 4096);
    };

    stage(0);
    #pragma unroll 2
    for (int it = 0; it < 8; ++it) {
        int buf = it & 1;
        asm volatile("s_waitcnt vmcnt(0)" ::: "memory");
        __builtin_amdgcn_s_barrier();
        __builtin_amdgcn_sched_barrier(0);
        if (it + 1 < 8) stage(it + 1);
        #pragma unroll
        for (int ks = 0; ks < 2; ++ks) {
            bf16x8 af[4], bfr[4];
            #pragma unroll
            for (int mi = 0; mi < 4; ++mi)
                af[mi] = *(const bf16x8*)&Als[buf][ks*4096 + (wr*64 + mi*16 + ln)*32 + kqs*8];
            #pragma unroll
            for (int ni = 0; ni < 4; ++ni)
                bfr[ni] = *(const bf16x8*)&Bls[buf][ks*4096 + (wc*64 + ni*16 + ln)*32 + kqs*8];
            #pragma unroll
            for (int mi = 0; mi < 4; ++mi)
                #pragma unroll
                for (int ni = 0; ni < 4; ++ni)
                    acc[mi][ni] = __builtin_amdgcn_mfma_f32_16x16x32_bf16(af[mi], bfr[ni], acc[mi][ni], 0, 0, 0);
        }
    }

    // C/D: col(ln)=o, row(kq*4+reg)=p. 16 lanes x 4B consecutive in o => full 64B lines.
    #pragma unroll
    for (int ni = 0; ni < 4; ++ni) {
        int o = o0 + wc*64 + ni*16 + ln;
        float bias = pb[o];
        #pragma unroll
        for (int mi = 0; mi < 4; ++mi) {
            int p = p0 + wr*64 + mi*16 + kq*4;
            f32x4 v = acc[mi][ni];
            float* op = out + ((size_t)(b*NP) + p)*NC + o;
            op[0]        = v[0] + bias;
            op[NC]       = v[1] + bias;
            op[2*NC]     = v[2] + bias;
            op[3*(size_t)NC] = v[3] + bias;
        }
    }
}

extern "C" void kernel_launch(void* const* d_in, const int* in_sizes, int n_in,
                              void* d_out, int out_size, void* d_ws, size_t ws_size,
                              hipStream_t stream)
{
    const float* x      = (const float*)d_in[0];
    const float* conv_w = (const float*)d_in[1];
    const float* conv_b = (const float*)d_in[2];
    const float* bn2g   = (const float*)d_in[3];
    const float* bn2b   = (const float*)d_in[4];
    const float* bn2m   = (const float*)d_in[5];
    const float* bn2v   = (const float*)d_in[6];
    const float* temp   = (const float*)d_in[7];
    const float* w1w    = (const float*)d_in[8];
    const float* w1b    = (const float*)d_in[9];
    const float* bnwg   = (const float*)d_in[10];
    const float* bnwb   = (const float*)d_in[11];
    const float* bnwm   = (const float*)d_in[12];
    const float* bnwv   = (const float*)d_in[13];
    const float* w2w    = (const float*)d_in[14];
    const float* w2b    = (const float*)d_in[15];
    const float* projw  = (const float*)d_in[16];
    const float* projb  = (const float*)d_in[17];
    float* out = (float*)d_out;

    char* ws = (char*)d_ws;
    // Head overlay region [0, 6,823,936):
    //   wB bf16 (2,359,296 B) during conv; nrm/Ap/g1 reuse it afterwards.
    unsigned short* wB = (unsigned short*)(ws);
    float*  nrm   = (float*)(ws);
    float2* Ap    = (float2*)(ws + 8192 + 4194304);
    float*  g1    = (float*)(ws + 8192 + 4194304 + 524288);   // [b][p][16] transposed, 2MB
    char* base = ws + 6823936;
    // conv region [base, +33.5MB): conv fp32 (dead after fft2_fwd), then outf2b bf16 (16.7MB)
    float*  conv  = (float*)(base);
    unsigned short* outf2b = (unsigned short*)(base);
    // f region [base+33.5MB, +67MB): xpad bf16 overlay (40.1MB, dead after conv);
    //   then split planes fRe (33.5MB) / fIm (33.5MB), live through k_ifft2_abs_gated.
    float* fRe = (float*)(base + 33554432);
    float* fIm = (float*)(base + 33554432 + 33554432);
    unsigned short* xpad = (unsigned short*)(base + 33554432);
    // Z region [base+100.6MB, +67MB): Gpart (8MB, gram->attn, dead before Z written);
    //   then Z complex; after k_outf2 Z dead -> pwb bf16 (0.5MB) at base, Abf bf16 (33.5MB)
    //   at +4MB, outl2b bf16 (16.7MB) at +37.7MB
    char* zbase = base + 33554432 + 67108864;
    float2* Gpart = (float2*)(zbase);     // 64 bh x NSPL x 1024 float2 = 8 MB
    float2* Z     = (float2*)(zbase);
    unsigned short* pwb = (unsigned short*)(zbase);
    unsigned short* Abf = (unsigned short*)(zbase + 4194304);
    unsigned short* outl2b = (unsigned short*)(zbase + 37748736);
    // total workspace used: 174,596,096 bytes (unchanged)

    k_wconv<<<dim3(4608), 256, 0, stream>>>(conv_w, wB);
    k_xpad<<<dim3(9800), 256, 0, stream>>>(x, xpad);
    k_conv_mfma<<<dim3(32, 2, 8), 256, 0, stream>>>(xpad, wB, conv_b, bn2g, bn2b, bn2m, bn2v, conv);
    k_fft2_fwd<<<dim3(2048), 512, 0, stream>>>(conv, fRe, fIm, nrm);
    k_gram<<<dim3(NSPL, 64), 256, 0, stream>>>(fRe, fIm, Gpart);
    k_attn<<<dim3(64), 256, 0, stream>>>(Gpart, nrm, temp, Ap);
    k_ifft_row4096<<<dim3(2048), 512, 0, stream>>>(fRe, fIm, Z);
    k_outf2<<<dim3(16, 64), 256, 0, stream>>>(Ap, Z, outf2b);
    k_g1<<<dim3(16, 8), 256, 0, stream>>>(fRe, w1w, w1b, bnwg, bnwb, bnwm, bnwv, g1);
    k_ifft2_abs_gated<<<dim3(2048), 512, 0, stream>>>(fRe, fIm, g1, w2w, w2b, outl2b);
    k_wproj<<<dim3(1024), 256, 0, stream>>>(projw, pwb);
    k_prep<<<dim3(64, 8, 8), 256, 0, stream>>>(outf2b, outl2b, x, Abf);
    k_projm<<<dim3(32, 4, 8), 256, 0, stream>>>(Abf, pwb, projb, out);
}

// Round 9
// 425.498 us; speedup vs baseline: 1.5269x; 1.1039x over previous
//
#include <hip/hip_runtime.h>

// Shapes (fixed by the problem)
#define NB 8
#define NC 512
#define ND 256
#define NP 4096
#define NHD 8
#define TWO_PI 6.2831853071795864f
#define FPITCH 65
#define HPAD 70
#define NSPL 16

typedef short bf16x8 __attribute__((ext_vector_type(8)));
typedef float f32x4 __attribute__((ext_vector_type(4)));

__device__ __forceinline__ unsigned short f2bf(float f) {
    unsigned u = __float_as_uint(f);
    u += 0x7FFFu + ((u >> 16) & 1u);
    return (unsigned short)(u >> 16);
}
__device__ __forceinline__ float bf2f(unsigned short u) {
    return __uint_as_float((unsigned)u << 16);
}

__device__ __forceinline__ void load_lds16(const void* g, void* l) {
    __builtin_amdgcn_global_load_lds((const __attribute__((address_space(1))) unsigned int*)g,
                                     (__attribute__((address_space(3))) unsigned int*)l, 16, 0, 0);
}

__device__ __forceinline__ float2 cmulf(float2 a, float2 b) {
    return make_float2(a.x*b.x - a.y*b.y, a.x*b.y + a.y*b.x);
}
__device__ __forceinline__ float2 caddf(float2 a, float2 b) { return make_float2(a.x+b.x, a.y+b.y); }
__device__ __forceinline__ float2 csubf(float2 a, float2 b) { return make_float2(a.x-b.x, a.y-b.y); }

// 8-point DFT in registers. S=-1 forward, S=+1 inverse (unscaled).
template<int S>
__device__ __forceinline__ void dft8(float2 v[8]) {
    float2 e0=v[0], e1=v[2], e2=v[4], e3=v[6];
    float2 o0=v[1], o1=v[3], o2=v[5], o3=v[7];
    float2 p0=caddf(e0,e2), p1=csubf(e0,e2), q0=caddf(e1,e3), q1=csubf(e1,e3);
    float2 q1r = make_float2(-(float)S*q1.y, (float)S*q1.x);
    float2 E0=caddf(p0,q0), E2=csubf(p0,q0), E1=caddf(p1,q1r), E3=csubf(p1,q1r);
    p0=caddf(o0,o2); p1=csubf(o0,o2); q0=caddf(o1,o3); q1=csubf(o1,o3);
    q1r = make_float2(-(float)S*q1.y, (float)S*q1.x);
    float2 O0=caddf(p0,q0), O2=csubf(p0,q0), O1=caddf(p1,q1r), O3=csubf(p1,q1r);
    const float r = 0.70710678118654752f;
    float2 w1 = make_float2(r, (float)S*r);
    float2 w2 = make_float2(0.f, (float)S);
    float2 w3 = make_float2(-r, (float)S*r);
    float2 t;
    t = O0;           v[0]=caddf(E0,t); v[4]=csubf(E0,t);
    t = cmulf(w1,O1); v[1]=caddf(E1,t); v[5]=csubf(E1,t);
    t = cmulf(w2,O2); v[2]=caddf(E2,t); v[6]=csubf(E2,t);
    t = cmulf(w3,O3); v[3]=caddf(E3,t); v[7]=csubf(E3,t);
}

// 64-pt transform along the contiguous axis of all 64 rows at once (512 threads: 64 rows x 8).
template<int S, int MODE>
__device__ void fft64_rows(float* Re, float* Im, const float* twc, const float* tws,
                           int tid, float2* gout, float scale)
{
    int r  = tid & 63;
    int t8 = tid >> 6;
    float2 v[8];
    __syncthreads();
    #pragma unroll
    for (int m = 0; m < 8; ++m) {
        int idx = r*FPITCH + 8*m + t8;
        v[m] = make_float2(Re[idx], Im[idx]);
    }
    dft8<S>(v);
    #pragma unroll
    for (int k1 = 1; k1 < 8; ++k1) {
        int mm = (t8*k1) & 63;
        v[k1] = cmulf(v[k1], make_float2(twc[mm], (float)S*tws[mm]));
    }
    __syncthreads();
    #pragma unroll
    for (int k1 = 0; k1 < 8; ++k1) {
        int idx = r*FPITCH + k1*8 + t8;
        Re[idx] = v[k1].x; Im[idx] = v[k1].y;
    }
    __syncthreads();
    float2 a[8];
    #pragma unroll
    for (int m = 0; m < 8; ++m) {
        int idx = r*FPITCH + t8*8 + m;
        a[m] = make_float2(Re[idx], Im[idx]);
    }
    dft8<S>(a);
    if (MODE == 0) {
        __syncthreads();
        #pragma unroll
        for (int k2 = 0; k2 < 8; ++k2) {
            int idx = r*FPITCH + t8 + 8*k2;
            Re[idx] = a[k2].x; Im[idx] = a[k2].y;
        }
    } else {
        #pragma unroll
        for (int k2 = 0; k2 < 8; ++k2) {
            int kq = t8 + 8*k2;
            gout[r + 64*kq] = make_float2(a[k2].x*scale, a[k2].y*scale);
        }
    }
    __syncthreads();
}

// 64-pt transform along the vertical axis of all 64 columns at once (512 threads).
// MODE 0: in-place. MODE 1: in-place * mid-twiddle.
// MODE 2: split-plane out gre/gim (+|.|^2 partial into *ss). MODE 3: bf16 |.|*scale out.
template<int S, int MODE>
__device__ void fft64_cols(float* Re, float* Im, const float* twc, const float* tws,
                           int tid, float* gre, float* gim, unsigned short* goutr,
                           float scale, float* ss)
{
    int col = tid & 63;
    int t8  = tid >> 6;
    float2 v[8];
    __syncthreads();
    #pragma unroll
    for (int m = 0; m < 8; ++m) {
        int idx = (8*m + t8)*FPITCH + col;
        v[m] = make_float2(Re[idx], Im[idx]);
    }
    dft8<S>(v);
    #pragma unroll
    for (int k1 = 1; k1 < 8; ++k1) {
        int mm = (t8*k1) & 63;
        v[k1] = cmulf(v[k1], make_float2(twc[mm], (float)S*tws[mm]));
    }
    __syncthreads();
    #pragma unroll
    for (int k1 = 0; k1 < 8; ++k1) {
        int idx = (k1*8 + t8)*FPITCH + col;
        Re[idx] = v[k1].x; Im[idx] = v[k1].y;
    }
    __syncthreads();
    float2 a[8];
    #pragma unroll
    for (int m = 0; m < 8; ++m) {
        int idx = (t8*8 + m)*FPITCH + col;
        a[m] = make_float2(Re[idx], Im[idx]);
    }
    dft8<S>(a);
    if (MODE <= 1) {
        __syncthreads();
        #pragma unroll
        for (int k2 = 0; k2 < 8; ++k2) {
            int row = t8 + 8*k2;
            float2 rv = a[k2];
            if (MODE == 1) {
                float sv, cv;
                __sincosf((TWO_PI/4096.f) * (float)(row*col), &sv, &cv);
                rv = cmulf(rv, make_float2(cv, (float)S*sv));
            }
            int idx = row*FPITCH + col;
            Re[idx] = rv.x; Im[idx] = rv.y;
        }
    } else if (MODE == 2) {
        #pragma unroll
        for (int k2 = 0; k2 < 8; ++k2) {
            int row = t8 + 8*k2;
            *ss += a[k2].x*a[k2].x + a[k2].y*a[k2].y;
            gre[row*64 + col] = a[k2].x*scale;
            gim[row*64 + col] = a[k2].y*scale;
        }
    } else {
        #pragma unroll
        for (int k2 = 0; k2 < 8; ++k2) {
            int row = t8 + 8*k2;
            goutr[row*64 + col] = f2bf(scale * sqrtf(a[k2].x*a[k2].x + a[k2].y*a[k2].y));
        }
    }
    __syncthreads();
}

// conv weights (256,512,3,3) fp32 -> wB[t][o][i] bf16 (i contiguous = K-contiguous B rows)
__global__ __launch_bounds__(256) void k_wconv(const float* __restrict__ w, unsigned short* __restrict__ wB) {
    int idx = blockIdx.x*256 + threadIdx.x;
    if (idx >= 9*NC*ND) return;
    int i = idx & 511;
    int rest = idx >> 9;
    int o = rest & 255;
    int t = rest >> 8;
    wB[idx] = f2bf(w[(o*NC + i)*9 + t]);
}

// proj weights (512,512) fp32 -> bf16, same [o][c] layout
__global__ __launch_bounds__(256) void k_wproj(const float* __restrict__ w, unsigned short* __restrict__ wb) {
    int i = blockIdx.x*256 + threadIdx.x;
    wb[i] = f2bf(w[i]);
}

// x (b, 4096, 512) fp32 -> spatially padded bf16 xpad[b][hp][wp][c], hp/wp in [0,70)
__global__ __launch_bounds__(256) void k_xpad(const float* __restrict__ x, unsigned short* __restrict__ xpad) {
    int idx = blockIdx.x*256 + threadIdx.x;
    int c8 = idx & 63;
    int rest = idx >> 6;
    int wp = rest % HPAD;
    int rest2 = rest / HPAD;
    int hp = rest2 % HPAD;
    int b = rest2 / HPAD;
    int h = hp - 3, w = wp - 3;
    bf16x8 v = {0,0,0,0,0,0,0,0};
    if (((unsigned)h) < 64u && ((unsigned)w) < 64u) {
        const float* s = x + (((size_t)b*NP + h*64 + w)*NC + c8*8);
        float4 f0 = *(const float4*)(s);
        float4 f1 = *(const float4*)(s + 4);
        v[0]=(short)f2bf(f0.x); v[1]=(short)f2bf(f0.y); v[2]=(short)f2bf(f0.z); v[3]=(short)f2bf(f0.w);
        v[4]=(short)f2bf(f1.x); v[5]=(short)f2bf(f1.y); v[6]=(short)f2bf(f1.z); v[7]=(short)f2bf(f1.w);
    }
    *(bf16x8*)(xpad + ((size_t)(b*HPAD*HPAD) + hp*HPAD + wp)*NC + c8*8) = v;
}

// bf16 MFMA implicit-GEMM dilated conv (d=3,pad=3) + bias + BN + ReLU -> out[b][o][p] fp32
// R4-proven 2-phase double-buffer: K=64 chunks, one barrier per chunk, stage issued before compute.
// K-slot swizzle (verified bijective; conflicts 0): source slot c16^((r0>>1)&3), read slot kq^((ln>>1)&3).
__global__ __launch_bounds__(256, 2) void k_conv_mfma(
        const unsigned short* __restrict__ xpad, const unsigned short* __restrict__ wB,
        const float* __restrict__ cbias, const float* __restrict__ bg, const float* __restrict__ bb,
        const float* __restrict__ bm, const float* __restrict__ bv, float* __restrict__ out)
{
    // [buf][ks*4096 + row*32 + slot*8] ; 2 bufs x (A,B) x 16 KB = 64 KB
    __shared__ short Als[2][8192];
    __shared__ short Bls[2][8192];
    int tid = threadIdx.x;
    int p0 = blockIdx.x * 128;
    int o0 = blockIdx.y * 128;
    int b  = blockIdx.z;
    int lane = tid & 63;
    int wv = tid >> 6;
    int wr = wv >> 1, wc = wv & 1;
    int ln = lane & 15, kq = lane >> 4;
    int kqs = kq ^ ((ln >> 1) & 3);          // swizzled K-slot (read side)

    f32x4 acc[4][4];
    #pragma unroll
    for (int i = 0; i < 4; ++i)
        #pragma unroll
        for (int j = 0; j < 4; ++j)
            acc[i][j] = (f32x4){0.f, 0.f, 0.f, 0.f};

    int r0 = tid >> 2;
    int c16 = tid & 3;
    int c16s = c16 ^ ((r0 >> 1) & 3);        // swizzled K-slot (global source side)
    int pA0 = p0 + r0, pA1 = p0 + 64 + r0;
    int h0 = pA0 >> 6, w0c = pA0 & 63;
    int h1 = pA1 >> 6, w1c = pA1 & 63;
    const unsigned short* xb = xpad + (size_t)b*(HPAD*HPAD)*NC;
    int oB0 = o0 + r0, oB1 = o0 + 64 + r0;
    short* AlsD0 = &Als[0][tid*8];
    short* AlsD1 = &Als[0][2048 + tid*8];
    short* BlsD0 = &Bls[0][tid*8];
    short* BlsD1 = &Bls[0][2048 + tid*8];

    // Stage K-chunk `it` (of 72 = 9 taps x 8 chunks of K=64) into buffer it&1.
    auto stage = [&](int it) {
        int buf = it & 1;
        int tap = it >> 3;
        int kc  = (it & 7) << 6;
        int q   = (tap*11) >> 5;             // tap/3 for tap in [0,9)
        int dh  = q*3, dw = (tap - q*3)*3;
        const unsigned short* a0 = xb + ((size_t)((h0 + dh)*HPAD + (w0c + dw)))*NC + kc + c16s*8;
        const unsigned short* a1 = xb + ((size_t)((h1 + dh)*HPAD + (w1c + dw)))*NC + kc + c16s*8;
        const unsigned short* b0 = wB + ((size_t)(tap*ND + oB0))*NC + kc + c16s*8;
        const unsigned short* b1 = wB + ((size_t)(tap*ND + oB1))*NC + kc + c16s*8;
        int bo = buf ? 8192 : 0;
        load_lds16(a0,      AlsD0 + bo);          // ks=0 rows 0..63
        load_lds16(a1,      AlsD1 + bo);          // ks=0 rows 64..127
        load_lds16(a0 + 32, AlsD0 + bo + 4096);   // ks=1 rows 0..63
        load_lds16(a1 + 32, AlsD1 + bo + 4096);   // ks=1 rows 64..127
        load_lds16(b0,      BlsD0 + bo);
        load_lds16(b1,      BlsD1 + bo);
        load_lds16(b0 + 32, BlsD0 + bo + 4096);
        load_lds16(b1 + 32, BlsD1 + bo + 4096);
    };

    stage(0);
    #pragma unroll 2
    for (int it = 0; it < 72; ++it) {
        int buf = it & 1;
        // my 8 loads for buf (issued last iteration / prologue) must be complete
        asm volatile("s_waitcnt vmcnt(0)" ::: "memory");
        __builtin_amdgcn_s_barrier();          // all waves: buf ready; all prev ds_reads done
        __builtin_amdgcn_sched_barrier(0);     // no LDS access motion across the barrier
        if (it + 1 < 72) stage(it + 1);        // overlap with compute below
        #pragma unroll
        for (int ks = 0; ks < 2; ++ks) {
            bf16x8 af[4], bfr[4];
            #pragma unroll
            for (int mi = 0; mi < 4; ++mi)
                af[mi] = *(const bf16x8*)&Als[buf][ks*4096 + (wr*64 + mi*16 + ln)*32 + kqs*8];
            #pragma unroll
            for (int ni = 0; ni < 4; ++ni)
                bfr[ni] = *(const bf16x8*)&Bls[buf][ks*4096 + (wc*64 + ni*16 + ln)*32 + kqs*8];
            #pragma unroll
            for (int mi = 0; mi < 4; ++mi)
                #pragma unroll
                for (int ni = 0; ni < 4; ++ni)
                    acc[mi][ni] = __builtin_amdgcn_mfma_f32_16x16x32_bf16(af[mi], bfr[ni], acc[mi][ni], 0, 0, 0);
        }
    }

    #pragma unroll
    for (int ni = 0; ni < 4; ++ni) {
        int o = o0 + wc*64 + ni*16 + ln;
        float inv = bg[o] * rsqrtf(bv[o] + 1e-5f);
        float beta = bb[o] - bm[o]*inv;
        float cbo = cbias[o];
        #pragma unroll
        for (int mi = 0; mi < 4; ++mi) {
            int p = p0 + wr*64 + mi*16 + kq*4;
            f32x4 v = acc[mi][ni];
            float4 rv;
            rv.x = fmaxf((v[0] + cbo)*inv + beta, 0.f);
            rv.y = fmaxf((v[1] + cbo)*inv + beta, 0.f);
            rv.z = fmaxf((v[2] + cbo)*inv + beta, 0.f);
            rv.w = fmaxf((v[3] + cbo)*inv + beta, 0.f);
            *(float4*)(out + ((size_t)(b*ND + o))*NP + p) = rv;
        }
    }
}

// fft2 (forward) of one 64x64 real image -> split planes fRe/fIm; also writes per-image L2 norm
__global__ __launch_bounds__(512) void k_fft2_fwd(const float* __restrict__ src, float* __restrict__ fRe,
                                                  float* __restrict__ fIm, float* __restrict__ nrm) {
    __shared__ float Re[64*FPITCH];
    __shared__ float Im[64*FPITCH];
    __shared__ float twc[64], tws[64];
    __shared__ float part[8];
    int tid = threadIdx.x;
    size_t img = blockIdx.x;
    const float* s = src + img*4096;
    if (tid < 64) { float sv, cv; __sincosf(TWO_PI*(float)tid/64.f, &sv, &cv); twc[tid]=cv; tws[tid]=sv; }
    for (int i = tid; i < 4096; i += 512) {
        Re[(i>>6)*FPITCH + (i&63)] = s[i];
        Im[(i>>6)*FPITCH + (i&63)] = 0.f;
    }
    fft64_rows<-1,0>(Re, Im, twc, tws, tid, nullptr, 1.f);
    float ssl = 0.f;
    fft64_cols<-1,2>(Re, Im, twc, tws, tid, fRe + img*4096, fIm + img*4096, nullptr, 1.f, &ssl);
    #pragma unroll
    for (int off = 32; off > 0; off >>= 1) ssl += __shfl_down(ssl, off, 64);
    if ((tid & 63) == 0) part[tid >> 6] = ssl;
    __syncthreads();
    if (tid == 0) {
        float t = part[0]+part[1]+part[2]+part[3]+part[4]+part[5]+part[6]+part[7];
        nrm[img] = fmaxf(sqrtf(t), 1e-12f);
    }
}

// 4096-pt inverse FFT of one f-row (Cooley-Tukey 64x64): Z[k1+64*k2], includes 1/4096
__global__ __launch_bounds__(512) void k_ifft_row4096(const float* __restrict__ fRe,
        const float* __restrict__ fIm, float2* __restrict__ Z) {
    __shared__ float Re[64*FPITCH];
    __shared__ float Im[64*FPITCH];
    __shared__ float twc[64], tws[64];
    int tid = threadIdx.x;
    size_t img = blockIdx.x;
    const float* sr = fRe + img*4096;
    const float* si = fIm + img*4096;
    if (tid < 64) { float sv, cv; __sincosf(TWO_PI*(float)tid/64.f, &sv, &cv); twc[tid]=cv; tws[tid]=sv; }
    for (int i = tid; i < 4096; i += 512) {
        Re[(i>>6)*FPITCH + (i&63)] = sr[i];
        Im[(i>>6)*FPITCH + (i&63)] = si[i];
    }
    fft64_cols<1,1>(Re, Im, twc, tws, tid, nullptr, nullptr, nullptr, 1.f, nullptr);
    fft64_rows<1,1>(Re, Im, twc, tws, tid, Z + img*4096, 1.f/4096.f);
}

// gated ifft2: computes gate = sigmoid(w2 @ g1 + b2) on the fly (g1 transposed [b][p][16],
// contiguous float4 reads), multiplies f, ifft2, abs * 1/4096 -> bf16 [c][p].
__global__ __launch_bounds__(512) void k_ifft2_abs_gated(const float* __restrict__ fRe,
        const float* __restrict__ fIm, const float* __restrict__ g1, const float* __restrict__ w2,
        const float* __restrict__ w2b, unsigned short* __restrict__ out) {
    __shared__ float Re[64*FPITCH];
    __shared__ float Im[64*FPITCH];
    __shared__ float twc[64], tws[64];
    int tid = threadIdx.x;
    size_t img = blockIdx.x;
    int b = (int)(img >> 8), ch = (int)(img & 255);
    const float* sr = fRe + img*4096;
    const float* si = fIm + img*4096;
    const float* g1b = g1 + (size_t)b*NP*16;
    float4 wv0 = *(const float4*)(w2 + ch*16);
    float4 wv1 = *(const float4*)(w2 + ch*16 + 4);
    float4 wv2 = *(const float4*)(w2 + ch*16 + 8);
    float4 wv3 = *(const float4*)(w2 + ch*16 + 12);
    float w2bias = w2b[ch];
    if (tid < 64) { float sv, cv; __sincosf(TWO_PI*(float)tid/64.f, &sv, &cv); twc[tid]=cv; tws[tid]=sv; }
    for (int i = tid; i < 4096; i += 512) {
        const float* gp = g1b + (size_t)i*16;
        float4 q0 = *(const float4*)(gp);
        float4 q1 = *(const float4*)(gp + 4);
        float4 q2 = *(const float4*)(gp + 8);
        float4 q3 = *(const float4*)(gp + 12);
        float acc = w2bias
            + wv0.x*q0.x + wv0.y*q0.y + wv0.z*q0.z + wv0.w*q0.w
            + wv1.x*q1.x + wv1.y*q1.y + wv1.z*q1.z + wv1.w*q1.w
            + wv2.x*q2.x + wv2.y*q2.y + wv2.z*q2.z + wv2.w*q2.w
            + wv3.x*q3.x + wv3.y*q3.y + wv3.z*q3.z + wv3.w*q3.w;
        float gate = 1.f / (1.f + __expf(-acc));
        Re[(i>>6)*FPITCH + (i&63)] = gate*sr[i];
        Im[(i>>6)*FPITCH + (i&63)] = gate*si[i];
    }
    fft64_rows<1,0>(Re, Im, twc, tws, tid, nullptr, 1.f);
    fft64_cols<1,3>(Re, Im, twc, tws, tid, nullptr, nullptr, out + img*4096, 1.f/4096.f, nullptr);
}

// G[c][d] = sum_n f_c[n]*f_d[n] (complex, no conj) via bf16 hi+lo split MFMA.
// Grid (NSPL=16 n-splits, 64 bh); 4 waves = 2x2 quadrants of the 32x32 output.
__global__ __launch_bounds__(256) void k_gram(const float* __restrict__ fRe, const float* __restrict__ fIm,
                                              float2* __restrict__ Gpart) {
    __shared__ short FrP[32*136];   // [row][K2=128], row padded to 136 (68 words -> 2-way max)
    __shared__ short FiP[32*136];
    int split = blockIdx.x;
    int bh = blockIdx.y;
    int b = bh >> 3, h = bh & 7;
    int tid = threadIdx.x;
    int lane = tid & 63;
    int wv = tid >> 6;
    int cr = (wv >> 1) * 16, dc = (wv & 1) * 16;
    int ln = lane & 15, kq = lane >> 4;
    int r = tid >> 3;          // staging row 0..31
    int g = tid & 7;           // staging n-octet
    const float* fRb = fRe + ((size_t)(b*ND + h*32) + r)*NP + split*256 + g*8;
    const float* fIb = fIm + ((size_t)(b*ND + h*32) + r)*NP + split*256 + g*8;
    short* wFr = FrP + r*136 + g*16;
    short* wFi = FiP + r*136 + g*16;

    f32x4 arr = {0.f,0.f,0.f,0.f}, aii = {0.f,0.f,0.f,0.f};
    f32x4 ari = {0.f,0.f,0.f,0.f}, air = {0.f,0.f,0.f,0.f};

    for (int chunk = 0; chunk < 4; ++chunk) {       // 4 chunks x 64 n = 256 n per split
        float4 v0 = *(const float4*)(fRb + chunk*64);
        float4 v1 = *(const float4*)(fRb + chunk*64 + 4);
        float4 w0 = *(const float4*)(fIb + chunk*64);
        float4 w1 = *(const float4*)(fIb + chunk*64 + 4);
        __syncthreads();                            // previous chunk's MFMA reads done
        float vr[8] = {v0.x,v0.y,v0.z,v0.w,v1.x,v1.y,v1.z,v1.w};
        float vi[8] = {w0.x,w0.y,w0.z,w0.w,w1.x,w1.y,w1.z,w1.w};
        bf16x8 r0v, r1v, i0v, i1v;
        #pragma unroll
        for (int j = 0; j < 4; ++j) {
            unsigned short hb;
            hb = f2bf(vr[j]);   r0v[2*j] = (short)hb; r0v[2*j+1] = (short)f2bf(vr[j]   - bf2f(hb));
            hb = f2bf(vr[4+j]); r1v[2*j] = (short)hb; r1v[2*j+1] = (short)f2bf(vr[4+j] - bf2f(hb));
            hb = f2bf(vi[j]);   i0v[2*j] = (short)hb; i0v[2*j+1] = (short)f2bf(vi[j]   - bf2f(hb));
            hb = f2bf(vi[4+j]); i1v[2*j] = (short)hb; i1v[2*j+1] = (short)f2bf(vi[4+j] - bf2f(hb));
        }
        *(bf16x8*)(wFr)     = r0v;
        *(bf16x8*)(wFr + 8) = r1v;
        *(bf16x8*)(wFi)     = i0v;
        *(bf16x8*)(wFi + 8) = i1v;
        __syncthreads();
        const short* aRp = FrP + (cr + ln)*136;
        const short* aIp = FiP + (cr + ln)*136;
        const short* bRp = FrP + (dc + ln)*136;
        const short* bIp = FiP + (dc + ln)*136;
        #pragma unroll
        for (int s = 0; s < 4; ++s) {               // K2 = 128 -> 4 mfma steps of K=32
            int ko = s*32 + kq*8;
            bf16x8 aR = *(const bf16x8*)(aRp + ko);
            bf16x8 aI = *(const bf16x8*)(aIp + ko);
            bf16x8 bR = *(const bf16x8*)(bRp + ko);
            bf16x8 bI = *(const bf16x8*)(bIp + ko);
            arr = __builtin_amdgcn_mfma_f32_16x16x32_bf16(aR, bR, arr, 0, 0, 0);
            aii = __builtin_amdgcn_mfma_f32_16x16x32_bf16(aI, bI, aii, 0, 0, 0);
            ari = __builtin_amdgcn_mfma_f32_16x16x32_bf16(aR, bI, ari, 0, 0, 0);
            air = __builtin_amdgcn_mfma_f32_16x16x32_bf16(aI, bR, air, 0, 0, 0);
        }
    }
    // C/D layout: col = ln (d), row = kq*4 + j (c) within the wave's 16x16 quadrant.
    float2* gout = Gpart + ((size_t)bh*NSPL + split)*1024;
    #pragma unroll
    for (int j = 0; j < 4; ++j) {
        int c = cr + kq*4 + j;
        int d = dc + ln;
        gout[c*32 + d] = make_float2(arr[j] - aii[j], ari[j] + air[j]);
    }
}

// reduce partials, normalize, *temp, dual softmax, then A' = (1/32) W32+ @ S
__global__ __launch_bounds__(256) void k_attn(const float2* __restrict__ Gpart, const float* __restrict__ nrm,
                                              const float* __restrict__ temp, float2* __restrict__ Ap) {
    int bh = blockIdx.x;
    int b = bh >> 3, h = bh & 7;
    int tid = threadIdx.x;
    __shared__ float2 Sm[32][33];
    __shared__ float twc[32], tws[32];
    if (tid < 32) { float sv, cv; __sincosf(TWO_PI*(float)tid/32.f, &sv, &cv); twc[tid]=cv; tws[tid]=sv; }
    const float* nb = nrm + b*ND + h*32;
    float tv = temp[h];
    const float2* gp = Gpart + (size_t)bh*NSPL*1024;
    #pragma unroll
    for (int j = 0; j < 4; ++j) {
        int e = tid*4 + j;
        int c = e >> 5, d = e & 31;
        float2 s = make_float2(0.f, 0.f);
        for (int sp = 0; sp < NSPL; ++sp) { float2 v = gp[sp*1024 + e]; s.x += v.x; s.y += v.y; }
        float sc = tv / (nb[c]*nb[d]);
        Sm[c][d] = make_float2(s.x*sc, s.y*sc);
    }
    __syncthreads();
    if (tid < 32) {
        float mr = -1e30f, mi = -1e30f;
        for (int d = 0; d < 32; ++d) { float2 v = Sm[tid][d]; mr = fmaxf(mr, v.x); mi = fmaxf(mi, v.y); }
        float sr = 0.f, si = 0.f;
        for (int d = 0; d < 32; ++d) {
            float2 v = Sm[tid][d];
            v.x = __expf(v.x - mr); v.y = __expf(v.y - mi);
            sr += v.x; si += v.y;
            Sm[tid][d] = v;
        }
        float ir = 1.f/sr, ii = 1.f/si;
        for (int d = 0; d < 32; ++d) { float2 v = Sm[tid][d]; Sm[tid][d] = make_float2(v.x*ir, v.y*ii); }
    }
    __syncthreads();
    float2* ap = Ap + (size_t)bh*1024;
    #pragma unroll
    for (int j = 0; j < 4; ++j) {
        int e = tid*4 + j;
        int k = e >> 5, d = e & 31;
        float2 acc = make_float2(0.f, 0.f);
        for (int c = 0; c < 32; ++c) {
            int m = (c*k) & 31;
            float2 w = make_float2(twc[m], tws[m]);
            float2 v = Sm[c][d];
            acc.x += w.x*v.x - w.y*v.y;
            acc.y += w.x*v.y + w.y*v.x;
        }
        ap[e] = make_float2(acc.x*(1.f/32.f), acc.y*(1.f/32.f));
    }
}

// out_f2 = | A' @ Z | per (b,head) -> bf16 [c][p], via MFMA with quad expansion:
// A entries [ah,ah,al,al], Z entries [zh,zl,zh,zl] per scalar (K=4*32=128) ->
// dot = (ah+al)(zh+zl) exact to ~2^-17. Same fragment mapping as k_gram (verified):
// both operands row-major [row][136], D[c][n]: col=ln, row=kq*4+j.
// Grid (64 n-chunks of 64, 64 bh); 4 waves, wave wv owns n-tile wv, both m-tiles.
__global__ __launch_bounds__(256) void k_outf2(const float2* __restrict__ Ap, const float2* __restrict__ Z,
                                               unsigned short* __restrict__ outf2) {
    __shared__ short Are[32*136], Aim[32*136];   // A' quad-expanded [c][128]
    __shared__ short Bre[64*136], Bim[64*136];   // Z  quad-expanded [n][128]
    int nchunk = blockIdx.x, bh = blockIdx.y;
    int b = bh >> 3, h = bh & 7;
    int n0 = nchunk * 64;
    int tid = threadIdx.x;
    int lane = tid & 63;
    int wv = tid >> 6;
    int ln = lane & 15, kq = lane >> 4;

    const float2* ap = Ap + (size_t)bh*1024;
    #pragma unroll
    for (int j = 0; j < 4; ++j) {
        int e = tid*4 + j;
        int c = e >> 5, d = e & 31;
        float2 a = ap[e];
        unsigned short rh = f2bf(a.x); unsigned short rl = f2bf(a.x - bf2f(rh));
        unsigned short ih = f2bf(a.y); unsigned short il = f2bf(a.y - bf2f(ih));
        short* pr = Are + c*136 + 4*d;
        short* pi = Aim + c*136 + 4*d;
        pr[0]=(short)rh; pr[1]=(short)rh; pr[2]=(short)rl; pr[3]=(short)rl;
        pi[0]=(short)ih; pi[1]=(short)ih; pi[2]=(short)il; pi[3]=(short)il;
    }
    const float2* zb = Z + ((size_t)(b*ND + h*32))*NP + n0;
    #pragma unroll
    for (int j = 0; j < 8; ++j) {
        int e = tid + 256*j;
        int d = e >> 6, n = e & 63;
        float2 z = zb[(size_t)d*NP + n];
        unsigned short rh = f2bf(z.x); unsigned short rl = f2bf(z.x - bf2f(rh));
        unsigned short ih = f2bf(z.y); unsigned short il = f2bf(z.y - bf2f(ih));
        short* pr = Bre + n*136 + 4*d;
        short* pi = Bim + n*136 + 4*d;
        pr[0]=(short)rh; pr[1]=(short)rl; pr[2]=(short)rh; pr[3]=(short)rl;
        pi[0]=(short)ih; pi[1]=(short)il; pi[2]=(short)ih; pi[3]=(short)il;
    }
    __syncthreads();

    f32x4 arr[2], aii[2], ari[2], air[2];
    #pragma unroll
    for (int mt = 0; mt < 2; ++mt) {
        arr[mt] = (f32x4){0.f,0.f,0.f,0.f}; aii[mt] = (f32x4){0.f,0.f,0.f,0.f};
        ari[mt] = (f32x4){0.f,0.f,0.f,0.f}; air[mt] = (f32x4){0.f,0.f,0.f,0.f};
    }
    const short* bRrow = Bre + (wv*16 + ln)*136;
    const short* bIrow = Bim + (wv*16 + ln)*136;
    #pragma unroll
    for (int s = 0; s < 4; ++s) {
        int ko = s*32 + kq*8;
        bf16x8 bR = *(const bf16x8*)(bRrow + ko);
        bf16x8 bI = *(const bf16x8*)(bIrow + ko);
        #pragma unroll
        for (int mt = 0; mt < 2; ++mt) {
            bf16x8 aR = *(const bf16x8*)(Are + (mt*16 + ln)*136 + ko);
            bf16x8 aI = *(const bf16x8*)(Aim + (mt*16 + ln)*136 + ko);
            arr[mt] = __builtin_amdgcn_mfma_f32_16x16x32_bf16(aR, bR, arr[mt], 0, 0, 0);
            aii[mt] = __builtin_amdgcn_mfma_f32_16x16x32_bf16(aI, bI, aii[mt], 0, 0, 0);
            ari[mt] = __builtin_amdgcn_mfma_f32_16x16x32_bf16(aR, bI, ari[mt], 0, 0, 0);
            air[mt] = __builtin_amdgcn_mfma_f32_16x16x32_bf16(aI, bR, air[mt], 0, 0, 0);
        }
    }
    // D[c][n]: c = mt*16 + kq*4 + j, n = n0 + wv*16 + ln
    #pragma unroll
    for (int mt = 0; mt < 2; ++mt)
        #pragma unroll
        for (int j = 0; j < 4; ++j) {
            int c = mt*16 + kq*4 + j;
            float re = arr[mt][j] - aii[mt][j];
            float im = ari[mt][j] + air[mt][j];
            outf2[((size_t)(b*ND + h*32 + c))*NP + n0 + wv*16 + ln] = f2bf(sqrtf(re*re + im*im));
        }
}

// g1 = relu(BN(w1 @ Re(f)))  -- reads the compact fRe plane; writes TRANSPOSED [b][p][16]
__global__ __launch_bounds__(256) void k_g1(const float* __restrict__ fRe, const float* __restrict__ w1,
        const float* __restrict__ w1b, const float* __restrict__ gg, const float* __restrict__ gb,
        const float* __restrict__ gm, const float* __restrict__ gv, float* __restrict__ g1)
{
    int pc = blockIdx.x, b = blockIdx.y;
    int tid = threadIdx.x;
    __shared__ float w1s[16*256];
    for (int i = tid; i < 4096; i += 256) w1s[i] = w1[i];
    __syncthreads();
    int p = pc*256 + tid;
    const float* fb = fRe + (size_t)b*ND*NP + p;
    float acc[16];
    #pragma unroll
    for (int j = 0; j < 16; ++j) acc[j] = 0.f;
    for (int i = 0; i < 256; ++i) {
        float v = fb[(size_t)i*NP];
        #pragma unroll
        for (int j = 0; j < 16; ++j) acc[j] += w1s[j*256 + i] * v;
    }
    float* go = g1 + ((size_t)b*NP + p)*16;
    float4 o4[4];
    #pragma unroll
    for (int j = 0; j < 16; ++j) {
        float inv = gg[j]*rsqrtf(gv[j] + 1e-5f);
        float val = (acc[j] + w1b[j])*inv + (gb[j] - gm[j]*inv);
        ((float*)o4)[j] = fmaxf(val, 0.f);
    }
    *(float4*)(go)      = o4[0];
    *(float4*)(go + 4)  = o4[1];
    *(float4*)(go + 8)  = o4[2];
    *(float4*)(go + 12) = o4[3];
}

// A[b][p][c] bf16 = cat(outf2b,outl2b)[c][p] + x[b][p][c]
__global__ __launch_bounds__(256) void k_prep(const unsigned short* __restrict__ outf2b,
        const unsigned short* __restrict__ outl2b, const float* __restrict__ x,
        unsigned short* __restrict__ A)
{
    int tid = threadIdx.x;
    int p = blockIdx.x*64 + (tid >> 2);
    int cs = blockIdx.y*64 + (tid & 3)*16;
    int b  = blockIdx.z;
    const unsigned short* src = (cs < ND) ? (outf2b + ((size_t)(b*ND) + cs)*NP + p)
                                          : (outl2b + ((size_t)(b*ND) + (cs - ND))*NP + p);
    float av[16];
    #pragma unroll
    for (int j = 0; j < 16; ++j) av[j] = bf2f(src[(size_t)j*NP]);
    const float* xp = x + ((size_t)(b*NP) + p)*NC + cs;
    #pragma unroll
    for (int j = 0; j < 4; ++j) {
        float4 xv = *(const float4*)(xp + j*4);
        av[j*4+0] += xv.x; av[j*4+1] += xv.y; av[j*4+2] += xv.z; av[j*4+3] += xv.w;
    }
    bf16x8 v0, v1;
    #pragma unroll
    for (int j = 0; j < 8; ++j) { v0[j] = (short)f2bf(av[j]); v1[j] = (short)f2bf(av[8+j]); }
    unsigned short* ap = A + ((size_t)(b*NP) + p)*NC + cs;
    *(bf16x8*)(ap) = v0;
    *(bf16x8*)(ap + 8) = v1;
}

// bf16 MFMA proj GEMM: out[b][p][o] = A[b][p][:] . pw[o][:] + pb[o]
// R4-proven 2-phase double-buffer + K-slot swizzle.
__global__ __launch_bounds__(256, 2) void k_projm(
        const unsigned short* __restrict__ A, const unsigned short* __restrict__ Bw,
        const float* __restrict__ pb, float* __restrict__ out)
{
    __shared__ short Als[2][8192];
    __shared__ short Bls[2][8192];
    int tid = threadIdx.x;
    int p0 = blockIdx.x * 128;
    int o0 = blockIdx.y * 128;
    int b  = blockIdx.z;
    int lane = tid & 63;
    int wv = tid >> 6;
    int wr = wv >> 1, wc = wv & 1;
    int ln = lane & 15, kq = lane >> 4;
    int kqs = kq ^ ((ln >> 1) & 3);

    f32x4 acc[4][4];
    #pragma unroll
    for (int i = 0; i < 4; ++i)
        #pragma unroll
        for (int j = 0; j < 4; ++j)
            acc[i][j] = (f32x4){0.f, 0.f, 0.f, 0.f};

    int r0 = tid >> 2;
    int c16 = tid & 3;
    int c16s = c16 ^ ((r0 >> 1) & 3);
    const unsigned short* ga0 = A + ((size_t)(b*NP) + p0 + r0)*NC + c16s*8;
    const unsigned short* ga1 = A + ((size_t)(b*NP) + p0 + 64 + r0)*NC + c16s*8;
    const unsigned short* gb0 = Bw + (size_t)(o0 + r0)*NC + c16s*8;
    const unsigned short* gb1 = Bw + (size_t)(o0 + 64 + r0)*NC + c16s*8;
    short* AlsD0 = &Als[0][tid*8];
    short* AlsD1 = &Als[0][2048 + tid*8];
    short* BlsD0 = &Bls[0][tid*8];
    short* BlsD1 = &Bls[0][2048 + tid*8];

    auto stage = [&](int it) {
        int buf = it & 1;
        int kc = it << 6;
        int bo = buf ? 8192 : 0;
        load_lds16(ga0 + kc,      AlsD0 + bo);
        load_lds16(ga1 + kc,      AlsD1 + bo);
        load_lds16(ga0 + kc + 32, AlsD0 + bo + 4096);
        load_lds16(ga1 + kc + 32, AlsD1 + bo + 4096);
        load_lds16(gb0 + kc,      BlsD0 + bo);
        load_lds16(gb1 + kc,      BlsD1 + bo);
        load_lds16(gb0 + kc + 32, BlsD0 + bo + 4096);
        load_lds16(gb1 + kc + 32, BlsD1 + bo + 4096);
    };

    stage(0);
    #pragma unroll 2
    for (int it = 0; it < 8; ++it) {
        int buf = it & 1;
        asm volatile("s_waitcnt vmcnt(0)" ::: "memory");
        __builtin_amdgcn_s_barrier();
        __builtin_amdgcn_sched_barrier(0);
        if (it + 1 < 8) stage(it + 1);
        #pragma unroll
        for (int ks = 0; ks < 2; ++ks) {
            bf16x8 af[4], bfr[4];
            #pragma unroll
            for (int mi = 0; mi < 4; ++mi)
                af[mi] = *(const bf16x8*)&Als[buf][ks*4096 + (wr*64 + mi*16 + ln)*32 + kqs*8];
            #pragma unroll
            for (int ni = 0; ni < 4; ++ni)
                bfr[ni] = *(const bf16x8*)&Bls[buf][ks*4096 + (wc*64 + ni*16 + ln)*32 + kqs*8];
            #pragma unroll
            for (int mi = 0; mi < 4; ++mi)
                #pragma unroll
                for (int ni = 0; ni < 4; ++ni)
                    acc[mi][ni] = __builtin_amdgcn_mfma_f32_16x16x32_bf16(af[mi], bfr[ni], acc[mi][ni], 0, 0, 0);
        }
    }

    // C/D: col(ln)=o, row(kq*4+reg)=p. 16 lanes x 4B consecutive in o => full 64B lines.
    #pragma unroll
    for (int ni = 0; ni < 4; ++ni) {
        int o = o0 + wc*64 + ni*16 + ln;
        float bias = pb[o];
        #pragma unroll
        for (int mi = 0; mi < 4; ++mi) {
            int p = p0 + wr*64 + mi*16 + kq*4;
            f32x4 v = acc[mi][ni];
            float* op = out + ((size_t)(b*NP) + p)*NC + o;
            op[0]        = v[0] + bias;
            op[NC]       = v[1] + bias;
            op[2*NC]     = v[2] + bias;
            op[3*(size_t)NC] = v[3] + bias;
        }
    }
}

extern "C" void kernel_launch(void* const* d_in, const int* in_sizes, int n_in,
                              void* d_out, int out_size, void* d_ws, size_t ws_size,
                              hipStream_t stream)
{
    const float* x      = (const float*)d_in[0];
    const float* conv_w = (const float*)d_in[1];
    const float* conv_b = (const float*)d_in[2];
    const float* bn2g   = (const float*)d_in[3];
    const float* bn2b   = (const float*)d_in[4];
    const float* bn2m   = (const float*)d_in[5];
    const float* bn2v   = (const float*)d_in[6];
    const float* temp   = (const float*)d_in[7];
    const float* w1w    = (const float*)d_in[8];
    const float* w1b    = (const float*)d_in[9];
    const float* bnwg   = (const float*)d_in[10];
    const float* bnwb   = (const float*)d_in[11];
    const float* bnwm   = (const float*)d_in[12];
    const float* bnwv   = (const float*)d_in[13];
    const float* w2w    = (const float*)d_in[14];
    const float* w2b    = (const float*)d_in[15];
    const float* projw  = (const float*)d_in[16];
    const float* projb  = (const float*)d_in[17];
    float* out = (float*)d_out;

    char* ws = (char*)d_ws;
    // Head overlay region [0, 6,823,936):
    //   wB bf16 (2,359,296 B) during conv; nrm/Ap/g1 reuse it afterwards.
    unsigned short* wB = (unsigned short*)(ws);
    float*  nrm   = (float*)(ws);
    float2* Ap    = (float2*)(ws + 8192 + 4194304);
    float*  g1    = (float*)(ws + 8192 + 4194304 + 524288);   // [b][p][16] transposed, 2MB
    char* base = ws + 6823936;
    // conv region [base, +33.5MB): conv fp32 (dead after fft2_fwd), then outf2b bf16 (16.7MB)
    float*  conv  = (float*)(base);
    unsigned short* outf2b = (unsigned short*)(base);
    // f region [base+33.5MB, +67MB): xpad bf16 overlay (40.1MB, dead after conv);
    //   then split planes fRe (33.5MB) / fIm (33.5MB), live through k_ifft2_abs_gated.
    float* fRe = (float*)(base + 33554432);
    float* fIm = (float*)(base + 33554432 + 33554432);
    unsigned short* xpad = (unsigned short*)(base + 33554432);
    // Z region [base+100.6MB, +67MB): Gpart (8MB, gram->attn, dead before Z written);
    //   then Z complex; after k_outf2 Z dead -> pwb bf16 (0.5MB) at base, Abf bf16 (33.5MB)
    //   at +4MB, outl2b bf16 (16.7MB) at +37.7MB
    char* zbase = base + 33554432 + 67108864;
    float2* Gpart = (float2*)(zbase);     // 64 bh x NSPL x 1024 float2 = 8 MB
    float2* Z     = (float2*)(zbase);
    unsigned short* pwb = (unsigned short*)(zbase);
    unsigned short* Abf = (unsigned short*)(zbase + 4194304);
    unsigned short* outl2b = (unsigned short*)(zbase + 37748736);
    // total workspace used: 174,596,096 bytes (unchanged)

    k_wconv<<<dim3(4608), 256, 0, stream>>>(conv_w, wB);
    k_xpad<<<dim3(9800), 256, 0, stream>>>(x, xpad);
    k_conv_mfma<<<dim3(32, 2, 8), 256, 0, stream>>>(xpad, wB, conv_b, bn2g, bn2b, bn2m, bn2v, conv);
    k_fft2_fwd<<<dim3(2048), 512, 0, stream>>>(conv, fRe, fIm, nrm);
    k_gram<<<dim3(NSPL, 64), 256, 0, stream>>>(fRe, fIm, Gpart);
    k_attn<<<dim3(64), 256, 0, stream>>>(Gpart, nrm, temp, Ap);
    k_ifft_row4096<<<dim3(2048), 512, 0, stream>>>(fRe, fIm, Z);
    k_outf2<<<dim3(64, 64), 256, 0, stream>>>(Ap, Z, outf2b);
    k_g1<<<dim3(16, 8), 256, 0, stream>>>(fRe, w1w, w1b, bnwg, bnwb, bnwm, bnwv, g1);
    k_ifft2_abs_gated<<<dim3(2048), 512, 0, stream>>>(fRe, fIm, g1, w2w, w2b, outl2b);
    k_wproj<<<dim3(1024), 256, 0, stream>>>(projw, pwb);
    k_prep<<<dim3(64, 8, 8), 256, 0, stream>>>(outf2b, outl2b, x, Abf);
    k_projm<<<dim3(32, 4, 8), 256, 0, stream>>>(Abf, pwb, projb, out);
}